// Round 2
// baseline (3949.850 us; speedup 1.0000x reference)
//
#include <hip/hip_runtime.h>
#include <hip/hip_bf16.h>
#include <math.h>

#define BATCH 512
#define NI 627
#define NH 1024
#define NOUTF 1254
#define LLEN 627
#define NBL (512 * 627)
#define EPSBN 1e-5f
#define NPART 64

// ---------------- masked MLP GEMM: C[M,N] = act(A[M,K] @ (W*mask)^T + bias) ----------------
// mode 0: od >= k (input mask); mode 1: od >= kd (hidden); mode 2: od > kd (output mask)
__global__ __launch_bounds__(256) void mlp_gemm(
    const float* __restrict__ A, const float* __restrict__ W,
    const float* __restrict__ bias, float* __restrict__ C,
    int M, int N, int K, int mode, int relu)
{
  __shared__ float as[16][68];
  __shared__ float wsd[16][68];
  const int tx = threadIdx.x & 15, ty = threadIdx.x >> 4;
  const int m0 = blockIdx.y * 64, n0 = blockIdx.x * 64;
  float acc[4][4] = {};
  for (int kc = 0; kc < K; kc += 16) {
    for (int i = threadIdx.x; i < 1024; i += 256) {
      int k = i & 15, m = i >> 4;
      int gk = kc + k, gm = m0 + m;
      as[k][m] = (gk < K && gm < M) ? A[gm * K + gk] : 0.f;
    }
    for (int i = threadIdx.x; i < 1024; i += 256) {
      int k = i & 15, n = i >> 4;
      int gk = kc + k, gn = n0 + n;
      float w = 0.f;
      if (gk < K && gn < N) {
        int od = gn >= 627 ? gn - 627 : gn;
        int kd = gk >= 627 ? gk - 627 : gk;
        bool keep = (mode == 0) ? (od >= gk) : (mode == 1) ? (od >= kd) : (od > kd);
        if (keep) w = W[gn * K + gk];
      }
      wsd[k][n] = w;
    }
    __syncthreads();
#pragma unroll
    for (int k = 0; k < 16; ++k) {
      float av[4], wv[4];
#pragma unroll
      for (int u = 0; u < 4; ++u) av[u] = as[k][ty * 4 + u];
#pragma unroll
      for (int v = 0; v < 4; ++v) wv[v] = wsd[k][tx * 4 + v];
#pragma unroll
      for (int u = 0; u < 4; ++u)
#pragma unroll
        for (int v = 0; v < 4; ++v) acc[u][v] = fmaf(av[u], wv[v], acc[u][v]);
    }
    __syncthreads();
  }
#pragma unroll
  for (int u = 0; u < 4; ++u) {
    int gm = m0 + ty * 4 + u;
    if (gm >= M) continue;
#pragma unroll
    for (int v = 0; v < 4; ++v) {
      int gn = n0 + tx * 4 + v;
      if (gn >= N) continue;
      float r = acc[u][v] + bias[gn];
      if (relu) r = fmaxf(r, 0.f);
      C[gm * N + gn] = r;
    }
  }
}

// ---------------- theta mean/var reduction ----------------
__global__ __launch_bounds__(256) void theta_stats(const float* __restrict__ outb, float* __restrict__ tstat)
{
  int b = blockIdx.x;
  const float* th = outb + (size_t)b * NOUTF + NI;
  float s = 0.f, q = 0.f;
  for (int l = threadIdx.x; l < LLEN; l += 256) { float t = th[l]; s += t; q += t * t; }
  for (int off = 1; off < 64; off <<= 1) { s += __shfl_xor(s, off); q += __shfl_xor(q, off); }
  __shared__ float tmp[8];
  int w = threadIdx.x >> 6;
  if ((threadIdx.x & 63) == 0) { tmp[w] = s; tmp[4 + w] = q; }
  __syncthreads();
  if (threadIdx.x == 0) {
    atomicAdd(&tstat[0], tmp[0] + tmp[1] + tmp[2] + tmp[3]);
    atomicAdd(&tstat[1], tmp[4] + tmp[5] + tmp[6] + tmp[7]);
  }
}

// conv1 + bn1 folded: x1[c] = relu(a1[c]*theta + b1[c])
__global__ void finalize_conv1(const float* __restrict__ tstat, const float* __restrict__ cw1,
                               const float* __restrict__ g1, const float* __restrict__ be1,
                               float* __restrict__ a1, float* __restrict__ b1)
{
  int c = threadIdx.x;
  if (c >= 90) return;
  float mt = tstat[0] / (float)NBL;
  float vt = tstat[1] / (float)NBL - mt * mt;
  float w = cw1[c];
  float rs = rsqrtf(w * w * vt + EPSBN);
  float a = w * g1[c] * rs;
  a1[c] = a;
  b1[c] = be1[c] - a * mt;
}

// sum NPART partial copies, then fold BN
__global__ void finalize_bn_part(const float* __restrict__ Sp, const float* __restrict__ Qp,
                                 const float* __restrict__ g, const float* __restrict__ be,
                                 float* __restrict__ aP, float* __restrict__ bP)
{
  int c = blockIdx.x * blockDim.x + threadIdx.x;
  if (c >= 180) return;
  float s = 0.f, q = 0.f;
  for (int p = 0; p < NPART; ++p) { s += Sp[p * 180 + c]; q += Qp[p * 180 + c]; }
  float m = s / (float)NBL;
  float v = q / (float)NBL - m * m;
  float a = g[c] * rsqrtf(v + EPSBN);
  aP[c] = a;
  bP[c] = be[c] - m * a;
}

// thread map shared by conv kernels: TX=col group (16), TY=row (16), rows r=TY+16u (u<12), cols j=TX*4+v
// ---------------- conv2 stats-only: y2 = cw2 @ relu(a1*theta+b1), accumulate per-channel stats ----
__global__ __launch_bounds__(256) void conv2_stats(
    const float* __restrict__ OUTB, const float* __restrict__ a1, const float* __restrict__ b1,
    const float* __restrict__ cw2, const float* __restrict__ cb2,
    float* __restrict__ Sp, float* __restrict__ Qp)
{
  __shared__ float xbuf[90][68];
  __shared__ float wt[16][192];
  const int tid = threadIdx.x;
  const int TX = tid & 15, TY = tid >> 4;
  const int b = blockIdx.y, j0 = blockIdx.x * 64;
  for (int i = tid; i < 90 * 64; i += 256) {
    int c = i >> 6, j = i & 63;
    int jj = j0 + j;
    float th = (jj < LLEN) ? OUTB[(size_t)b * NOUTF + NI + jj] : 0.f;
    xbuf[c][j] = fmaxf(fmaf(a1[c], th, b1[c]), 0.f);
  }
  __syncthreads();
  float acc[12][4] = {};
  for (int kc = 0; kc < 90; kc += 16) {
    for (int i = tid; i < 16 * 192; i += 256) {
      int k = i / 192, o = i - k * 192;
      int gk = kc + k;
      wt[k][o] = (gk < 90 && o < 180) ? cw2[o * 90 + gk] : 0.f;
    }
    __syncthreads();
    int kmax = (90 - kc) < 16 ? (90 - kc) : 16;
    for (int k = 0; k < kmax; ++k) {
      float4 xv = *reinterpret_cast<const float4*>(&xbuf[kc + k][TX * 4]);
#pragma unroll
      for (int u = 0; u < 12; ++u) {
        float w = wt[k][TY + 16 * u];
        acc[u][0] = fmaf(w, xv.x, acc[u][0]);
        acc[u][1] = fmaf(w, xv.y, acc[u][1]);
        acc[u][2] = fmaf(w, xv.z, acc[u][2]);
        acc[u][3] = fmaf(w, xv.w, acc[u][3]);
      }
    }
    __syncthreads();
  }
  int part = (blockIdx.y * gridDim.x + blockIdx.x) & (NPART - 1);
  float rsum[12] = {}, rsq[12] = {};
#pragma unroll
  for (int u = 0; u < 12; ++u) {
    int r = TY + 16 * u;
    if (r < 180) {
      float cb = cb2[r];
#pragma unroll
      for (int v = 0; v < 4; ++v) {
        int jj = j0 + TX * 4 + v;
        if (jj < LLEN) {
          float val = acc[u][v] + cb;
          rsum[u] += val;
          rsq[u] += val * val;
        }
      }
    }
  }
#pragma unroll
  for (int u = 0; u < 12; ++u)
#pragma unroll
    for (int off = 1; off < 16; off <<= 1) {
      rsum[u] += __shfl_xor(rsum[u], off);
      rsq[u] += __shfl_xor(rsq[u], off);
    }
  if (TX == 0) {
#pragma unroll
    for (int u = 0; u < 12; ++u) {
      int r = TY + 16 * u;
      if (r < 180) {
        atomicAdd(&Sp[part * 180 + r], rsum[u]);
        atomicAdd(&Qp[part * 180 + r], rsq[u]);
      }
    }
  }
}

// ---------------- fused conv2 -> bn2 -> relu -> conv3, write y3 (bf16) + stats3 ----------------
__global__ __launch_bounds__(256) void fused_conv23(
    const float* __restrict__ OUTB, const float* __restrict__ a1, const float* __restrict__ b1,
    const float* __restrict__ cw2, const float* __restrict__ cb2,
    const float* __restrict__ a2, const float* __restrict__ b2,
    const float* __restrict__ cw3, const float* __restrict__ cb3,
    __hip_bfloat16* __restrict__ Y, float* __restrict__ Sp, float* __restrict__ Qp)
{
  __shared__ float xbuf[192][68];
  __shared__ float wt[16][192];
  const int tid = threadIdx.x;
  const int TX = tid & 15, TY = tid >> 4;
  const int b = blockIdx.y, j0 = blockIdx.x * 64;
  // stage 1: x1 = relu(a1*theta+b1) into rows 0..89
  for (int i = tid; i < 90 * 64; i += 256) {
    int c = i >> 6, j = i & 63;
    int jj = j0 + j;
    float th = (jj < LLEN) ? OUTB[(size_t)b * NOUTF + NI + jj] : 0.f;
    xbuf[c][j] = fmaxf(fmaf(a1[c], th, b1[c]), 0.f);
  }
  __syncthreads();
  float acc[12][4] = {};
  for (int kc = 0; kc < 90; kc += 16) {
    for (int i = tid; i < 16 * 192; i += 256) {
      int k = i / 192, o = i - k * 192;
      int gk = kc + k;
      wt[k][o] = (gk < 90 && o < 180) ? cw2[o * 90 + gk] : 0.f;
    }
    __syncthreads();
    int kmax = (90 - kc) < 16 ? (90 - kc) : 16;
    for (int k = 0; k < kmax; ++k) {
      float4 xv = *reinterpret_cast<const float4*>(&xbuf[kc + k][TX * 4]);
#pragma unroll
      for (int u = 0; u < 12; ++u) {
        float w = wt[k][TY + 16 * u];
        acc[u][0] = fmaf(w, xv.x, acc[u][0]);
        acc[u][1] = fmaf(w, xv.y, acc[u][1]);
        acc[u][2] = fmaf(w, xv.z, acc[u][2]);
        acc[u][3] = fmaf(w, xv.w, acc[u][3]);
      }
    }
    __syncthreads();
  }
  // x2 = relu(a2*(y2)+b2) into rows 0..191 (rows >=180 zeroed)
#pragma unroll
  for (int u = 0; u < 12; ++u) {
    int r = TY + 16 * u;
    float a2r = (r < 180) ? a2[r] : 0.f;
    float b2r = (r < 180) ? b2[r] : 0.f;
    float cb = (r < 180) ? cb2[r] : 0.f;
#pragma unroll
    for (int v = 0; v < 4; ++v) {
      float y2 = acc[u][v] + cb;
      xbuf[r][TX * 4 + v] = fmaxf(fmaf(a2r, y2, b2r), 0.f);
    }
  }
  __syncthreads();
  // stage 2: y3 = cw3 @ x2
  float acc2[12][4] = {};
  for (int kc = 0; kc < 180; kc += 16) {
    for (int i = tid; i < 16 * 192; i += 256) {
      int k = i / 192, o = i - k * 192;
      int gk = kc + k;
      wt[k][o] = (gk < 180 && o < 180) ? cw3[o * 180 + gk] : 0.f;
    }
    __syncthreads();
    int kmax = (180 - kc) < 16 ? (180 - kc) : 16;
    for (int k = 0; k < kmax; ++k) {
      float4 xv = *reinterpret_cast<const float4*>(&xbuf[kc + k][TX * 4]);
#pragma unroll
      for (int u = 0; u < 12; ++u) {
        float w = wt[k][TY + 16 * u];
        acc2[u][0] = fmaf(w, xv.x, acc2[u][0]);
        acc2[u][1] = fmaf(w, xv.y, acc2[u][1]);
        acc2[u][2] = fmaf(w, xv.z, acc2[u][2]);
        acc2[u][3] = fmaf(w, xv.w, acc2[u][3]);
      }
    }
    __syncthreads();
  }
  int part = (blockIdx.y * gridDim.x + blockIdx.x) & (NPART - 1);
  float rsum[12] = {}, rsq[12] = {};
#pragma unroll
  for (int u = 0; u < 12; ++u) {
    int r = TY + 16 * u;
    if (r < 180) {
      float cb = cb3[r];
#pragma unroll
      for (int v = 0; v < 4; ++v) {
        int jj = j0 + TX * 4 + v;
        if (jj < LLEN) {
          float val = acc2[u][v] + cb;
          Y[((size_t)b * 180 + r) * LLEN + jj] = __float2bfloat16(val);
          rsum[u] += val;
          rsq[u] += val * val;
        }
      }
    }
  }
#pragma unroll
  for (int u = 0; u < 12; ++u)
#pragma unroll
    for (int off = 1; off < 16; off <<= 1) {
      rsum[u] += __shfl_xor(rsum[u], off);
      rsq[u] += __shfl_xor(rsq[u], off);
    }
  if (TX == 0) {
#pragma unroll
    for (int u = 0; u < 12; ++u) {
      int r = TY + 16 * u;
      if (r < 180) {
        atomicAdd(&Sp[part * 180 + r], rsum[u]);
        atomicAdd(&Qp[part * 180 + r], rsq[u]);
      }
    }
  }
}

// ---------------- conv4 in place on Y: x3 = relu(a3*y3+b3); y4 = cw4 @ x3 ----------------
__global__ __launch_bounds__(256) void conv4_inplace(
    __hip_bfloat16* __restrict__ Y, const float* __restrict__ a3, const float* __restrict__ b3,
    const float* __restrict__ cw4, const float* __restrict__ cb4,
    float* __restrict__ Sp, float* __restrict__ Qp)
{
  __shared__ float xbuf[180][68];
  __shared__ float wt[16][192];
  const int tid = threadIdx.x;
  const int TX = tid & 15, TY = tid >> 4;
  const int b = blockIdx.y, j0 = blockIdx.x * 64;
  for (int i = tid; i < 180 * 64; i += 256) {
    int c = i >> 6, j = i & 63;
    int jj = j0 + j;
    float v = 0.f;
    if (jj < LLEN) {
      float raw = __bfloat162float(Y[((size_t)b * 180 + c) * LLEN + jj]);
      v = fmaxf(fmaf(a3[c], raw, b3[c]), 0.f);
    }
    xbuf[c][j] = v;
  }
  __syncthreads();  // all reads of the slab done; safe to overwrite later
  float acc[12][4] = {};
  for (int kc = 0; kc < 180; kc += 16) {
    for (int i = tid; i < 16 * 192; i += 256) {
      int k = i / 192, o = i - k * 192;
      int gk = kc + k;
      wt[k][o] = (gk < 180 && o < 180) ? cw4[o * 180 + gk] : 0.f;
    }
    __syncthreads();
    int kmax = (180 - kc) < 16 ? (180 - kc) : 16;
    for (int k = 0; k < kmax; ++k) {
      float4 xv = *reinterpret_cast<const float4*>(&xbuf[kc + k][TX * 4]);
#pragma unroll
      for (int u = 0; u < 12; ++u) {
        float w = wt[k][TY + 16 * u];
        acc[u][0] = fmaf(w, xv.x, acc[u][0]);
        acc[u][1] = fmaf(w, xv.y, acc[u][1]);
        acc[u][2] = fmaf(w, xv.z, acc[u][2]);
        acc[u][3] = fmaf(w, xv.w, acc[u][3]);
      }
    }
    __syncthreads();
  }
  int part = (blockIdx.y * gridDim.x + blockIdx.x) & (NPART - 1);
  float rsum[12] = {}, rsq[12] = {};
#pragma unroll
  for (int u = 0; u < 12; ++u) {
    int r = TY + 16 * u;
    if (r < 180) {
      float cb = cb4[r];
#pragma unroll
      for (int v = 0; v < 4; ++v) {
        int jj = j0 + TX * 4 + v;
        if (jj < LLEN) {
          float val = acc[u][v] + cb;
          Y[((size_t)b * 180 + r) * LLEN + jj] = __float2bfloat16(val);
          rsum[u] += val;
          rsq[u] += val * val;
        }
      }
    }
  }
#pragma unroll
  for (int u = 0; u < 12; ++u)
#pragma unroll
    for (int off = 1; off < 16; off <<= 1) {
      rsum[u] += __shfl_xor(rsum[u], off);
      rsq[u] += __shfl_xor(rsq[u], off);
    }
  if (TX == 0) {
#pragma unroll
    for (int u = 0; u < 12; ++u) {
      int r = TY + 16 * u;
      if (r < 180) {
        atomicAdd(&Sp[part * 180 + r], rsum[u]);
        atomicAdd(&Qp[part * 180 + r], rsq[u]);
      }
    }
  }
}

// ---------------- conv5 + log_softmax + NLL gather, fused ----------------
__global__ __launch_bounds__(256) void conv5_nll(
    const __hip_bfloat16* __restrict__ Y4, const float* __restrict__ a4, const float* __restrict__ b4,
    const float* __restrict__ cw5, const float* __restrict__ cb5,
    const float* __restrict__ inputs, float* __restrict__ nll)
{
  __shared__ float lds[320 * 33];  // union: {wsd[20][324] + xs[20][36]} then pt[320][33]
  float* wsd = lds;
  float* xs = lds + 20 * 324;
  const int tid = threadIdx.x;
  const int rg = tid & 63, cg = tid >> 6;
  const int b = blockIdx.y;
  const int l0 = blockIdx.x * 32;
  float acc[5][8] = {};
  for (int kc = 0; kc < 180; kc += 20) {
    for (int i = tid; i < 320 * 20; i += 256) {
      int o = i / 20, k = i - o * 20;
      wsd[k * 324 + o] = (o < 300) ? cw5[o * 180 + kc + k] : 0.f;
    }
    for (int i = tid; i < 20 * 32; i += 256) {
      int j = i & 31, k = i >> 5;
      int c = kc + k, jj = l0 + j;
      float v = 0.f;
      if (jj < LLEN) {
        float raw = __bfloat162float(Y4[((size_t)b * 180 + c) * LLEN + jj]);
        v = fmaxf(fmaf(a4[c], raw, b4[c]), 0.f);
      }
      xs[k * 36 + j] = v;
    }
    __syncthreads();
#pragma unroll
    for (int k = 0; k < 20; ++k) {
      float xv[8], wv[5];
#pragma unroll
      for (int v = 0; v < 8; ++v) xv[v] = xs[k * 36 + cg * 8 + v];
#pragma unroll
      for (int u = 0; u < 5; ++u) wv[u] = wsd[k * 324 + rg + 64 * u];
#pragma unroll
      for (int u = 0; u < 5; ++u)
#pragma unroll
        for (int v = 0; v < 8; ++v) acc[u][v] = fmaf(wv[u], xv[v], acc[u][v]);
    }
    __syncthreads();
  }
  float* pt = lds;
#pragma unroll
  for (int u = 0; u < 5; ++u) {
    int r = rg + 64 * u;
    float bi = (r < 300) ? cb5[r] : 0.f;
#pragma unroll
    for (int v = 0; v < 8; ++v) {
      int col = cg * 8 + v;
      pt[r * 33 + col] = (r < 300) ? (acc[u][v] + bi) : -1e30f;
    }
  }
  __syncthreads();
  int col = tid >> 3, sub = tid & 7;
  int jj = l0 + col;
  if (jj < LLEN) {
    float mx = -1e30f;
    for (int r = sub; r < 300; r += 8) mx = fmaxf(mx, pt[r * 33 + col]);
    for (int off = 1; off < 8; off <<= 1) mx = fmaxf(mx, __shfl_xor(mx, off));
    float sm = 0.f;
    for (int r = sub; r < 300; r += 8) sm += expf(pt[r * 33 + col] - mx);
    for (int off = 1; off < 8; off <<= 1) sm += __shfl_xor(sm, off);
    if (sub == 0) {
      float lse = mx + logf(sm);
      int tgt = (int)inputs[(size_t)b * NI + jj];
      nll[(size_t)b * LLEN + jj] = lse - pt[tgt * 33 + col];
    }
  }
}

// ---------------- final log-likelihood assembly ----------------
__global__ __launch_bounds__(256) void ll_pass1(
    const float* __restrict__ outb, const float* __restrict__ nll,
    const float* __restrict__ inputs, float* __restrict__ llp, float* __restrict__ sc)
{
  int b = blockIdx.x;
  float s = 0.f;
  for (int l = 2 + (int)threadIdx.x; l < LLEN; l += 256) {
    float graw = outb[(size_t)b * NOUTF + l];
    float sg = 1.f / (1.f + expf(-graw));
    float term;
    if (inputs[(size_t)b * NI + l] > 0.f)
      term = 0.1f * logf(sg + 1e-10f) - nll[(size_t)b * LLEN + l];
    else
      term = 0.1f * logf(1.f - sg + 1e-10f);
    s += term;
  }
  for (int off = 1; off < 64; off <<= 1) s += __shfl_xor(s, off);
  __shared__ float tmp[4];
  if ((threadIdx.x & 63) == 0) tmp[threadIdx.x >> 6] = s;
  __syncthreads();
  if (threadIdx.x == 0) {
    llp[b] = tmp[0] + tmp[1] + tmp[2] + tmp[3];
    atomicAdd(sc, nll[(size_t)b * LLEN] + nll[(size_t)b * LLEN + 1]);
  }
}

__global__ void ll_pass2(const float* __restrict__ llp, const float* __restrict__ sc, float* __restrict__ outp)
{
  int i = blockIdx.x * blockDim.x + threadIdx.x;
  if (i < BATCH) outp[i] = llp[i] - sc[0] * (1.f / 1024.f);
}

extern "C" void kernel_launch(void* const* d_in, const int* in_sizes, int n_in,
                              void* d_out, int out_size, void* d_ws, size_t ws_size,
                              hipStream_t stream)
{
  const float* inputs = (const float*)d_in[0];
  const float* W_in = (const float*)d_in[1];
  const float* b_in = (const float*)d_in[2];
  const float* W_h1 = (const float*)d_in[3];
  const float* b_h1 = (const float*)d_in[4];
  const float* W_h2 = (const float*)d_in[5];
  const float* b_h2 = (const float*)d_in[6];
  const float* W_out = (const float*)d_in[7];
  const float* b_out = (const float*)d_in[8];
  const float* cw1 = (const float*)d_in[9];
  const float* cb1 = (const float*)d_in[10];  (void)cb1;  // cancels in BN fold
  const float* g1 = (const float*)d_in[11];
  const float* be1 = (const float*)d_in[12];
  const float* cw2 = (const float*)d_in[13];
  const float* cb2 = (const float*)d_in[14];
  const float* g2 = (const float*)d_in[15];
  const float* be2 = (const float*)d_in[16];
  const float* cw3 = (const float*)d_in[17];
  const float* cb3 = (const float*)d_in[18];
  const float* g3 = (const float*)d_in[19];
  const float* be3 = (const float*)d_in[20];
  const float* cw4 = (const float*)d_in[21];
  const float* cb4 = (const float*)d_in[22];
  const float* g4 = (const float*)d_in[23];
  const float* be4 = (const float*)d_in[24];
  const float* cw5 = (const float*)d_in[25];
  const float* cb5 = (const float*)d_in[26];

  // workspace layout: Y (bf16) first, then fp32 region
  __hip_bfloat16* Y = (__hip_bfloat16*)d_ws;                 // 512*180*627 bf16 = 115.6 MB
  float* ws = (float*)((char*)d_ws + (size_t)BATCH * 180 * LLEN * sizeof(__hip_bfloat16));
  size_t off = 0;
  float* OUTB = ws + off; off += (size_t)BATCH * NOUTF;
  float* H1 = ws + off; off += (size_t)BATCH * NH;
  float* H2 = ws + off; off += (size_t)BATCH * NH;
  float* H3 = ws + off; off += (size_t)BATCH * NH;
  float* NLLB = ws + off; off += (size_t)BATCH * LLEN;
  float* LLP = ws + off; off += BATCH;
  float* A1 = ws + off; off += 90;  float* B1 = ws + off; off += 90;
  float* A2 = ws + off; off += 180; float* B2 = ws + off; off += 180;
  float* A3 = ws + off; off += 180; float* B3 = ws + off; off += 180;
  float* A4 = ws + off; off += 180; float* B4 = ws + off; off += 180;
  float* STAT = ws + off;
  float* TST = STAT;                 // 2
  float* SC = STAT + 2;              // 1
  float* S2P = STAT + 3;             float* Q2P = S2P + NPART * 180;
  float* S3P = Q2P + NPART * 180;    float* Q3P = S3P + NPART * 180;
  float* S4P = Q3P + NPART * 180;    float* Q4P = S4P + NPART * 180;
  size_t statN = 3 + 6 * (size_t)NPART * 180;

  hipMemsetAsync(STAT, 0, statN * sizeof(float), stream);

  // masked MLP
  mlp_gemm<<<dim3(16, 8), 256, 0, stream>>>(inputs, W_in, b_in, H1, BATCH, NH, NI, 0, 1);
  mlp_gemm<<<dim3(16, 8), 256, 0, stream>>>(H1, W_h1, b_h1, H2, BATCH, NH, NH, 1, 1);
  mlp_gemm<<<dim3(16, 8), 256, 0, stream>>>(H2, W_h2, b_h2, H3, BATCH, NH, NH, 1, 0);
  mlp_gemm<<<dim3(20, 8), 256, 0, stream>>>(H3, W_out, b_out, OUTB, BATCH, NOUTF, NH, 2, 0);

  // conv1+bn1 folded via theta stats
  theta_stats<<<dim3(BATCH), 256, 0, stream>>>(OUTB, TST);
  finalize_conv1<<<1, 128, 0, stream>>>(TST, cw1, g1, be1, A1, B1);

  // conv2 stats (no store), then fused conv2->conv3 -> Y (y3)
  conv2_stats<<<dim3(10, BATCH), 256, 0, stream>>>(OUTB, A1, B1, cw2, cb2, S2P, Q2P);
  finalize_bn_part<<<1, 256, 0, stream>>>(S2P, Q2P, g2, be2, A2, B2);
  fused_conv23<<<dim3(10, BATCH), 256, 0, stream>>>(OUTB, A1, B1, cw2, cb2, A2, B2, cw3, cb3, Y, S3P, Q3P);
  finalize_bn_part<<<1, 256, 0, stream>>>(S3P, Q3P, g3, be3, A3, B3);

  // conv4 in place on Y
  conv4_inplace<<<dim3(10, BATCH), 256, 0, stream>>>(Y, A3, B3, cw4, cb4, S4P, Q4P);
  finalize_bn_part<<<1, 256, 0, stream>>>(S4P, Q4P, g4, be4, A4, B4);

  // conv5 + log_softmax + nll
  conv5_nll<<<dim3(20, BATCH), 256, 0, stream>>>(Y, A4, B4, cw5, cb5, inputs, NLLB);

  // final assembly
  ll_pass1<<<dim3(BATCH), 256, 0, stream>>>(OUTB, NLLB, inputs, LLP, SC);
  ll_pass2<<<dim3(2), 256, 0, stream>>>(LLP, SC, (float*)d_out);
}

// Round 3
// 915.246 us; speedup vs baseline: 4.3156x; 4.3156x over previous
//
#include <hip/hip_runtime.h>
#include <math.h>

#define BATCH 512
#define NI 627
#define NH 1024
#define NOUTF 1254
#define LLEN 627
#define NBL (512 * 627)
#define EPSBN 1e-5f
#define NPART 64

typedef __attribute__((ext_vector_type(8))) short bf16x8;
typedef __attribute__((ext_vector_type(4))) float f32x4;
typedef unsigned int uint32;
typedef unsigned short ushort16;

__device__ inline short f2b(float x) {
  uint32 u = __float_as_uint(x);
  uint32 r = (u + 0x7fffu + ((u >> 16) & 1u)) >> 16;
  return (short)r;
}
__device__ inline float b2f(short s) {
  return __uint_as_float(((uint32)(ushort16)s) << 16);
}
__device__ inline f32x4 mfma16(bf16x8 a, bf16x8 b, f32x4 c) {
  return __builtin_amdgcn_mfma_f32_16x16x32_bf16(a, b, c, 0, 0, 0);
}

// ================= prep kernels =================
__global__ __launch_bounds__(256) void prep_inputs(const float* __restrict__ in, short* __restrict__ outp) {
  int i = blockIdx.x * 256 + threadIdx.x;
  if (i >= 512 * 640) return;
  int m = i / 640, k = i - m * 640;
  outp[i] = (k < NI) ? f2b(in[m * NI + k]) : (short)0;
}

__global__ __launch_bounds__(256) void prep_mlpw(const float* __restrict__ W, short* __restrict__ Wb,
                                                 int Nreal, int Kreal, int Npad, int Kpad, int mode) {
  int i = blockIdx.x * 256 + threadIdx.x;
  if (i >= Npad * Kpad) return;
  int n = i / Kpad, k = i - n * Kpad;
  float w = 0.f;
  if (n < Nreal && k < Kreal) {
    int od = n >= 627 ? n - 627 : n;
    int kd = k >= 627 ? k - 627 : k;
    bool keep = (mode == 0) ? (od >= k) : (mode == 1) ? (od >= kd) : (od > kd);
    if (keep) w = W[n * Kreal + k];
  }
  Wb[i] = f2b(w);
}

__global__ __launch_bounds__(256) void prep_convw(const float* __restrict__ W, short* __restrict__ Wb,
                                                  int Oreal, int Kreal, int Opad, int Kpad) {
  int i = blockIdx.x * 256 + threadIdx.x;
  if (i >= Opad * Kpad) return;
  int o = i / Kpad, k = i - o * Kpad;
  Wb[i] = (o < Oreal && k < Kreal) ? f2b(W[o * Kreal + k]) : (short)0;
}

__global__ void prep_cb(const float* __restrict__ cb2, const float* __restrict__ cb3,
                        const float* __restrict__ cb4, const float* __restrict__ cb5,
                        float* __restrict__ cb2p, float* __restrict__ cb3p,
                        float* __restrict__ cb4p, float* __restrict__ cb5p) {
  int c = threadIdx.x;  // 320 threads
  if (c < 192) {
    cb2p[c] = (c < 180) ? cb2[c] : 0.f;
    cb3p[c] = (c < 180) ? cb3[c] : 0.f;
    cb4p[c] = (c < 180) ? cb4[c] : 0.f;
  }
  if (c < 320) cb5p[c] = (c < 300) ? cb5[c] : 0.f;
}

// ================= MLP MFMA GEMM: C[M,Nreal] = act(A @ Wb^T + bias) =================
// A: bf16 [512][Kpad], Wb: bf16 [Npad][Kpad] (mask pre-applied)
__global__ __launch_bounds__(256) void mlp_mfma(
    const short* __restrict__ A, const short* __restrict__ Wb, const float* __restrict__ bias,
    float* __restrict__ Cf, short* __restrict__ Cb, int Nreal, int Kpad, int relu)
{
  const int l = threadIdx.x & 63, wv = threadIdx.x >> 6;
  const int wm = wv >> 1, wn = wv & 1;
  const int m0 = blockIdx.y * 64 + wm * 32;
  const int n0 = blockIdx.x * 64 + wn * 32;
  const int lr = l & 15, lk = (l >> 4) * 8, lm4 = (l >> 4) * 4;
  f32x4 acc[2][2] = {};
  const int nk = Kpad >> 5;
  for (int ks = 0; ks < nk; ++ks) {
    int k0 = ks * 32 + lk;
    bf16x8 a0 = *reinterpret_cast<const bf16x8*>(&A[(size_t)(m0 + lr) * Kpad + k0]);
    bf16x8 a1 = *reinterpret_cast<const bf16x8*>(&A[(size_t)(m0 + 16 + lr) * Kpad + k0]);
    bf16x8 b0 = *reinterpret_cast<const bf16x8*>(&Wb[(size_t)(n0 + lr) * Kpad + k0]);
    bf16x8 b1 = *reinterpret_cast<const bf16x8*>(&Wb[(size_t)(n0 + 16 + lr) * Kpad + k0]);
    acc[0][0] = mfma16(a0, b0, acc[0][0]);
    acc[0][1] = mfma16(a0, b1, acc[0][1]);
    acc[1][0] = mfma16(a1, b0, acc[1][0]);
    acc[1][1] = mfma16(a1, b1, acc[1][1]);
  }
#pragma unroll
  for (int mi = 0; mi < 2; ++mi)
#pragma unroll
    for (int nj = 0; nj < 2; ++nj) {
      int n = n0 + nj * 16 + lr;
      if (n >= Nreal) continue;
      float bi = bias[n];
#pragma unroll
      for (int r = 0; r < 4; ++r) {
        int m = m0 + mi * 16 + lm4 + r;
        float v = acc[mi][nj][r] + bi;
        if (relu) v = fmaxf(v, 0.f);
        if (Cb) Cb[(size_t)m * Nreal + n] = f2b(v);
        else Cf[(size_t)m * Nreal + n] = v;
      }
    }
}

// ================= theta stats =================
__global__ __launch_bounds__(256) void theta_stats(const float* __restrict__ outb, float* __restrict__ tstat)
{
  int b = blockIdx.x;
  const float* th = outb + (size_t)b * NOUTF + NI;
  float s = 0.f, q = 0.f;
  for (int l = threadIdx.x; l < LLEN; l += 256) { float t = th[l]; s += t; q += t * t; }
  for (int off = 1; off < 64; off <<= 1) { s += __shfl_xor(s, off); q += __shfl_xor(q, off); }
  __shared__ float tmp[8];
  int w = threadIdx.x >> 6;
  if ((threadIdx.x & 63) == 0) { tmp[w] = s; tmp[4 + w] = q; }
  __syncthreads();
  if (threadIdx.x == 0) {
    atomicAdd(&tstat[0], tmp[0] + tmp[1] + tmp[2] + tmp[3]);
    atomicAdd(&tstat[1], tmp[4] + tmp[5] + tmp[6] + tmp[7]);
  }
}

__global__ void finalize_conv1(const float* __restrict__ tstat, const float* __restrict__ cw1,
                               const float* __restrict__ g1, const float* __restrict__ be1,
                               float* __restrict__ a1, float* __restrict__ b1)
{
  int c = threadIdx.x;  // 96
  if (c >= 96) return;
  if (c < 90) {
    float mt = tstat[0] / (float)NBL;
    float vt = tstat[1] / (float)NBL - mt * mt;
    float w = cw1[c];
    float rs = rsqrtf(w * w * vt + EPSBN);
    float a = w * g1[c] * rs;
    a1[c] = a;
    b1[c] = be1[c] - a * mt;
  } else { a1[c] = 0.f; b1[c] = 0.f; }
}

__global__ void finalize_bn_part(const float* __restrict__ Sp, const float* __restrict__ Qp,
                                 const float* __restrict__ g, const float* __restrict__ be,
                                 float* __restrict__ aP, float* __restrict__ bP)
{
  int c = threadIdx.x;  // 192
  if (c >= 192) return;
  if (c < 180) {
    float s = 0.f, q = 0.f;
    for (int p = 0; p < NPART; ++p) { s += Sp[p * 180 + c]; q += Qp[p * 180 + c]; }
    float m = s / (float)NBL;
    float v = q / (float)NBL - m * m;
    float a = g[c] * rsqrtf(v + EPSBN);
    aP[c] = a;
    bP[c] = be[c] - m * a;
  } else { aP[c] = 0.f; bP[c] = 0.f; }
}

// ================= conv2 stats-only (MFMA) =================
__global__ __launch_bounds__(256) void conv2_stats(
    const float* __restrict__ OUTB, const float* __restrict__ a1, const float* __restrict__ b1,
    const short* __restrict__ cw2b, const float* __restrict__ cb2p,
    float* __restrict__ Sp, float* __restrict__ Qp)
{
  __shared__ float th[64];
  __shared__ float ab[192];
  __shared__ short xT[64][104];
  const int tid = threadIdx.x;
  const int b = blockIdx.y, j0 = blockIdx.x * 64;
  if (tid < 64) {
    int jj = j0 + tid;
    th[tid] = (jj < LLEN) ? OUTB[(size_t)b * NOUTF + NI + jj] : 0.f;
  }
  if (tid < 96) ab[tid] = a1[tid];
  else if (tid < 192) ab[tid] = b1[tid - 96];
  __syncthreads();
  for (int t = tid; t < 64 * 12; t += 256) {
    int col = t / 12, oct = t - col * 12;
    float tv = th[col];
    int c0 = oct * 8;
    bf16x8 pk;
#pragma unroll
    for (int i = 0; i < 8; ++i)
      pk[i] = f2b(fmaxf(fmaf(ab[c0 + i], tv, ab[96 + c0 + i]), 0.f));
    *reinterpret_cast<bf16x8*>(&xT[col][c0]) = pk;
  }
  __syncthreads();
  const int l = tid & 63, wv = tid >> 6, wm = wv >> 1, wn = wv & 1;
  const int lr = l & 15, lk = (l >> 4) * 8, lm4 = (l >> 4) * 4;
  f32x4 acc[6][2] = {};
#pragma unroll
  for (int ks = 0; ks < 3; ++ks) {
    int k0 = ks * 32 + lk;
    bf16x8 b0 = *reinterpret_cast<const bf16x8*>(&xT[wn * 32 + lr][k0]);
    bf16x8 b1 = *reinterpret_cast<const bf16x8*>(&xT[wn * 32 + 16 + lr][k0]);
#pragma unroll
    for (int mi = 0; mi < 6; ++mi) {
      bf16x8 av = *reinterpret_cast<const bf16x8*>(&cw2b[(wm * 96 + mi * 16 + lr) * 96 + k0]);
      acc[mi][0] = mfma16(av, b0, acc[mi][0]);
      acc[mi][1] = mfma16(av, b1, acc[mi][1]);
    }
  }
  int part = (blockIdx.y * gridDim.x + blockIdx.x) & (NPART - 1);
#pragma unroll
  for (int mi = 0; mi < 6; ++mi) {
    int m0c = wm * 96 + mi * 16 + lm4;
    float s4[4] = {0.f, 0.f, 0.f, 0.f}, q4[4] = {0.f, 0.f, 0.f, 0.f};
#pragma unroll
    for (int nj = 0; nj < 2; ++nj) {
      int jj = j0 + wn * 32 + nj * 16 + lr;
      if (jj < LLEN) {
#pragma unroll
        for (int r = 0; r < 4; ++r) {
          float v = acc[mi][nj][r] + cb2p[m0c + r];
          s4[r] += v; q4[r] += v * v;
        }
      }
    }
#pragma unroll
    for (int off = 1; off < 16; off <<= 1)
#pragma unroll
      for (int r = 0; r < 4; ++r) { s4[r] += __shfl_xor(s4[r], off); q4[r] += __shfl_xor(q4[r], off); }
    if (lr == 0) {
#pragma unroll
      for (int r = 0; r < 4; ++r) {
        int o = m0c + r;
        if (o < 180) {
          atomicAdd(&Sp[part * 180 + o], s4[r]);
          atomicAdd(&Qp[part * 180 + o], q4[r]);
        }
      }
    }
  }
}

// ================= fused conv2 -> bn2 -> relu -> conv3 (MFMA), write Y + stats3 =================
__global__ __launch_bounds__(256) void fused_conv23(
    const float* __restrict__ OUTB, const float* __restrict__ a1, const float* __restrict__ b1,
    const short* __restrict__ cw2b, const float* __restrict__ cb2p,
    const float* __restrict__ a2, const float* __restrict__ b2,
    const short* __restrict__ cw3b, const float* __restrict__ cb3p,
    short* __restrict__ Y, float* __restrict__ Sp, float* __restrict__ Qp)
{
  __shared__ float th[64];
  __shared__ float ab[192];
  __shared__ short xT1[64][104];
  __shared__ short xT2[64][200];
  const int tid = threadIdx.x;
  const int b = blockIdx.y, j0 = blockIdx.x * 64;
  if (tid < 64) {
    int jj = j0 + tid;
    th[tid] = (jj < LLEN) ? OUTB[(size_t)b * NOUTF + NI + jj] : 0.f;
  }
  if (tid < 96) ab[tid] = a1[tid];
  else if (tid < 192) ab[tid] = b1[tid - 96];
  __syncthreads();
  for (int t = tid; t < 64 * 12; t += 256) {
    int col = t / 12, oct = t - col * 12;
    float tv = th[col];
    int c0 = oct * 8;
    bf16x8 pk;
#pragma unroll
    for (int i = 0; i < 8; ++i)
      pk[i] = f2b(fmaxf(fmaf(ab[c0 + i], tv, ab[96 + c0 + i]), 0.f));
    *reinterpret_cast<bf16x8*>(&xT1[col][c0]) = pk;
  }
  __syncthreads();
  const int l = tid & 63, wv = tid >> 6, wm = wv >> 1, wn = wv & 1;
  const int lr = l & 15, lk = (l >> 4) * 8, lm4 = (l >> 4) * 4;
  // conv2
  f32x4 acc[6][2] = {};
#pragma unroll
  for (int ks = 0; ks < 3; ++ks) {
    int k0 = ks * 32 + lk;
    bf16x8 b0 = *reinterpret_cast<const bf16x8*>(&xT1[wn * 32 + lr][k0]);
    bf16x8 b1 = *reinterpret_cast<const bf16x8*>(&xT1[wn * 32 + 16 + lr][k0]);
#pragma unroll
    for (int mi = 0; mi < 6; ++mi) {
      bf16x8 av = *reinterpret_cast<const bf16x8*>(&cw2b[(wm * 96 + mi * 16 + lr) * 96 + k0]);
      acc[mi][0] = mfma16(av, b0, acc[mi][0]);
      acc[mi][1] = mfma16(av, b1, acc[mi][1]);
    }
  }
  // x2 = relu(a2*(y2+cb2)+b2) -> xT2
#pragma unroll
  for (int mi = 0; mi < 6; ++mi) {
    int m0c = wm * 96 + mi * 16 + lm4;
#pragma unroll
    for (int nj = 0; nj < 2; ++nj) {
      int col = wn * 32 + nj * 16 + lr;
      uint32 lo, hi;
      {
        float y0 = acc[mi][nj][0] + cb2p[m0c + 0];
        float y1 = acc[mi][nj][1] + cb2p[m0c + 1];
        float x0 = fmaxf(fmaf(a2[m0c + 0], y0, b2[m0c + 0]), 0.f);
        float x1 = fmaxf(fmaf(a2[m0c + 1], y1, b2[m0c + 1]), 0.f);
        lo = (uint32)(ushort16)f2b(x0) | ((uint32)(ushort16)f2b(x1) << 16);
        float y2v = acc[mi][nj][2] + cb2p[m0c + 2];
        float y3v = acc[mi][nj][3] + cb2p[m0c + 3];
        float x2 = fmaxf(fmaf(a2[m0c + 2], y2v, b2[m0c + 2]), 0.f);
        float x3 = fmaxf(fmaf(a2[m0c + 3], y3v, b2[m0c + 3]), 0.f);
        hi = (uint32)(ushort16)f2b(x2) | ((uint32)(ushort16)f2b(x3) << 16);
      }
      uint2 w2; w2.x = lo; w2.y = hi;
      *reinterpret_cast<uint2*>(&xT2[col][m0c]) = w2;
    }
  }
  __syncthreads();
  // conv3
  f32x4 acc2[6][2] = {};
#pragma unroll
  for (int ks = 0; ks < 6; ++ks) {
    int k0 = ks * 32 + lk;
    bf16x8 b0 = *reinterpret_cast<const bf16x8*>(&xT2[wn * 32 + lr][k0]);
    bf16x8 b1 = *reinterpret_cast<const bf16x8*>(&xT2[wn * 32 + 16 + lr][k0]);
#pragma unroll
    for (int mi = 0; mi < 6; ++mi) {
      bf16x8 av = *reinterpret_cast<const bf16x8*>(&cw3b[(wm * 96 + mi * 16 + lr) * 192 + k0]);
      acc2[mi][0] = mfma16(av, b0, acc2[mi][0]);
      acc2[mi][1] = mfma16(av, b1, acc2[mi][1]);
    }
  }
  int part = (blockIdx.y * gridDim.x + blockIdx.x) & (NPART - 1);
#pragma unroll
  for (int mi = 0; mi < 6; ++mi) {
    int m0c = wm * 96 + mi * 16 + lm4;
    float s4[4] = {0.f, 0.f, 0.f, 0.f}, q4[4] = {0.f, 0.f, 0.f, 0.f};
#pragma unroll
    for (int nj = 0; nj < 2; ++nj) {
      int jj = j0 + wn * 32 + nj * 16 + lr;
      if (jj < LLEN) {
        float v0 = acc2[mi][nj][0] + cb3p[m0c + 0];
        float v1 = acc2[mi][nj][1] + cb3p[m0c + 1];
        float v2 = acc2[mi][nj][2] + cb3p[m0c + 2];
        float v3 = acc2[mi][nj][3] + cb3p[m0c + 3];
        s4[0] += v0; q4[0] += v0 * v0;
        s4[1] += v1; q4[1] += v1 * v1;
        s4[2] += v2; q4[2] += v2 * v2;
        s4[3] += v3; q4[3] += v3 * v3;
        uint2 w2;
        w2.x = (uint32)(ushort16)f2b(v0) | ((uint32)(ushort16)f2b(v1) << 16);
        w2.y = (uint32)(ushort16)f2b(v2) | ((uint32)(ushort16)f2b(v3) << 16);
        *reinterpret_cast<uint2*>(&Y[((size_t)b * 627 + jj) * 192 + m0c]) = w2;
      }
    }
#pragma unroll
    for (int off = 1; off < 16; off <<= 1)
#pragma unroll
      for (int r = 0; r < 4; ++r) { s4[r] += __shfl_xor(s4[r], off); q4[r] += __shfl_xor(q4[r], off); }
    if (lr == 0) {
#pragma unroll
      for (int r = 0; r < 4; ++r) {
        int o = m0c + r;
        if (o < 180) {
          atomicAdd(&Sp[part * 180 + o], s4[r]);
          atomicAdd(&Qp[part * 180 + o], q4[r]);
        }
      }
    }
  }
}

// ================= conv4 in place on Y (MFMA) =================
__global__ __launch_bounds__(256) void conv4_ip(
    short* __restrict__ Y, const float* __restrict__ a3, const float* __restrict__ b3,
    const short* __restrict__ cw4b, const float* __restrict__ cb4p,
    float* __restrict__ Sp, float* __restrict__ Qp)
{
  __shared__ float ab[384];
  __shared__ short xT[64][200];
  const int tid = threadIdx.x;
  const int b = blockIdx.y, j0 = blockIdx.x * 64;
  for (int t = tid; t < 384; t += 256) ab[t] = (t < 192) ? a3[t] : b3[t - 192];
  __syncthreads();
  for (int t = tid; t < 64 * 24; t += 256) {
    int col = t / 24, oct = t - col * 24;
    int jj = j0 + col;
    int c0 = oct * 8;
    bf16x8 pk;
    if (jj < LLEN) {
      bf16x8 raw = *reinterpret_cast<const bf16x8*>(&Y[((size_t)b * 627 + jj) * 192 + c0]);
#pragma unroll
      for (int i = 0; i < 8; ++i)
        pk[i] = f2b(fmaxf(fmaf(ab[c0 + i], b2f(raw[i]), ab[192 + c0 + i]), 0.f));
    } else {
#pragma unroll
      for (int i = 0; i < 8; ++i) pk[i] = 0;
    }
    *reinterpret_cast<bf16x8*>(&xT[col][c0]) = pk;
  }
  __syncthreads();
  const int l = tid & 63, wv = tid >> 6, wm = wv >> 1, wn = wv & 1;
  const int lr = l & 15, lk = (l >> 4) * 8, lm4 = (l >> 4) * 4;
  f32x4 acc[6][2] = {};
#pragma unroll
  for (int ks = 0; ks < 6; ++ks) {
    int k0 = ks * 32 + lk;
    bf16x8 b0 = *reinterpret_cast<const bf16x8*>(&xT[wn * 32 + lr][k0]);
    bf16x8 b1 = *reinterpret_cast<const bf16x8*>(&xT[wn * 32 + 16 + lr][k0]);
#pragma unroll
    for (int mi = 0; mi < 6; ++mi) {
      bf16x8 av = *reinterpret_cast<const bf16x8*>(&cw4b[(wm * 96 + mi * 16 + lr) * 192 + k0]);
      acc[mi][0] = mfma16(av, b0, acc[mi][0]);
      acc[mi][1] = mfma16(av, b1, acc[mi][1]);
    }
  }
  int part = (blockIdx.y * gridDim.x + blockIdx.x) & (NPART - 1);
#pragma unroll
  for (int mi = 0; mi < 6; ++mi) {
    int m0c = wm * 96 + mi * 16 + lm4;
    float s4[4] = {0.f, 0.f, 0.f, 0.f}, q4[4] = {0.f, 0.f, 0.f, 0.f};
#pragma unroll
    for (int nj = 0; nj < 2; ++nj) {
      int jj = j0 + wn * 32 + nj * 16 + lr;
      if (jj < LLEN) {
        float v0 = acc[mi][nj][0] + cb4p[m0c + 0];
        float v1 = acc[mi][nj][1] + cb4p[m0c + 1];
        float v2 = acc[mi][nj][2] + cb4p[m0c + 2];
        float v3 = acc[mi][nj][3] + cb4p[m0c + 3];
        s4[0] += v0; q4[0] += v0 * v0;
        s4[1] += v1; q4[1] += v1 * v1;
        s4[2] += v2; q4[2] += v2 * v2;
        s4[3] += v3; q4[3] += v3 * v3;
        uint2 w2;
        w2.x = (uint32)(ushort16)f2b(v0) | ((uint32)(ushort16)f2b(v1) << 16);
        w2.y = (uint32)(ushort16)f2b(v2) | ((uint32)(ushort16)f2b(v3) << 16);
        *reinterpret_cast<uint2*>(&Y[((size_t)b * 627 + jj) * 192 + m0c]) = w2;
      }
    }
#pragma unroll
    for (int off = 1; off < 16; off <<= 1)
#pragma unroll
      for (int r = 0; r < 4; ++r) { s4[r] += __shfl_xor(s4[r], off); q4[r] += __shfl_xor(q4[r], off); }
    if (lr == 0) {
#pragma unroll
      for (int r = 0; r < 4; ++r) {
        int o = m0c + r;
        if (o < 180) {
          atomicAdd(&Sp[part * 180 + o], s4[r]);
          atomicAdd(&Qp[part * 180 + o], q4[r]);
        }
      }
    }
  }
}

// ================= conv5 (MFMA) + log_softmax + NLL =================
__global__ __launch_bounds__(256) void conv5_nll(
    const short* __restrict__ Y, const float* __restrict__ a4, const float* __restrict__ b4,
    const short* __restrict__ cw5b, const float* __restrict__ cb5p,
    const float* __restrict__ inputs, float* __restrict__ nll)
{
  __shared__ float ab[384];
  __shared__ float pts[320 * 33];  // 42240 B; xT (32*200 shorts = 12800 B) aliases the front
  short* xT = reinterpret_cast<short*>(pts);
  const int tid = threadIdx.x;
  const int b = blockIdx.y, l0 = blockIdx.x * 32;
  for (int t = tid; t < 384; t += 256) ab[t] = (t < 192) ? a4[t] : b4[t - 192];
  __syncthreads();
  for (int t = tid; t < 32 * 24; t += 256) {
    int col = t / 24, oct = t - col * 24;
    int jj = l0 + col;
    int c0 = oct * 8;
    bf16x8 pk;
    if (jj < LLEN) {
      bf16x8 raw = *reinterpret_cast<const bf16x8*>(&Y[((size_t)b * 627 + jj) * 192 + c0]);
#pragma unroll
      for (int i = 0; i < 8; ++i)
        pk[i] = f2b(fmaxf(fmaf(ab[c0 + i], b2f(raw[i]), ab[192 + c0 + i]), 0.f));
    } else {
#pragma unroll
      for (int i = 0; i < 8; ++i) pk[i] = 0;
    }
    *reinterpret_cast<bf16x8*>(&xT[col * 200 + c0]) = pk;
  }
  __syncthreads();
  const int l = tid & 63, wv = tid >> 6;
  const int lr = l & 15, lk = (l >> 4) * 8, lm4 = (l >> 4) * 4;
  const int mf0 = wv * 5;
  f32x4 acc[5][2] = {};
#pragma unroll
  for (int ks = 0; ks < 6; ++ks) {
    int k0 = ks * 32 + lk;
    bf16x8 b0 = *reinterpret_cast<const bf16x8*>(&xT[(lr) * 200 + k0]);
    bf16x8 b1 = *reinterpret_cast<const bf16x8*>(&xT[(16 + lr) * 200 + k0]);
#pragma unroll
    for (int mi = 0; mi < 5; ++mi) {
      bf16x8 av = *reinterpret_cast<const bf16x8*>(&cw5b[((mf0 + mi) * 16 + lr) * 192 + k0]);
      acc[mi][0] = mfma16(av, b0, acc[mi][0]);
      acc[mi][1] = mfma16(av, b1, acc[mi][1]);
    }
  }
  __syncthreads();  // all xT reads done before pts overwrite
#pragma unroll
  for (int mi = 0; mi < 5; ++mi) {
#pragma unroll
    for (int nj = 0; nj < 2; ++nj) {
      int coln = nj * 16 + lr;
#pragma unroll
      for (int r = 0; r < 4; ++r) {
        int m = (mf0 + mi) * 16 + lm4 + r;
        float v = (m < 300) ? (acc[mi][nj][r] + cb5p[m]) : -1e30f;
        pts[m * 33 + coln] = v;
      }
    }
  }
  __syncthreads();
  int col = tid >> 3, sub = tid & 7;
  int jj = l0 + col;
  if (jj < LLEN) {
    float mx = -1e30f;
    for (int r = sub; r < 300; r += 8) mx = fmaxf(mx, pts[r * 33 + col]);
    for (int off = 1; off < 8; off <<= 1) mx = fmaxf(mx, __shfl_xor(mx, off));
    float sm = 0.f;
    for (int r = sub; r < 300; r += 8) sm += expf(pts[r * 33 + col] - mx);
    for (int off = 1; off < 8; off <<= 1) sm += __shfl_xor(sm, off);
    if (sub == 0) {
      float lse = mx + logf(sm);
      int tgt = (int)inputs[(size_t)b * NI + jj];
      nll[(size_t)b * LLEN + jj] = lse - pts[tgt * 33 + col];
    }
  }
}

// ================= final assembly =================
__global__ __launch_bounds__(256) void ll_pass1(
    const float* __restrict__ outb, const float* __restrict__ nll,
    const float* __restrict__ inputs, float* __restrict__ llp, float* __restrict__ sc)
{
  int b = blockIdx.x;
  float s = 0.f;
  for (int l = 2 + (int)threadIdx.x; l < LLEN; l += 256) {
    float graw = outb[(size_t)b * NOUTF + l];
    float sg = 1.f / (1.f + expf(-graw));
    float term;
    if (inputs[(size_t)b * NI + l] > 0.f)
      term = 0.1f * logf(sg + 1e-10f) - nll[(size_t)b * LLEN + l];
    else
      term = 0.1f * logf(1.f - sg + 1e-10f);
    s += term;
  }
  for (int off = 1; off < 64; off <<= 1) s += __shfl_xor(s, off);
  __shared__ float tmp[4];
  if ((threadIdx.x & 63) == 0) tmp[threadIdx.x >> 6] = s;
  __syncthreads();
  if (threadIdx.x == 0) {
    llp[b] = tmp[0] + tmp[1] + tmp[2] + tmp[3];
    atomicAdd(sc, nll[(size_t)b * LLEN] + nll[(size_t)b * LLEN + 1]);
  }
}

__global__ void ll_pass2(const float* __restrict__ llp, const float* __restrict__ sc, float* __restrict__ outp)
{
  int i = blockIdx.x * blockDim.x + threadIdx.x;
  if (i < BATCH) outp[i] = llp[i] - sc[0] * (1.f / 1024.f);
}

extern "C" void kernel_launch(void* const* d_in, const int* in_sizes, int n_in,
                              void* d_out, int out_size, void* d_ws, size_t ws_size,
                              hipStream_t stream)
{
  const float* inputs = (const float*)d_in[0];
  const float* W_in = (const float*)d_in[1];
  const float* b_in = (const float*)d_in[2];
  const float* W_h1 = (const float*)d_in[3];
  const float* b_h1 = (const float*)d_in[4];
  const float* W_h2 = (const float*)d_in[5];
  const float* b_h2 = (const float*)d_in[6];
  const float* W_out = (const float*)d_in[7];
  const float* b_out = (const float*)d_in[8];
  const float* cw1 = (const float*)d_in[9];
  const float* g1 = (const float*)d_in[11];
  const float* be1 = (const float*)d_in[12];
  const float* cw2 = (const float*)d_in[13];
  const float* cb2 = (const float*)d_in[14];
  const float* g2 = (const float*)d_in[15];
  const float* be2 = (const float*)d_in[16];
  const float* cw3 = (const float*)d_in[17];
  const float* cb3 = (const float*)d_in[18];
  const float* g3 = (const float*)d_in[19];
  const float* be3 = (const float*)d_in[20];
  const float* cw4 = (const float*)d_in[21];
  const float* cb4 = (const float*)d_in[22];
  const float* g4 = (const float*)d_in[23];
  const float* be4 = (const float*)d_in[24];
  const float* cw5 = (const float*)d_in[25];
  const float* cb5 = (const float*)d_in[26];

  char* p = (char*)d_ws;
  short* Y = (short*)p;    p += (size_t)512 * 627 * 192 * 2;
  short* INB = (short*)p;  p += (size_t)512 * 640 * 2;
  short* HB1 = (short*)p;  p += (size_t)512 * 1024 * 2;
  short* HB2 = (short*)p;  p += (size_t)512 * 1024 * 2;
  short* HB3 = (short*)p;  p += (size_t)512 * 1024 * 2;
  short* WB1 = (short*)p;  p += (size_t)1024 * 640 * 2;
  short* WB2 = (short*)p;  p += (size_t)1024 * 1024 * 2;
  short* WB3 = (short*)p;  p += (size_t)1024 * 1024 * 2;
  short* WB4 = (short*)p;  p += (size_t)1280 * 1024 * 2;
  short* CW2B = (short*)p; p += (size_t)192 * 96 * 2;
  short* CW3B = (short*)p; p += (size_t)192 * 192 * 2;
  short* CW4B = (short*)p; p += (size_t)192 * 192 * 2;
  short* CW5B = (short*)p; p += (size_t)320 * 192 * 2;
  float* fp = (float*)p;
  float* OUTB = fp;  fp += (size_t)512 * 1254;
  float* NLLB = fp;  fp += (size_t)512 * 627 + 1;  // +1 keeps 16B-ish alignment irrelevant for f32
  float* LLP = fp;   fp += 512;
  float* A1 = fp;    fp += 96;
  float* B1g = fp;   fp += 96;
  float* A2 = fp;    fp += 192;
  float* B2g = fp;   fp += 192;
  float* A3 = fp;    fp += 192;
  float* B3g = fp;   fp += 192;
  float* A4 = fp;    fp += 192;
  float* B4g = fp;   fp += 192;
  float* CB2P = fp;  fp += 192;
  float* CB3P = fp;  fp += 192;
  float* CB4P = fp;  fp += 192;
  float* CB5P = fp;  fp += 320;
  float* STAT = fp;  // 4 + 6*NPART*180
  float* TST = STAT;
  float* SC = STAT + 2;
  float* S2P = STAT + 4;
  float* Q2P = S2P + NPART * 180;
  float* S3P = Q2P + NPART * 180;
  float* Q3P = S3P + NPART * 180;
  float* S4P = Q3P + NPART * 180;
  float* Q4P = S4P + NPART * 180;

  hipMemsetAsync(STAT, 0, (4 + 6 * (size_t)NPART * 180) * sizeof(float), stream);

  // prep: inputs, masked MLP weights, conv weights, padded biases
  prep_inputs<<<dim3((512 * 640 + 255) / 256), 256, 0, stream>>>(inputs, INB);
  prep_mlpw<<<dim3((1024 * 640 + 255) / 256), 256, 0, stream>>>(W_in, WB1, 1024, 627, 1024, 640, 0);
  prep_mlpw<<<dim3((1024 * 1024 + 255) / 256), 256, 0, stream>>>(W_h1, WB2, 1024, 1024, 1024, 1024, 1);
  prep_mlpw<<<dim3((1024 * 1024 + 255) / 256), 256, 0, stream>>>(W_h2, WB3, 1024, 1024, 1024, 1024, 1);
  prep_mlpw<<<dim3((1280 * 1024 + 255) / 256), 256, 0, stream>>>(W_out, WB4, 1254, 1024, 1280, 1024, 2);
  prep_convw<<<dim3((192 * 96 + 255) / 256), 256, 0, stream>>>(cw2, CW2B, 180, 90, 192, 96);
  prep_convw<<<dim3((192 * 192 + 255) / 256), 256, 0, stream>>>(cw3, CW3B, 180, 180, 192, 192);
  prep_convw<<<dim3((192 * 192 + 255) / 256), 256, 0, stream>>>(cw4, CW4B, 180, 180, 192, 192);
  prep_convw<<<dim3((320 * 192 + 255) / 256), 256, 0, stream>>>(cw5, CW5B, 300, 180, 320, 192);
  prep_cb<<<1, 320, 0, stream>>>(cb2, cb3, cb4, cb5, CB2P, CB3P, CB4P, CB5P);

  // masked MLP (MFMA)
  mlp_mfma<<<dim3(16, 8), 256, 0, stream>>>(INB, WB1, b_in, nullptr, HB1, 1024, 640, 1);
  mlp_mfma<<<dim3(16, 8), 256, 0, stream>>>(HB1, WB2, b_h1, nullptr, HB2, 1024, 1024, 1);
  mlp_mfma<<<dim3(16, 8), 256, 0, stream>>>(HB2, WB3, b_h2, nullptr, HB3, 1024, 1024, 0);
  mlp_mfma<<<dim3(20, 8), 256, 0, stream>>>(HB3, WB4, b_out, OUTB, nullptr, 1254, 1024, 0);

  // conv1+bn1 folded via theta stats
  theta_stats<<<dim3(BATCH), 256, 0, stream>>>(OUTB, TST);
  finalize_conv1<<<1, 96, 0, stream>>>(TST, cw1, g1, be1, A1, B1g);

  // conv2 stats, then fused conv2->conv3 -> Y (y3) + stats3
  conv2_stats<<<dim3(10, BATCH), 256, 0, stream>>>(OUTB, A1, B1g, CW2B, CB2P, S2P, Q2P);
  finalize_bn_part<<<1, 192, 0, stream>>>(S2P, Q2P, g2, be2, A2, B2g);
  fused_conv23<<<dim3(10, BATCH), 256, 0, stream>>>(OUTB, A1, B1g, CW2B, CB2P, A2, B2g, CW3B, CB3P, Y, S3P, Q3P);
  finalize_bn_part<<<1, 192, 0, stream>>>(S3P, Q3P, g3, be3, A3, B3g);

  // conv4 in place
  conv4_ip<<<dim3(10, BATCH), 256, 0, stream>>>(Y, A3, B3g, CW4B, CB4P, S4P, Q4P);
  finalize_bn_part<<<1, 192, 0, stream>>>(S4P, Q4P, g4, be4, A4, B4g);

  // conv5 + log_softmax + nll
  conv5_nll<<<dim3(20, BATCH), 256, 0, stream>>>(Y, A4, B4g, CW5B, CB5P, inputs, NLLB);

  // final assembly
  ll_pass1<<<dim3(BATCH), 256, 0, stream>>>(OUTB, NLLB, inputs, LLP, SC);
  ll_pass2<<<dim3(2), 256, 0, stream>>>(LLP, SC, (float*)d_out);
}

// Round 6
// 806.345 us; speedup vs baseline: 4.8985x; 1.1351x over previous
//
#include <hip/hip_runtime.h>
#include <math.h>

#define BATCH 512
#define NI 627
#define NH 1024
#define NOUTF 1254
#define LLEN 627
#define NBL (512 * 627)
#define EPSBN 1e-5f
#define NPART 64

typedef __attribute__((ext_vector_type(8))) short bf16x8;
typedef __attribute__((ext_vector_type(4))) float f32x4;
typedef unsigned int uint32;
typedef unsigned short ushort16;

__device__ inline short f2b(float x) {
  uint32 u = __float_as_uint(x);
  uint32 r = (u + 0x7fffu + ((u >> 16) & 1u)) >> 16;
  return (short)r;
}
__device__ inline float b2f(short s) {
  return __uint_as_float(((uint32)(ushort16)s) << 16);
}
__device__ inline f32x4 mfma16(bf16x8 a, bf16x8 b, f32x4 c) {
  return __builtin_amdgcn_mfma_f32_16x16x32_bf16(a, b, c, 0, 0, 0);
}

// ================= prep kernels =================
__global__ __launch_bounds__(256) void prep_inputs(const float* __restrict__ in, short* __restrict__ outp) {
  int i = blockIdx.x * 256 + threadIdx.x;
  if (i >= 512 * 640) return;
  int m = i / 640, k = i - m * 640;
  outp[i] = (k < NI) ? f2b(in[m * NI + k]) : (short)0;
}

__global__ __launch_bounds__(256) void prep_mlpw(const float* __restrict__ W, short* __restrict__ Wb,
                                                 int Nreal, int Kreal, int Npad, int Kpad, int mode) {
  int i = blockIdx.x * 256 + threadIdx.x;
  if (i >= Npad * Kpad) return;
  int n = i / Kpad, k = i - n * Kpad;
  float w = 0.f;
  if (n < Nreal && k < Kreal) {
    int od = n >= 627 ? n - 627 : n;
    int kd = k >= 627 ? k - 627 : k;
    bool keep = (mode == 0) ? (od >= k) : (mode == 1) ? (od >= kd) : (od > kd);
    if (keep) w = W[n * Kreal + k];
  }
  Wb[i] = f2b(w);
}

__global__ __launch_bounds__(256) void prep_convw(const float* __restrict__ W, short* __restrict__ Wb,
                                                  int Oreal, int Kreal, int Opad, int Kpad) {
  int i = blockIdx.x * 256 + threadIdx.x;
  if (i >= Opad * Kpad) return;
  int o = i / Kpad, k = i - o * Kpad;
  Wb[i] = (o < Oreal && k < Kreal) ? f2b(W[o * Kreal + k]) : (short)0;
}

__global__ void prep_cb(const float* __restrict__ cb2, const float* __restrict__ cb3,
                        const float* __restrict__ cb4, const float* __restrict__ cb5,
                        float* __restrict__ cb2p, float* __restrict__ cb3p,
                        float* __restrict__ cb4p, float* __restrict__ cb5p) {
  int c = threadIdx.x;  // 320 threads
  if (c < 192) {
    cb2p[c] = (c < 180) ? cb2[c] : 0.f;
    cb3p[c] = (c < 180) ? cb3[c] : 0.f;
    cb4p[c] = (c < 180) ? cb4[c] : 0.f;
  }
  if (c < 320) cb5p[c] = (c < 300) ? cb5[c] : 0.f;
}

// ================= MLP MFMA GEMM: C[M,Nreal] = act(A @ Wb^T + bias) =================
__global__ __launch_bounds__(256) void mlp_mfma(
    const short* __restrict__ A, const short* __restrict__ Wb, const float* __restrict__ bias,
    float* __restrict__ Cf, short* __restrict__ Cb, int Nreal, int Kpad, int relu)
{
  const int l = threadIdx.x & 63, wv = threadIdx.x >> 6;
  const int wm = wv >> 1, wn = wv & 1;
  const int m0 = blockIdx.y * 64 + wm * 32;
  const int n0 = blockIdx.x * 64 + wn * 32;
  const int lr = l & 15, lk = (l >> 4) * 8, lm4 = (l >> 4) * 4;
  f32x4 acc[2][2] = {};
  const int nk = Kpad >> 5;
  for (int ks = 0; ks < nk; ++ks) {
    int k0 = ks * 32 + lk;
    bf16x8 a0 = *reinterpret_cast<const bf16x8*>(&A[(size_t)(m0 + lr) * Kpad + k0]);
    bf16x8 a1 = *reinterpret_cast<const bf16x8*>(&A[(size_t)(m0 + 16 + lr) * Kpad + k0]);
    bf16x8 b0 = *reinterpret_cast<const bf16x8*>(&Wb[(size_t)(n0 + lr) * Kpad + k0]);
    bf16x8 b1 = *reinterpret_cast<const bf16x8*>(&Wb[(size_t)(n0 + 16 + lr) * Kpad + k0]);
    acc[0][0] = mfma16(a0, b0, acc[0][0]);
    acc[0][1] = mfma16(a0, b1, acc[0][1]);
    acc[1][0] = mfma16(a1, b0, acc[1][0]);
    acc[1][1] = mfma16(a1, b1, acc[1][1]);
  }
#pragma unroll
  for (int mi = 0; mi < 2; ++mi)
#pragma unroll
    for (int nj = 0; nj < 2; ++nj) {
      int n = n0 + nj * 16 + lr;
      if (n >= Nreal) continue;
      float bi = bias[n];
#pragma unroll
      for (int r = 0; r < 4; ++r) {
        int m = m0 + mi * 16 + lm4 + r;
        float v = acc[mi][nj][r] + bi;
        if (relu) v = fmaxf(v, 0.f);
        if (Cb) Cb[(size_t)m * Nreal + n] = f2b(v);
        else Cf[(size_t)m * Nreal + n] = v;
      }
    }
}

// ================= theta stats =================
__global__ __launch_bounds__(256) void theta_stats(const float* __restrict__ outb, float* __restrict__ tstat)
{
  int b = blockIdx.x;
  const float* th = outb + (size_t)b * NOUTF + NI;
  float s = 0.f, q = 0.f;
  for (int l = threadIdx.x; l < LLEN; l += 256) { float t = th[l]; s += t; q += t * t; }
  for (int off = 1; off < 64; off <<= 1) { s += __shfl_xor(s, off); q += __shfl_xor(q, off); }
  __shared__ float tmp[8];
  int w = threadIdx.x >> 6;
  if ((threadIdx.x & 63) == 0) { tmp[w] = s; tmp[4 + w] = q; }
  __syncthreads();
  if (threadIdx.x == 0) {
    atomicAdd(&tstat[0], tmp[0] + tmp[1] + tmp[2] + tmp[3]);
    atomicAdd(&tstat[1], tmp[4] + tmp[5] + tmp[6] + tmp[7]);
  }
}

__global__ void finalize_conv1(const float* __restrict__ tstat, const float* __restrict__ cw1,
                               const float* __restrict__ g1, const float* __restrict__ be1,
                               float* __restrict__ a1, float* __restrict__ b1)
{
  int c = threadIdx.x;  // 96
  if (c >= 96) return;
  if (c < 90) {
    float mt = tstat[0] / (float)NBL;
    float vt = tstat[1] / (float)NBL - mt * mt;
    float w = cw1[c];
    float rs = rsqrtf(w * w * vt + EPSBN);
    float a = w * g1[c] * rs;
    a1[c] = a;
    b1[c] = be1[c] - a * mt;
  } else { a1[c] = 0.f; b1[c] = 0.f; }
}

__global__ void finalize_bn_part(const float* __restrict__ Sp, const float* __restrict__ Qp,
                                 const float* __restrict__ g, const float* __restrict__ be,
                                 float* __restrict__ aP, float* __restrict__ bP)
{
  int c = threadIdx.x;  // 192
  if (c >= 192) return;
  if (c < 180) {
    float s = 0.f, q = 0.f;
    for (int p = 0; p < NPART; ++p) { s += Sp[p * 180 + c]; q += Qp[p * 180 + c]; }
    float m = s / (float)NBL;
    float v = q / (float)NBL - m * m;
    float a = g[c] * rsqrtf(v + EPSBN);
    aP[c] = a;
    bP[c] = be[c] - m * a;
  } else { aP[c] = 0.f; bP[c] = 0.f; }
}

// ================= conv2 stats-only (MFMA) =================
__global__ __launch_bounds__(256) void conv2_stats(
    const float* __restrict__ OUTB, const float* __restrict__ a1, const float* __restrict__ b1,
    const short* __restrict__ cw2b, const float* __restrict__ cb2p,
    float* __restrict__ Sp, float* __restrict__ Qp)
{
  __shared__ float th[64];
  __shared__ float ab[192];
  __shared__ short xT[64][104];
  const int tid = threadIdx.x;
  const int b = blockIdx.y, j0 = blockIdx.x * 64;
  if (tid < 64) {
    int jj = j0 + tid;
    th[tid] = (jj < LLEN) ? OUTB[(size_t)b * NOUTF + NI + jj] : 0.f;
  }
  if (tid < 96) ab[tid] = a1[tid];
  else if (tid < 192) ab[tid] = b1[tid - 96];
  __syncthreads();
  for (int t = tid; t < 64 * 12; t += 256) {
    int col = t / 12, oct = t - col * 12;
    float tv = th[col];
    int c0 = oct * 8;
    bf16x8 pk;
#pragma unroll
    for (int i = 0; i < 8; ++i)
      pk[i] = f2b(fmaxf(fmaf(ab[c0 + i], tv, ab[96 + c0 + i]), 0.f));
    *reinterpret_cast<bf16x8*>(&xT[col][c0]) = pk;
  }
  __syncthreads();
  const int l = tid & 63, wv = tid >> 6, wm = wv >> 1, wn = wv & 1;
  const int lr = l & 15, lk = (l >> 4) * 8, lm4 = (l >> 4) * 4;
  f32x4 acc[6][2] = {};
#pragma unroll
  for (int ks = 0; ks < 3; ++ks) {
    int k0 = ks * 32 + lk;
    bf16x8 b0 = *reinterpret_cast<const bf16x8*>(&xT[wn * 32 + lr][k0]);
    bf16x8 b1 = *reinterpret_cast<const bf16x8*>(&xT[wn * 32 + 16 + lr][k0]);
#pragma unroll
    for (int mi = 0; mi < 6; ++mi) {
      bf16x8 av = *reinterpret_cast<const bf16x8*>(&cw2b[(wm * 96 + mi * 16 + lr) * 96 + k0]);
      acc[mi][0] = mfma16(av, b0, acc[mi][0]);
      acc[mi][1] = mfma16(av, b1, acc[mi][1]);
    }
  }
  int part = (blockIdx.y * gridDim.x + blockIdx.x) & (NPART - 1);
#pragma unroll
  for (int mi = 0; mi < 6; ++mi) {
    int m0c = wm * 96 + mi * 16 + lm4;
    float s4[4] = {0.f, 0.f, 0.f, 0.f}, q4[4] = {0.f, 0.f, 0.f, 0.f};
#pragma unroll
    for (int nj = 0; nj < 2; ++nj) {
      int jj = j0 + wn * 32 + nj * 16 + lr;
      if (jj < LLEN) {
#pragma unroll
        for (int r = 0; r < 4; ++r) {
          float v = acc[mi][nj][r] + cb2p[m0c + r];
          s4[r] += v; q4[r] += v * v;
        }
      }
    }
#pragma unroll
    for (int off = 1; off < 16; off <<= 1)
#pragma unroll
      for (int r = 0; r < 4; ++r) { s4[r] += __shfl_xor(s4[r], off); q4[r] += __shfl_xor(q4[r], off); }
    if (lr == 0) {
#pragma unroll
      for (int r = 0; r < 4; ++r) {
        int o = m0c + r;
        if (o < 180) {
          atomicAdd(&Sp[part * 180 + o], s4[r]);
          atomicAdd(&Qp[part * 180 + o], q4[r]);
        }
      }
    }
  }
}

// ================= fused conv2 -> bn2 -> relu -> conv3 (MFMA), write Y + stats3 =================
__global__ __launch_bounds__(256) void fused_conv23(
    const float* __restrict__ OUTB, const float* __restrict__ a1, const float* __restrict__ b1,
    const short* __restrict__ cw2b, const float* __restrict__ cb2p,
    const float* __restrict__ a2, const float* __restrict__ b2,
    const short* __restrict__ cw3b, const float* __restrict__ cb3p,
    short* __restrict__ Y, float* __restrict__ Sp, float* __restrict__ Qp)
{
  __shared__ float th[64];
  __shared__ float ab[192];
  __shared__ short xT1[64][104];
  __shared__ short xT2[64][200];
  const int tid = threadIdx.x;
  const int b = blockIdx.y, j0 = blockIdx.x * 64;
  if (tid < 64) {
    int jj = j0 + tid;
    th[tid] = (jj < LLEN) ? OUTB[(size_t)b * NOUTF + NI + jj] : 0.f;
  }
  if (tid < 96) ab[tid] = a1[tid];
  else if (tid < 192) ab[tid] = b1[tid - 96];
  __syncthreads();
  for (int t = tid; t < 64 * 12; t += 256) {
    int col = t / 12, oct = t - col * 12;
    float tv = th[col];
    int c0 = oct * 8;
    bf16x8 pk;
#pragma unroll
    for (int i = 0; i < 8; ++i)
      pk[i] = f2b(fmaxf(fmaf(ab[c0 + i], tv, ab[96 + c0 + i]), 0.f));
    *reinterpret_cast<bf16x8*>(&xT1[col][c0]) = pk;
  }
  __syncthreads();
  const int l = tid & 63, wv = tid >> 6, wm = wv >> 1, wn = wv & 1;
  const int lr = l & 15, lk = (l >> 4) * 8, lm4 = (l >> 4) * 4;
  // conv2
  f32x4 acc[6][2] = {};
#pragma unroll
  for (int ks = 0; ks < 3; ++ks) {
    int k0 = ks * 32 + lk;
    bf16x8 b0 = *reinterpret_cast<const bf16x8*>(&xT1[wn * 32 + lr][k0]);
    bf16x8 b1 = *reinterpret_cast<const bf16x8*>(&xT1[wn * 32 + 16 + lr][k0]);
#pragma unroll
    for (int mi = 0; mi < 6; ++mi) {
      bf16x8 av = *reinterpret_cast<const bf16x8*>(&cw2b[(wm * 96 + mi * 16 + lr) * 96 + k0]);
      acc[mi][0] = mfma16(av, b0, acc[mi][0]);
      acc[mi][1] = mfma16(av, b1, acc[mi][1]);
    }
  }
  // x2 = relu(a2*(y2+cb2)+b2) -> xT2
#pragma unroll
  for (int mi = 0; mi < 6; ++mi) {
    int m0c = wm * 96 + mi * 16 + lm4;
#pragma unroll
    for (int nj = 0; nj < 2; ++nj) {
      int col = wn * 32 + nj * 16 + lr;
      uint32 lo, hi;
      {
        float y0 = acc[mi][nj][0] + cb2p[m0c + 0];
        float y1 = acc[mi][nj][1] + cb2p[m0c + 1];
        float x0 = fmaxf(fmaf(a2[m0c + 0], y0, b2[m0c + 0]), 0.f);
        float x1 = fmaxf(fmaf(a2[m0c + 1], y1, b2[m0c + 1]), 0.f);
        lo = (uint32)(ushort16)f2b(x0) | ((uint32)(ushort16)f2b(x1) << 16);
        float y2v = acc[mi][nj][2] + cb2p[m0c + 2];
        float y3v = acc[mi][nj][3] + cb2p[m0c + 3];
        float x2 = fmaxf(fmaf(a2[m0c + 2], y2v, b2[m0c + 2]), 0.f);
        float x3 = fmaxf(fmaf(a2[m0c + 3], y3v, b2[m0c + 3]), 0.f);
        hi = (uint32)(ushort16)f2b(x2) | ((uint32)(ushort16)f2b(x3) << 16);
      }
      uint2 w2; w2.x = lo; w2.y = hi;
      *reinterpret_cast<uint2*>(&xT2[col][m0c]) = w2;
    }
  }
  __syncthreads();
  // conv3
  f32x4 acc2[6][2] = {};
#pragma unroll
  for (int ks = 0; ks < 6; ++ks) {
    int k0 = ks * 32 + lk;
    bf16x8 b0 = *reinterpret_cast<const bf16x8*>(&xT2[wn * 32 + lr][k0]);
    bf16x8 b1 = *reinterpret_cast<const bf16x8*>(&xT2[wn * 32 + 16 + lr][k0]);
#pragma unroll
    for (int mi = 0; mi < 6; ++mi) {
      bf16x8 av = *reinterpret_cast<const bf16x8*>(&cw3b[(wm * 96 + mi * 16 + lr) * 192 + k0]);
      acc2[mi][0] = mfma16(av, b0, acc2[mi][0]);
      acc2[mi][1] = mfma16(av, b1, acc2[mi][1]);
    }
  }
  int part = (blockIdx.y * gridDim.x + blockIdx.x) & (NPART - 1);
#pragma unroll
  for (int mi = 0; mi < 6; ++mi) {
    int m0c = wm * 96 + mi * 16 + lm4;
    float s4[4] = {0.f, 0.f, 0.f, 0.f}, q4[4] = {0.f, 0.f, 0.f, 0.f};
#pragma unroll
    for (int nj = 0; nj < 2; ++nj) {
      int jj = j0 + wn * 32 + nj * 16 + lr;
      if (jj < LLEN) {
        float v0 = acc2[mi][nj][0] + cb3p[m0c + 0];
        float v1 = acc2[mi][nj][1] + cb3p[m0c + 1];
        float v2 = acc2[mi][nj][2] + cb3p[m0c + 2];
        float v3 = acc2[mi][nj][3] + cb3p[m0c + 3];
        s4[0] += v0; q4[0] += v0 * v0;
        s4[1] += v1; q4[1] += v1 * v1;
        s4[2] += v2; q4[2] += v2 * v2;
        s4[3] += v3; q4[3] += v3 * v3;
        uint2 w2;
        w2.x = (uint32)(ushort16)f2b(v0) | ((uint32)(ushort16)f2b(v1) << 16);
        w2.y = (uint32)(ushort16)f2b(v2) | ((uint32)(ushort16)f2b(v3) << 16);
        *reinterpret_cast<uint2*>(&Y[((size_t)b * 627 + jj) * 192 + m0c]) = w2;
      }
    }
#pragma unroll
    for (int off = 1; off < 16; off <<= 1)
#pragma unroll
      for (int r = 0; r < 4; ++r) { s4[r] += __shfl_xor(s4[r], off); q4[r] += __shfl_xor(q4[r], off); }
    if (lr == 0) {
#pragma unroll
      for (int r = 0; r < 4; ++r) {
        int o = m0c + r;
        if (o < 180) {
          atomicAdd(&Sp[part * 180 + o], s4[r]);
          atomicAdd(&Qp[part * 180 + o], q4[r]);
        }
      }
    }
  }
}

// ================= conv4 in place on Y (MFMA) =================
__global__ __launch_bounds__(256) void conv4_ip(
    short* __restrict__ Y, const float* __restrict__ a3, const float* __restrict__ b3,
    const short* __restrict__ cw4b, const float* __restrict__ cb4p,
    float* __restrict__ Sp, float* __restrict__ Qp)
{
  __shared__ float ab[384];
  __shared__ short xT[64][200];
  const int tid = threadIdx.x;
  const int b = blockIdx.y, j0 = blockIdx.x * 64;
  for (int t = tid; t < 384; t += 256) ab[t] = (t < 192) ? a3[t] : b3[t - 192];
  __syncthreads();
  for (int t = tid; t < 64 * 24; t += 256) {
    int col = t / 24, oct = t - col * 24;
    int jj = j0 + col;
    int c0 = oct * 8;
    bf16x8 pk;
    if (jj < LLEN) {
      bf16x8 raw = *reinterpret_cast<const bf16x8*>(&Y[((size_t)b * 627 + jj) * 192 + c0]);
#pragma unroll
      for (int i = 0; i < 8; ++i)
        pk[i] = f2b(fmaxf(fmaf(ab[c0 + i], b2f(raw[i]), ab[192 + c0 + i]), 0.f));
    } else {
#pragma unroll
      for (int i = 0; i < 8; ++i) pk[i] = 0;
    }
    *reinterpret_cast<bf16x8*>(&xT[col][c0]) = pk;
  }
  __syncthreads();
  const int l = tid & 63, wv = tid >> 6, wm = wv >> 1, wn = wv & 1;
  const int lr = l & 15, lk = (l >> 4) * 8, lm4 = (l >> 4) * 4;
  f32x4 acc[6][2] = {};
#pragma unroll
  for (int ks = 0; ks < 6; ++ks) {
    int k0 = ks * 32 + lk;
    bf16x8 b0 = *reinterpret_cast<const bf16x8*>(&xT[wn * 32 + lr][k0]);
    bf16x8 b1 = *reinterpret_cast<const bf16x8*>(&xT[wn * 32 + 16 + lr][k0]);
#pragma unroll
    for (int mi = 0; mi < 6; ++mi) {
      bf16x8 av = *reinterpret_cast<const bf16x8*>(&cw4b[(wm * 96 + mi * 16 + lr) * 192 + k0]);
      acc[mi][0] = mfma16(av, b0, acc[mi][0]);
      acc[mi][1] = mfma16(av, b1, acc[mi][1]);
    }
  }
  int part = (blockIdx.y * gridDim.x + blockIdx.x) & (NPART - 1);
#pragma unroll
  for (int mi = 0; mi < 6; ++mi) {
    int m0c = wm * 96 + mi * 16 + lm4;
    float s4[4] = {0.f, 0.f, 0.f, 0.f}, q4[4] = {0.f, 0.f, 0.f, 0.f};
#pragma unroll
    for (int nj = 0; nj < 2; ++nj) {
      int jj = j0 + wn * 32 + nj * 16 + lr;
      if (jj < LLEN) {
        float v0 = acc[mi][nj][0] + cb4p[m0c + 0];
        float v1 = acc[mi][nj][1] + cb4p[m0c + 1];
        float v2 = acc[mi][nj][2] + cb4p[m0c + 2];
        float v3 = acc[mi][nj][3] + cb4p[m0c + 3];
        s4[0] += v0; q4[0] += v0 * v0;
        s4[1] += v1; q4[1] += v1 * v1;
        s4[2] += v2; q4[2] += v2 * v2;
        s4[3] += v3; q4[3] += v3 * v3;
        uint2 w2;
        w2.x = (uint32)(ushort16)f2b(v0) | ((uint32)(ushort16)f2b(v1) << 16);
        w2.y = (uint32)(ushort16)f2b(v2) | ((uint32)(ushort16)f2b(v3) << 16);
        *reinterpret_cast<uint2*>(&Y[((size_t)b * 627 + jj) * 192 + m0c]) = w2;
      }
    }
#pragma unroll
    for (int off = 1; off < 16; off <<= 1)
#pragma unroll
      for (int r = 0; r < 4; ++r) { s4[r] += __shfl_xor(s4[r], off); q4[r] += __shfl_xor(q4[r], off); }
    if (lr == 0) {
#pragma unroll
      for (int r = 0; r < 4; ++r) {
        int o = m0c + r;
        if (o < 180) {
          atomicAdd(&Sp[part * 180 + o], s4[r]);
          atomicAdd(&Qp[part * 180 + o], q4[r]);
        }
      }
    }
  }
}

// ================= conv5 (MFMA) + register log_softmax + NLL =================
__global__ __launch_bounds__(256) void conv5_nll(
    const short* __restrict__ Y, const float* __restrict__ a4, const float* __restrict__ b4,
    const short* __restrict__ cw5b, const float* __restrict__ cb5p,
    const float* __restrict__ inputs, float* __restrict__ nll)
{
  __shared__ float ab[384];
  __shared__ short xT[32][200];
  __shared__ float wmax[4][32];
  __shared__ float wsum[4][32];
  __shared__ float ptgt[32];
  __shared__ int tg[32];
  const int tid = threadIdx.x;
  const int b = blockIdx.y, l0 = blockIdx.x * 32;
  for (int t = tid; t < 384; t += 256) ab[t] = (t < 192) ? a4[t] : b4[t - 192];
  if (tid < 32) {
    int jj = l0 + tid;
    tg[tid] = (jj < LLEN) ? (int)inputs[(size_t)b * NI + jj] : 0;
  }
  __syncthreads();
  for (int t = tid; t < 32 * 24; t += 256) {
    int col = t / 24, oct = t - col * 24;
    int jj = l0 + col;
    int c0 = oct * 8;
    bf16x8 pk;
    if (jj < LLEN) {
      bf16x8 raw = *reinterpret_cast<const bf16x8*>(&Y[((size_t)b * 627 + jj) * 192 + c0]);
#pragma unroll
      for (int i = 0; i < 8; ++i)
        pk[i] = f2b(fmaxf(fmaf(ab[c0 + i], b2f(raw[i]), ab[192 + c0 + i]), 0.f));
    } else {
#pragma unroll
      for (int i = 0; i < 8; ++i) pk[i] = 0;
    }
    *reinterpret_cast<bf16x8*>(&xT[col][c0]) = pk;
  }
  __syncthreads();
  const int l = tid & 63, wv = tid >> 6;
  const int lr = l & 15, lk = (l >> 4) * 8, lm4 = (l >> 4) * 4;
  const int mf0 = wv * 5;
  f32x4 acc[5][2] = {};
#pragma unroll
  for (int ks = 0; ks < 6; ++ks) {
    int k0 = ks * 32 + lk;
    bf16x8 b0 = *reinterpret_cast<const bf16x8*>(&xT[lr][k0]);
    bf16x8 b1 = *reinterpret_cast<const bf16x8*>(&xT[16 + lr][k0]);
#pragma unroll
    for (int mi = 0; mi < 5; ++mi) {
      bf16x8 av = *reinterpret_cast<const bf16x8*>(&cw5b[((mf0 + mi) * 16 + lr) * 192 + k0]);
      acc[mi][0] = mfma16(av, b0, acc[mi][0]);
      acc[mi][1] = mfma16(av, b1, acc[mi][1]);
    }
  }
  // logits to registers; per-lane per-col max
  float vv[5][2][4];
  float vmax0 = -1e30f, vmax1 = -1e30f;
#pragma unroll
  for (int mi = 0; mi < 5; ++mi) {
#pragma unroll
    for (int r = 0; r < 4; ++r) {
      int m = (mf0 + mi) * 16 + lm4 + r;
      float bi = cb5p[m];
      float v0 = (m < 300) ? (acc[mi][0][r] + bi) : -1e30f;
      float v1 = (m < 300) ? (acc[mi][1][r] + bi) : -1e30f;
      vv[mi][0][r] = v0;
      vv[mi][1][r] = v1;
      vmax0 = fmaxf(vmax0, v0);
      vmax1 = fmaxf(vmax1, v1);
    }
  }
  // NLL target gather: each (row,col) value has exactly one owner lane
  {
    int t0 = tg[lr], t1 = tg[16 + lr];
#pragma unroll
    for (int mi = 0; mi < 5; ++mi) {
#pragma unroll
      for (int r = 0; r < 4; ++r) {
        int m = (mf0 + mi) * 16 + lm4 + r;
        if (m == t0) ptgt[lr] = vv[mi][0][r];
        if (m == t1) ptgt[16 + lr] = vv[mi][1][r];
      }
    }
  }
  // cross-lane max within wave (row groups at lanes lr, lr+16, lr+32, lr+48)
  vmax0 = fmaxf(vmax0, __shfl_xor(vmax0, 16)); vmax0 = fmaxf(vmax0, __shfl_xor(vmax0, 32));
  vmax1 = fmaxf(vmax1, __shfl_xor(vmax1, 16)); vmax1 = fmaxf(vmax1, __shfl_xor(vmax1, 32));
  if (l < 16) { wmax[wv][lr] = vmax0; wmax[wv][16 + lr] = vmax1; }
  __syncthreads();
  float gmax0 = fmaxf(fmaxf(wmax[0][lr], wmax[1][lr]), fmaxf(wmax[2][lr], wmax[3][lr]));
  float gmax1 = fmaxf(fmaxf(wmax[0][16 + lr], wmax[1][16 + lr]), fmaxf(wmax[2][16 + lr], wmax[3][16 + lr]));
  float vs0 = 0.f, vs1 = 0.f;
#pragma unroll
  for (int mi = 0; mi < 5; ++mi) {
#pragma unroll
    for (int r = 0; r < 4; ++r) {
      vs0 += __expf(vv[mi][0][r] - gmax0);
      vs1 += __expf(vv[mi][1][r] - gmax1);
    }
  }
  vs0 += __shfl_xor(vs0, 16); vs0 += __shfl_xor(vs0, 32);
  vs1 += __shfl_xor(vs1, 16); vs1 += __shfl_xor(vs1, 32);
  if (l < 16) { wsum[wv][lr] = vs0; wsum[wv][16 + lr] = vs1; }
  __syncthreads();
  if (tid < 32) {
    int jj = l0 + tid;
    if (jj < LLEN) {
      float gm = fmaxf(fmaxf(wmax[0][tid], wmax[1][tid]), fmaxf(wmax[2][tid], wmax[3][tid]));
      float gs = wsum[0][tid] + wsum[1][tid] + wsum[2][tid] + wsum[3][tid];
      nll[(size_t)b * LLEN + jj] = gm + logf(gs) - ptgt[tid];
    }
  }
}

// ================= final assembly =================
__global__ __launch_bounds__(256) void ll_pass1(
    const float* __restrict__ outb, const float* __restrict__ nll,
    const float* __restrict__ inputs, float* __restrict__ llp, float* __restrict__ sc)
{
  int b = blockIdx.x;
  float s = 0.f;
  for (int l = 2 + (int)threadIdx.x; l < LLEN; l += 256) {
    float graw = outb[(size_t)b * NOUTF + l];
    float sg = 1.f / (1.f + expf(-graw));
    float term;
    if (inputs[(size_t)b * NI + l] > 0.f)
      term = 0.1f * logf(sg + 1e-10f) - nll[(size_t)b * LLEN + l];
    else
      term = 0.1f * logf(1.f - sg + 1e-10f);
    s += term;
  }
  for (int off = 1; off < 64; off <<= 1) s += __shfl_xor(s, off);
  __shared__ float tmp[4];
  if ((threadIdx.x & 63) == 0) tmp[threadIdx.x >> 6] = s;
  __syncthreads();
  if (threadIdx.x == 0) {
    llp[b] = tmp[0] + tmp[1] + tmp[2] + tmp[3];
    atomicAdd(sc, nll[(size_t)b * LLEN] + nll[(size_t)b * LLEN + 1]);
  }
}

__global__ void ll_pass2(const float* __restrict__ llp, const float* __restrict__ sc, float* __restrict__ outp)
{
  int i = blockIdx.x * blockDim.x + threadIdx.x;
  if (i < BATCH) outp[i] = llp[i] - sc[0] * (1.f / 1024.f);
}

extern "C" void kernel_launch(void* const* d_in, const int* in_sizes, int n_in,
                              void* d_out, int out_size, void* d_ws, size_t ws_size,
                              hipStream_t stream)
{
  const float* inputs = (const float*)d_in[0];
  const float* W_in = (const float*)d_in[1];
  const float* b_in = (const float*)d_in[2];
  const float* W_h1 = (const float*)d_in[3];
  const float* b_h1 = (const float*)d_in[4];
  const float* W_h2 = (const float*)d_in[5];
  const float* b_h2 = (const float*)d_in[6];
  const float* W_out = (const float*)d_in[7];
  const float* b_out = (const float*)d_in[8];
  const float* cw1 = (const float*)d_in[9];
  const float* g1 = (const float*)d_in[11];
  const float* be1 = (const float*)d_in[12];
  const float* cw2 = (const float*)d_in[13];
  const float* cb2 = (const float*)d_in[14];
  const float* g2 = (const float*)d_in[15];
  const float* be2 = (const float*)d_in[16];
  const float* cw3 = (const float*)d_in[17];
  const float* cb3 = (const float*)d_in[18];
  const float* g3 = (const float*)d_in[19];
  const float* be3 = (const float*)d_in[20];
  const float* cw4 = (const float*)d_in[21];
  const float* cb4 = (const float*)d_in[22];
  const float* g4 = (const float*)d_in[23];
  const float* be4 = (const float*)d_in[24];
  const float* cw5 = (const float*)d_in[25];
  const float* cb5 = (const float*)d_in[26];

  char* p = (char*)d_ws;
  short* Y = (short*)p;    p += (size_t)512 * 627 * 192 * 2;
  short* INB = (short*)p;  p += (size_t)512 * 640 * 2;
  short* HB1 = (short*)p;  p += (size_t)512 * 1024 * 2;
  short* HB2 = (short*)p;  p += (size_t)512 * 1024 * 2;
  short* HB3 = (short*)p;  p += (size_t)512 * 1024 * 2;
  short* WB1 = (short*)p;  p += (size_t)1024 * 640 * 2;
  short* WB2 = (short*)p;  p += (size_t)1024 * 1024 * 2;
  short* WB3 = (short*)p;  p += (size_t)1024 * 1024 * 2;
  short* WB4 = (short*)p;  p += (size_t)1280 * 1024 * 2;
  short* CW2B = (short*)p; p += (size_t)192 * 96 * 2;
  short* CW3B = (short*)p; p += (size_t)192 * 192 * 2;
  short* CW4B = (short*)p; p += (size_t)192 * 192 * 2;
  short* CW5B = (short*)p; p += (size_t)320 * 192 * 2;
  float* fp = (float*)p;
  float* OUTB = fp;  fp += (size_t)512 * 1254;
  float* NLLB = fp;  fp += (size_t)512 * 627 + 1;
  float* LLP = fp;   fp += 512;
  float* A1 = fp;    fp += 96;
  float* B1g = fp;   fp += 96;
  float* A2 = fp;    fp += 192;
  float* B2g = fp;   fp += 192;
  float* A3 = fp;    fp += 192;
  float* B3g = fp;   fp += 192;
  float* A4 = fp;    fp += 192;
  float* B4g = fp;   fp += 192;
  float* CB2P = fp;  fp += 192;
  float* CB3P = fp;  fp += 192;
  float* CB4P = fp;  fp += 192;
  float* CB5P = fp;  fp += 320;
  float* STAT = fp;  // 4 + 6*NPART*180
  float* TST = STAT;
  float* SC = STAT + 2;
  float* S2P = STAT + 4;
  float* Q2P = S2P + NPART * 180;
  float* S3P = Q2P + NPART * 180;
  float* Q3P = S3P + NPART * 180;
  float* S4P = Q3P + NPART * 180;
  float* Q4P = S4P + NPART * 180;

  hipMemsetAsync(STAT, 0, (4 + 6 * (size_t)NPART * 180) * sizeof(float), stream);

  // prep: inputs, masked MLP weights, conv weights, padded biases
  prep_inputs<<<dim3((512 * 640 + 255) / 256), 256, 0, stream>>>(inputs, INB);
  prep_mlpw<<<dim3((1024 * 640 + 255) / 256), 256, 0, stream>>>(W_in, WB1, 1024, 627, 1024, 640, 0);
  prep_mlpw<<<dim3((1024 * 1024 + 255) / 256), 256, 0, stream>>>(W_h1, WB2, 1024, 1024, 1024, 1024, 1);
  prep_mlpw<<<dim3((1024 * 1024 + 255) / 256), 256, 0, stream>>>(W_h2, WB3, 1024, 1024, 1024, 1024, 1);
  prep_mlpw<<<dim3((1280 * 1024 + 255) / 256), 256, 0, stream>>>(W_out, WB4, 1254, 1024, 1280, 1024, 2);
  prep_convw<<<dim3((192 * 96 + 255) / 256), 256, 0, stream>>>(cw2, CW2B, 180, 90, 192, 96);
  prep_convw<<<dim3((192 * 192 + 255) / 256), 256, 0, stream>>>(cw3, CW3B, 180, 180, 192, 192);
  prep_convw<<<dim3((192 * 192 + 255) / 256), 256, 0, stream>>>(cw4, CW4B, 180, 180, 192, 192);
  prep_convw<<<dim3((320 * 192 + 255) / 256), 256, 0, stream>>>(cw5, CW5B, 300, 180, 320, 192);
  prep_cb<<<1, 320, 0, stream>>>(cb2, cb3, cb4, cb5, CB2P, CB3P, CB4P, CB5P);

  // masked MLP (MFMA)
  mlp_mfma<<<dim3(16, 8), 256, 0, stream>>>(INB, WB1, b_in, nullptr, HB1, 1024, 640, 1);
  mlp_mfma<<<dim3(16, 8), 256, 0, stream>>>(HB1, WB2, b_h1, nullptr, HB2, 1024, 1024, 1);
  mlp_mfma<<<dim3(16, 8), 256, 0, stream>>>(HB2, WB3, b_h2, nullptr, HB3, 1024, 1024, 0);
  mlp_mfma<<<dim3(20, 8), 256, 0, stream>>>(HB3, WB4, b_out, OUTB, nullptr, 1254, 1024, 0);

  // conv1+bn1 folded via theta stats
  theta_stats<<<dim3(BATCH), 256, 0, stream>>>(OUTB, TST);
  finalize_conv1<<<1, 96, 0, stream>>>(TST, cw1, g1, be1, A1, B1g);

  // conv2 stats, then fused conv2->conv3 -> Y (y3) + stats3
  conv2_stats<<<dim3(10, BATCH), 256, 0, stream>>>(OUTB, A1, B1g, CW2B, CB2P, S2P, Q2P);
  finalize_bn_part<<<1, 192, 0, stream>>>(S2P, Q2P, g2, be2, A2, B2g);
  fused_conv23<<<dim3(10, BATCH), 256, 0, stream>>>(OUTB, A1, B1g, CW2B, CB2P, A2, B2g, CW3B, CB3P, Y, S3P, Q3P);
  finalize_bn_part<<<1, 192, 0, stream>>>(S3P, Q3P, g3, be3, A3, B3g);

  // conv4 in place
  conv4_ip<<<dim3(10, BATCH), 256, 0, stream>>>(Y, A3, B3g, CW4B, CB4P, S4P, Q4P);
  finalize_bn_part<<<1, 192, 0, stream>>>(S4P, Q4P, g4, be4, A4, B4g);

  // conv5 + register log_softmax + nll
  conv5_nll<<<dim3(20, BATCH), 256, 0, stream>>>(Y, A4, B4g, CW5B, CB5P, inputs, NLLB);

  // final assembly
  ll_pass1<<<dim3(BATCH), 256, 0, stream>>>(OUTB, NLLB, inputs, LLP, SC);
  ll_pass2<<<dim3(2), 256, 0, stream>>>(LLP, SC, (float*)d_out);
}

// Round 7
// 775.308 us; speedup vs baseline: 5.0946x; 1.0400x over previous
//
#include <hip/hip_runtime.h>
#include <hip/hip_bf16.h>
#include <math.h>

#define BATCH 512
#define NI 627
#define NH 1024
#define NOUTF 1254
#define LLEN 627
#define NBL (512 * 627)
#define EPSBN 1e-5f
#define NPART 64

typedef __attribute__((ext_vector_type(8))) short bf16x8;
typedef __attribute__((ext_vector_type(4))) float f32x4;
typedef unsigned int uint32;
typedef unsigned short ushort16;

__device__ inline short f2b(float x) {
  __hip_bfloat16 h = __float2bfloat16(x);
  return *reinterpret_cast<short*>(&h);
}
__device__ inline float b2f(short s) {
  return __uint_as_float(((uint32)(ushort16)s) << 16);
}
__device__ inline f32x4 mfma16(bf16x8 a, bf16x8 b, f32x4 c) {
  return __builtin_amdgcn_mfma_f32_16x16x32_bf16(a, b, c, 0, 0, 0);
}
// x1 fragment build: 8 channels k0..k0+7 of relu(a1*th+b1), packed bf16
__device__ inline bf16x8 buildx1(const float* __restrict__ A1v, const float* __restrict__ B1v,
                                 int k0, float th) {
  float4 alo = *reinterpret_cast<const float4*>(&A1v[k0]);
  float4 ahi = *reinterpret_cast<const float4*>(&A1v[k0 + 4]);
  float4 blo = *reinterpret_cast<const float4*>(&B1v[k0]);
  float4 bhi = *reinterpret_cast<const float4*>(&B1v[k0 + 4]);
  bf16x8 r;
  r[0] = f2b(fmaxf(fmaf(alo.x, th, blo.x), 0.f));
  r[1] = f2b(fmaxf(fmaf(alo.y, th, blo.y), 0.f));
  r[2] = f2b(fmaxf(fmaf(alo.z, th, blo.z), 0.f));
  r[3] = f2b(fmaxf(fmaf(alo.w, th, blo.w), 0.f));
  r[4] = f2b(fmaxf(fmaf(ahi.x, th, bhi.x), 0.f));
  r[5] = f2b(fmaxf(fmaf(ahi.y, th, bhi.y), 0.f));
  r[6] = f2b(fmaxf(fmaf(ahi.z, th, bhi.z), 0.f));
  r[7] = f2b(fmaxf(fmaf(ahi.w, th, bhi.w), 0.f));
  return r;
}

// ================= prep kernels =================
__global__ __launch_bounds__(256) void prep_inputs(const float* __restrict__ in, short* __restrict__ outp) {
  int i = blockIdx.x * 256 + threadIdx.x;
  if (i >= 512 * 640) return;
  int m = i / 640, k = i - m * 640;
  outp[i] = (k < NI) ? f2b(in[m * NI + k]) : (short)0;
}

__global__ __launch_bounds__(256) void prep_mlpw(const float* __restrict__ W, short* __restrict__ Wb,
                                                 int Nreal, int Kreal, int Npad, int Kpad, int mode) {
  int i = blockIdx.x * 256 + threadIdx.x;
  if (i >= Npad * Kpad) return;
  int n = i / Kpad, k = i - n * Kpad;
  float w = 0.f;
  if (n < Nreal && k < Kreal) {
    int od = n >= 627 ? n - 627 : n;
    int kd = k >= 627 ? k - 627 : k;
    bool keep = (mode == 0) ? (od >= k) : (mode == 1) ? (od >= kd) : (od > kd);
    if (keep) w = W[n * Kreal + k];
  }
  Wb[i] = f2b(w);
}

__global__ __launch_bounds__(256) void prep_convw(const float* __restrict__ W, short* __restrict__ Wb,
                                                  int Oreal, int Kreal, int Opad, int Kpad) {
  int i = blockIdx.x * 256 + threadIdx.x;
  if (i >= Opad * Kpad) return;
  int o = i / Kpad, k = i - o * Kpad;
  Wb[i] = (o < Oreal && k < Kreal) ? f2b(W[o * Kreal + k]) : (short)0;
}

__global__ void prep_cb(const float* __restrict__ cb2, const float* __restrict__ cb3,
                        const float* __restrict__ cb4, const float* __restrict__ cb5,
                        float* __restrict__ cb2p, float* __restrict__ cb3p,
                        float* __restrict__ cb4p, float* __restrict__ cb5p) {
  int c = threadIdx.x;  // 320 threads
  if (c < 192) {
    cb2p[c] = (c < 180) ? cb2[c] : 0.f;
    cb3p[c] = (c < 180) ? cb3[c] : 0.f;
    cb4p[c] = (c < 180) ? cb4[c] : 0.f;
  }
  if (c < 320) cb5p[c] = (c < 300) ? cb5[c] : 0.f;
}

// ================= MLP MFMA GEMM: C[M,Nreal] = act(A @ Wb^T + bias) =================
__global__ __launch_bounds__(256) void mlp_mfma(
    const short* __restrict__ A, const short* __restrict__ Wb, const float* __restrict__ bias,
    float* __restrict__ Cf, short* __restrict__ Cb, int Nreal, int Kpad, int relu)
{
  const int l = threadIdx.x & 63, wv = threadIdx.x >> 6;
  const int wm = wv >> 1, wn = wv & 1;
  const int m0 = blockIdx.y * 64 + wm * 32;
  const int n0 = blockIdx.x * 64 + wn * 32;
  const int lr = l & 15, lk = (l >> 4) * 8, lm4 = (l >> 4) * 4;
  f32x4 acc[2][2] = {};
  const int nk = Kpad >> 5;
  for (int ks = 0; ks < nk; ++ks) {
    int k0 = ks * 32 + lk;
    bf16x8 a0 = *reinterpret_cast<const bf16x8*>(&A[(size_t)(m0 + lr) * Kpad + k0]);
    bf16x8 a1 = *reinterpret_cast<const bf16x8*>(&A[(size_t)(m0 + 16 + lr) * Kpad + k0]);
    bf16x8 b0 = *reinterpret_cast<const bf16x8*>(&Wb[(size_t)(n0 + lr) * Kpad + k0]);
    bf16x8 b1 = *reinterpret_cast<const bf16x8*>(&Wb[(size_t)(n0 + 16 + lr) * Kpad + k0]);
    acc[0][0] = mfma16(a0, b0, acc[0][0]);
    acc[0][1] = mfma16(a0, b1, acc[0][1]);
    acc[1][0] = mfma16(a1, b0, acc[1][0]);
    acc[1][1] = mfma16(a1, b1, acc[1][1]);
  }
#pragma unroll
  for (int mi = 0; mi < 2; ++mi)
#pragma unroll
    for (int nj = 0; nj < 2; ++nj) {
      int n = n0 + nj * 16 + lr;
      if (n >= Nreal) continue;
      float bi = bias[n];
#pragma unroll
      for (int r = 0; r < 4; ++r) {
        int m = m0 + mi * 16 + lm4 + r;
        float v = acc[mi][nj][r] + bi;
        if (relu) v = fmaxf(v, 0.f);
        if (Cb) Cb[(size_t)m * Nreal + n] = f2b(v);
        else Cf[(size_t)m * Nreal + n] = v;
      }
    }
}

// ================= theta stats =================
__global__ __launch_bounds__(256) void theta_stats(const float* __restrict__ outb, float* __restrict__ tstat)
{
  int b = blockIdx.x;
  const float* th = outb + (size_t)b * NOUTF + NI;
  float s = 0.f, q = 0.f;
  for (int l = threadIdx.x; l < LLEN; l += 256) { float t = th[l]; s += t; q += t * t; }
  for (int off = 1; off < 64; off <<= 1) { s += __shfl_xor(s, off); q += __shfl_xor(q, off); }
  __shared__ float tmp[8];
  int w = threadIdx.x >> 6;
  if ((threadIdx.x & 63) == 0) { tmp[w] = s; tmp[4 + w] = q; }
  __syncthreads();
  if (threadIdx.x == 0) {
    atomicAdd(&tstat[0], tmp[0] + tmp[1] + tmp[2] + tmp[3]);
    atomicAdd(&tstat[1], tmp[4] + tmp[5] + tmp[6] + tmp[7]);
  }
}

__global__ void finalize_conv1(const float* __restrict__ tstat, const float* __restrict__ cw1,
                               const float* __restrict__ g1, const float* __restrict__ be1,
                               float* __restrict__ a1, float* __restrict__ b1)
{
  int c = threadIdx.x;  // 96
  if (c >= 96) return;
  if (c < 90) {
    float mt = tstat[0] / (float)NBL;
    float vt = tstat[1] / (float)NBL - mt * mt;
    float w = cw1[c];
    float rs = rsqrtf(w * w * vt + EPSBN);
    float a = w * g1[c] * rs;
    a1[c] = a;
    b1[c] = be1[c] - a * mt;
  } else { a1[c] = 0.f; b1[c] = 0.f; }
}

__global__ void finalize_bn_part(const float* __restrict__ Sp, const float* __restrict__ Qp,
                                 const float* __restrict__ g, const float* __restrict__ be,
                                 float* __restrict__ aP, float* __restrict__ bP)
{
  int c = threadIdx.x;  // 192
  if (c >= 192) return;
  if (c < 180) {
    float s = 0.f, q = 0.f;
    for (int p = 0; p < NPART; ++p) { s += Sp[p * 180 + c]; q += Qp[p * 180 + c]; }
    float m = s / (float)NBL;
    float v = q / (float)NBL - m * m;
    float a = g[c] * rsqrtf(v + EPSBN);
    aP[c] = a;
    bP[c] = be[c] - m * a;
  } else { aP[c] = 0.f; bP[c] = 0.f; }
}

// ================= conv2 stats-only (MFMA, zero LDS, x1 built in regs) =================
__global__ __launch_bounds__(256) void conv2_stats(
    const float* __restrict__ OUTB, const float* __restrict__ A1v, const float* __restrict__ B1v,
    const short* __restrict__ cw2b, const float* __restrict__ cb2p,
    float* __restrict__ Sp, float* __restrict__ Qp)
{
  const int tid = threadIdx.x;
  const int b = blockIdx.y, j0 = blockIdx.x * 64;
  const int l = tid & 63, wv = tid >> 6, wm = wv >> 1, wn = wv & 1;
  const int lr = l & 15, lk = (l >> 4) * 8, lm4 = (l >> 4) * 4;
  const int jj0 = j0 + wn * 32 + lr, jj1 = jj0 + 16;
  const float th0 = (jj0 < LLEN) ? OUTB[(size_t)b * NOUTF + NI + jj0] : 0.f;
  const float th1 = (jj1 < LLEN) ? OUTB[(size_t)b * NOUTF + NI + jj1] : 0.f;
  f32x4 acc[6][2] = {};
#pragma unroll
  for (int ks = 0; ks < 3; ++ks) {
    int k0 = ks * 32 + lk;
    bf16x8 b0 = buildx1(A1v, B1v, k0, th0);
    bf16x8 b1 = buildx1(A1v, B1v, k0, th1);
#pragma unroll
    for (int mi = 0; mi < 6; ++mi) {
      bf16x8 av = *reinterpret_cast<const bf16x8*>(&cw2b[(wm * 96 + mi * 16 + lr) * 96 + k0]);
      acc[mi][0] = mfma16(av, b0, acc[mi][0]);
      acc[mi][1] = mfma16(av, b1, acc[mi][1]);
    }
  }
  int part = (blockIdx.y * gridDim.x + blockIdx.x) & (NPART - 1);
#pragma unroll
  for (int mi = 0; mi < 6; ++mi) {
    int m0c = wm * 96 + mi * 16 + lm4;
    float s4[4] = {0.f, 0.f, 0.f, 0.f}, q4[4] = {0.f, 0.f, 0.f, 0.f};
#pragma unroll
    for (int nj = 0; nj < 2; ++nj) {
      int jj = j0 + wn * 32 + nj * 16 + lr;
      if (jj < LLEN) {
#pragma unroll
        for (int r = 0; r < 4; ++r) {
          float v = acc[mi][nj][r] + cb2p[m0c + r];
          s4[r] += v; q4[r] += v * v;
        }
      }
    }
#pragma unroll
    for (int off = 1; off < 16; off <<= 1)
#pragma unroll
      for (int r = 0; r < 4; ++r) { s4[r] += __shfl_xor(s4[r], off); q4[r] += __shfl_xor(q4[r], off); }
    if (lr == 0) {
#pragma unroll
      for (int r = 0; r < 4; ++r) {
        int o = m0c + r;
        if (o < 180) {
          atomicAdd(&Sp[part * 180 + o], s4[r]);
          atomicAdd(&Qp[part * 180 + o], q4[r]);
        }
      }
    }
  }
}

// ================= fused conv2 -> bn2 -> relu -> conv3, write Y (coalesced) + stats3 =========
__global__ __launch_bounds__(256) void fused_conv23(
    const float* __restrict__ OUTB, const float* __restrict__ A1v, const float* __restrict__ B1v,
    const short* __restrict__ cw2b, const float* __restrict__ cb2p,
    const float* __restrict__ a2, const float* __restrict__ b2,
    const short* __restrict__ cw3b, const float* __restrict__ cb3p,
    short* __restrict__ Y, float* __restrict__ Sp, float* __restrict__ Qp)
{
  __shared__ short xT2[64][200];  // x2 staging, then reused as y3 output staging [64][0..191]
  const int tid = threadIdx.x;
  const int b = blockIdx.y, j0 = blockIdx.x * 64;
  const int l = tid & 63, wv = tid >> 6, wm = wv >> 1, wn = wv & 1;
  const int lr = l & 15, lk = (l >> 4) * 8, lm4 = (l >> 4) * 4;
  const int jj0 = j0 + wn * 32 + lr, jj1 = jj0 + 16;
  const float th0 = (jj0 < LLEN) ? OUTB[(size_t)b * NOUTF + NI + jj0] : 0.f;
  const float th1 = (jj1 < LLEN) ? OUTB[(size_t)b * NOUTF + NI + jj1] : 0.f;
  // conv2 (x1 built in registers from theta)
  f32x4 acc[6][2] = {};
#pragma unroll
  for (int ks = 0; ks < 3; ++ks) {
    int k0 = ks * 32 + lk;
    bf16x8 b0 = buildx1(A1v, B1v, k0, th0);
    bf16x8 b1 = buildx1(A1v, B1v, k0, th1);
#pragma unroll
    for (int mi = 0; mi < 6; ++mi) {
      bf16x8 av = *reinterpret_cast<const bf16x8*>(&cw2b[(wm * 96 + mi * 16 + lr) * 96 + k0]);
      acc[mi][0] = mfma16(av, b0, acc[mi][0]);
      acc[mi][1] = mfma16(av, b1, acc[mi][1]);
    }
  }
  // x2 = relu(a2*(y2+cb2)+b2) -> xT2
#pragma unroll
  for (int mi = 0; mi < 6; ++mi) {
    int m0c = wm * 96 + mi * 16 + lm4;
#pragma unroll
    for (int nj = 0; nj < 2; ++nj) {
      int col = wn * 32 + nj * 16 + lr;
      float y0 = acc[mi][nj][0] + cb2p[m0c + 0];
      float y1 = acc[mi][nj][1] + cb2p[m0c + 1];
      float y2v = acc[mi][nj][2] + cb2p[m0c + 2];
      float y3v = acc[mi][nj][3] + cb2p[m0c + 3];
      float x0 = fmaxf(fmaf(a2[m0c + 0], y0, b2[m0c + 0]), 0.f);
      float x1 = fmaxf(fmaf(a2[m0c + 1], y1, b2[m0c + 1]), 0.f);
      float x2 = fmaxf(fmaf(a2[m0c + 2], y2v, b2[m0c + 2]), 0.f);
      float x3 = fmaxf(fmaf(a2[m0c + 3], y3v, b2[m0c + 3]), 0.f);
      uint2 w2;
      w2.x = (uint32)(ushort16)f2b(x0) | ((uint32)(ushort16)f2b(x1) << 16);
      w2.y = (uint32)(ushort16)f2b(x2) | ((uint32)(ushort16)f2b(x3) << 16);
      *reinterpret_cast<uint2*>(&xT2[col][m0c]) = w2;
    }
  }
  __syncthreads();
  // conv3
  f32x4 acc2[6][2] = {};
#pragma unroll
  for (int ks = 0; ks < 6; ++ks) {
    int k0 = ks * 32 + lk;
    bf16x8 b0 = *reinterpret_cast<const bf16x8*>(&xT2[wn * 32 + lr][k0]);
    bf16x8 b1 = *reinterpret_cast<const bf16x8*>(&xT2[wn * 32 + 16 + lr][k0]);
#pragma unroll
    for (int mi = 0; mi < 6; ++mi) {
      bf16x8 av = *reinterpret_cast<const bf16x8*>(&cw3b[(wm * 96 + mi * 16 + lr) * 192 + k0]);
      acc2[mi][0] = mfma16(av, b0, acc2[mi][0]);
      acc2[mi][1] = mfma16(av, b1, acc2[mi][1]);
    }
  }
  __syncthreads();  // all conv3 reads of xT2 done; reuse as y3 staging
  int part = (blockIdx.y * gridDim.x + blockIdx.x) & (NPART - 1);
#pragma unroll
  for (int mi = 0; mi < 6; ++mi) {
    int m0c = wm * 96 + mi * 16 + lm4;
    float s4[4] = {0.f, 0.f, 0.f, 0.f}, q4[4] = {0.f, 0.f, 0.f, 0.f};
#pragma unroll
    for (int nj = 0; nj < 2; ++nj) {
      int col = wn * 32 + nj * 16 + lr;
      int jj = j0 + col;
      float v0 = acc2[mi][nj][0] + cb3p[m0c + 0];
      float v1 = acc2[mi][nj][1] + cb3p[m0c + 1];
      float v2 = acc2[mi][nj][2] + cb3p[m0c + 2];
      float v3 = acc2[mi][nj][3] + cb3p[m0c + 3];
      if (jj < LLEN) {
        s4[0] += v0; q4[0] += v0 * v0;
        s4[1] += v1; q4[1] += v1 * v1;
        s4[2] += v2; q4[2] += v2 * v2;
        s4[3] += v3; q4[3] += v3 * v3;
      }
      uint2 w2;
      w2.x = (uint32)(ushort16)f2b(v0) | ((uint32)(ushort16)f2b(v1) << 16);
      w2.y = (uint32)(ushort16)f2b(v2) | ((uint32)(ushort16)f2b(v3) << 16);
      *reinterpret_cast<uint2*>(&xT2[col][m0c]) = w2;
    }
#pragma unroll
    for (int off = 1; off < 16; off <<= 1)
#pragma unroll
      for (int r = 0; r < 4; ++r) { s4[r] += __shfl_xor(s4[r], off); q4[r] += __shfl_xor(q4[r], off); }
    if (lr == 0) {
#pragma unroll
      for (int r = 0; r < 4; ++r) {
        int o = m0c + r;
        if (o < 180) {
          atomicAdd(&Sp[part * 180 + o], s4[r]);
          atomicAdd(&Qp[part * 180 + o], q4[r]);
        }
      }
    }
  }
  __syncthreads();
  // coalesced copy out: 64 rows x 192 shorts
  for (int f = tid; f < 64 * 24; f += 256) {
    int row = f / 24, c0 = (f - row * 24) * 8;
    int jj = j0 + row;
    if (jj < LLEN) {
      bf16x8 v = *reinterpret_cast<const bf16x8*>(&xT2[row][c0]);
      *reinterpret_cast<bf16x8*>(&Y[((size_t)b * 627 + jj) * 192 + c0]) = v;
    }
  }
}

// ================= conv4 in place on Y (MFMA, coalesced output) =================
__global__ __launch_bounds__(256) void conv4_ip(
    short* __restrict__ Y, const float* __restrict__ a3, const float* __restrict__ b3,
    const short* __restrict__ cw4b, const float* __restrict__ cb4p,
    float* __restrict__ Sp, float* __restrict__ Qp)
{
  __shared__ float ab[384];
  __shared__ short xT[64][200];  // x3 staging, then y4 output staging
  const int tid = threadIdx.x;
  const int b = blockIdx.y, j0 = blockIdx.x * 64;
  for (int t = tid; t < 384; t += 256) ab[t] = (t < 192) ? a3[t] : b3[t - 192];
  __syncthreads();
  for (int t = tid; t < 64 * 24; t += 256) {
    int col = t / 24, oct = t - col * 24;
    int jj = j0 + col;
    int c0 = oct * 8;
    bf16x8 pk;
    if (jj < LLEN) {
      bf16x8 raw = *reinterpret_cast<const bf16x8*>(&Y[((size_t)b * 627 + jj) * 192 + c0]);
#pragma unroll
      for (int i = 0; i < 8; ++i)
        pk[i] = f2b(fmaxf(fmaf(ab[c0 + i], b2f(raw[i]), ab[192 + c0 + i]), 0.f));
    } else {
#pragma unroll
      for (int i = 0; i < 8; ++i) pk[i] = 0;
    }
    *reinterpret_cast<bf16x8*>(&xT[col][c0]) = pk;
  }
  __syncthreads();
  const int l = tid & 63, wv = tid >> 6, wm = wv >> 1, wn = wv & 1;
  const int lr = l & 15, lk = (l >> 4) * 8, lm4 = (l >> 4) * 4;
  f32x4 acc[6][2] = {};
#pragma unroll
  for (int ks = 0; ks < 6; ++ks) {
    int k0 = ks * 32 + lk;
    bf16x8 b0 = *reinterpret_cast<const bf16x8*>(&xT[wn * 32 + lr][k0]);
    bf16x8 b1 = *reinterpret_cast<const bf16x8*>(&xT[wn * 32 + 16 + lr][k0]);
#pragma unroll
    for (int mi = 0; mi < 6; ++mi) {
      bf16x8 av = *reinterpret_cast<const bf16x8*>(&cw4b[(wm * 96 + mi * 16 + lr) * 192 + k0]);
      acc[mi][0] = mfma16(av, b0, acc[mi][0]);
      acc[mi][1] = mfma16(av, b1, acc[mi][1]);
    }
  }
  __syncthreads();  // input reads done; reuse xT as y4 staging
  int part = (blockIdx.y * gridDim.x + blockIdx.x) & (NPART - 1);
#pragma unroll
  for (int mi = 0; mi < 6; ++mi) {
    int m0c = wm * 96 + mi * 16 + lm4;
    float s4[4] = {0.f, 0.f, 0.f, 0.f}, q4[4] = {0.f, 0.f, 0.f, 0.f};
#pragma unroll
    for (int nj = 0; nj < 2; ++nj) {
      int col = wn * 32 + nj * 16 + lr;
      int jj = j0 + col;
      float v0 = acc[mi][nj][0] + cb4p[m0c + 0];
      float v1 = acc[mi][nj][1] + cb4p[m0c + 1];
      float v2 = acc[mi][nj][2] + cb4p[m0c + 2];
      float v3 = acc[mi][nj][3] + cb4p[m0c + 3];
      if (jj < LLEN) {
        s4[0] += v0; q4[0] += v0 * v0;
        s4[1] += v1; q4[1] += v1 * v1;
        s4[2] += v2; q4[2] += v2 * v2;
        s4[3] += v3; q4[3] += v3 * v3;
      }
      uint2 w2;
      w2.x = (uint32)(ushort16)f2b(v0) | ((uint32)(ushort16)f2b(v1) << 16);
      w2.y = (uint32)(ushort16)f2b(v2) | ((uint32)(ushort16)f2b(v3) << 16);
      *reinterpret_cast<uint2*>(&xT[col][m0c]) = w2;
    }
#pragma unroll
    for (int off = 1; off < 16; off <<= 1)
#pragma unroll
      for (int r = 0; r < 4; ++r) { s4[r] += __shfl_xor(s4[r], off); q4[r] += __shfl_xor(q4[r], off); }
    if (lr == 0) {
#pragma unroll
      for (int r = 0; r < 4; ++r) {
        int o = m0c + r;
        if (o < 180) {
          atomicAdd(&Sp[part * 180 + o], s4[r]);
          atomicAdd(&Qp[part * 180 + o], q4[r]);
        }
      }
    }
  }
  __syncthreads();
  for (int f = tid; f < 64 * 24; f += 256) {
    int row = f / 24, c0 = (f - row * 24) * 8;
    int jj = j0 + row;
    if (jj < LLEN) {
      bf16x8 v = *reinterpret_cast<const bf16x8*>(&xT[row][c0]);
      *reinterpret_cast<bf16x8*>(&Y[((size_t)b * 627 + jj) * 192 + c0]) = v;
    }
  }
}

// ================= conv5 (MFMA) + register log_softmax + NLL =================
__global__ __launch_bounds__(256) void conv5_nll(
    const short* __restrict__ Y, const float* __restrict__ a4, const float* __restrict__ b4,
    const short* __restrict__ cw5b, const float* __restrict__ cb5p,
    const float* __restrict__ inputs, float* __restrict__ nll)
{
  __shared__ float ab[384];
  __shared__ short xT[32][200];
  __shared__ float wmax[4][32];
  __shared__ float wsum[4][32];
  __shared__ float ptgt[32];
  __shared__ int tg[32];
  const int tid = threadIdx.x;
  const int b = blockIdx.y, l0 = blockIdx.x * 32;
  for (int t = tid; t < 384; t += 256) ab[t] = (t < 192) ? a4[t] : b4[t - 192];
  if (tid < 32) {
    int jj = l0 + tid;
    tg[tid] = (jj < LLEN) ? (int)inputs[(size_t)b * NI + jj] : 0;
  }
  __syncthreads();
  for (int t = tid; t < 32 * 24; t += 256) {
    int col = t / 24, oct = t - col * 24;
    int jj = l0 + col;
    int c0 = oct * 8;
    bf16x8 pk;
    if (jj < LLEN) {
      bf16x8 raw = *reinterpret_cast<const bf16x8*>(&Y[((size_t)b * 627 + jj) * 192 + c0]);
#pragma unroll
      for (int i = 0; i < 8; ++i)
        pk[i] = f2b(fmaxf(fmaf(ab[c0 + i], b2f(raw[i]), ab[192 + c0 + i]), 0.f));
    } else {
#pragma unroll
      for (int i = 0; i < 8; ++i) pk[i] = 0;
    }
    *reinterpret_cast<bf16x8*>(&xT[col][c0]) = pk;
  }
  __syncthreads();
  const int l = tid & 63, wv = tid >> 6;
  const int lr = l & 15, lk = (l >> 4) * 8, lm4 = (l >> 4) * 4;
  const int mf0 = wv * 5;
  f32x4 acc[5][2] = {};
#pragma unroll
  for (int ks = 0; ks < 6; ++ks) {
    int k0 = ks * 32 + lk;
    bf16x8 b0 = *reinterpret_cast<const bf16x8*>(&xT[lr][k0]);
    bf16x8 b1 = *reinterpret_cast<const bf16x8*>(&xT[16 + lr][k0]);
#pragma unroll
    for (int mi = 0; mi < 5; ++mi) {
      bf16x8 av = *reinterpret_cast<const bf16x8*>(&cw5b[((mf0 + mi) * 16 + lr) * 192 + k0]);
      acc[mi][0] = mfma16(av, b0, acc[mi][0]);
      acc[mi][1] = mfma16(av, b1, acc[mi][1]);
    }
  }
  float vv[5][2][4];
  float vmax0 = -1e30f, vmax1 = -1e30f;
#pragma unroll
  for (int mi = 0; mi < 5; ++mi) {
#pragma unroll
    for (int r = 0; r < 4; ++r) {
      int m = (mf0 + mi) * 16 + lm4 + r;
      float bi = cb5p[m];
      float v0 = (m < 300) ? (acc[mi][0][r] + bi) : -1e30f;
      float v1 = (m < 300) ? (acc[mi][1][r] + bi) : -1e30f;
      vv[mi][0][r] = v0;
      vv[mi][1][r] = v1;
      vmax0 = fmaxf(vmax0, v0);
      vmax1 = fmaxf(vmax1, v1);
    }
  }
  {
    int t0 = tg[lr], t1 = tg[16 + lr];
#pragma unroll
    for (int mi = 0; mi < 5; ++mi) {
#pragma unroll
      for (int r = 0; r < 4; ++r) {
        int m = (mf0 + mi) * 16 + lm4 + r;
        if (m == t0) ptgt[lr] = vv[mi][0][r];
        if (m == t1) ptgt[16 + lr] = vv[mi][1][r];
      }
    }
  }
  vmax0 = fmaxf(vmax0, __shfl_xor(vmax0, 16)); vmax0 = fmaxf(vmax0, __shfl_xor(vmax0, 32));
  vmax1 = fmaxf(vmax1, __shfl_xor(vmax1, 16)); vmax1 = fmaxf(vmax1, __shfl_xor(vmax1, 32));
  if (l < 16) { wmax[wv][lr] = vmax0; wmax[wv][16 + lr] = vmax1; }
  __syncthreads();
  float gmax0 = fmaxf(fmaxf(wmax[0][lr], wmax[1][lr]), fmaxf(wmax[2][lr], wmax[3][lr]));
  float gmax1 = fmaxf(fmaxf(wmax[0][16 + lr], wmax[1][16 + lr]), fmaxf(wmax[2][16 + lr], wmax[3][16 + lr]));
  float vs0 = 0.f, vs1 = 0.f;
#pragma unroll
  for (int mi = 0; mi < 5; ++mi) {
#pragma unroll
    for (int r = 0; r < 4; ++r) {
      vs0 += __expf(vv[mi][0][r] - gmax0);
      vs1 += __expf(vv[mi][1][r] - gmax1);
    }
  }
  vs0 += __shfl_xor(vs0, 16); vs0 += __shfl_xor(vs0, 32);
  vs1 += __shfl_xor(vs1, 16); vs1 += __shfl_xor(vs1, 32);
  if (l < 16) { wsum[wv][lr] = vs0; wsum[wv][16 + lr] = vs1; }
  __syncthreads();
  if (tid < 32) {
    int jj = l0 + tid;
    if (jj < LLEN) {
      float gm = fmaxf(fmaxf(wmax[0][tid], wmax[1][tid]), fmaxf(wmax[2][tid], wmax[3][tid]));
      float gs = wsum[0][tid] + wsum[1][tid] + wsum[2][tid] + wsum[3][tid];
      nll[(size_t)b * LLEN + jj] = gm + logf(gs) - ptgt[tid];
    }
  }
}

// ================= final assembly =================
__global__ __launch_bounds__(256) void ll_pass1(
    const float* __restrict__ outb, const float* __restrict__ nll,
    const float* __restrict__ inputs, float* __restrict__ llp, float* __restrict__ sc)
{
  int b = blockIdx.x;
  float s = 0.f;
  for (int l = 2 + (int)threadIdx.x; l < LLEN; l += 256) {
    float graw = outb[(size_t)b * NOUTF + l];
    float sg = 1.f / (1.f + expf(-graw));
    float term;
    if (inputs[(size_t)b * NI + l] > 0.f)
      term = 0.1f * logf(sg + 1e-10f) - nll[(size_t)b * LLEN + l];
    else
      term = 0.1f * logf(1.f - sg + 1e-10f);
    s += term;
  }
  for (int off = 1; off < 64; off <<= 1) s += __shfl_xor(s, off);
  __shared__ float tmp[4];
  if ((threadIdx.x & 63) == 0) tmp[threadIdx.x >> 6] = s;
  __syncthreads();
  if (threadIdx.x == 0) {
    llp[b] = tmp[0] + tmp[1] + tmp[2] + tmp[3];
    atomicAdd(sc, nll[(size_t)b * LLEN] + nll[(size_t)b * LLEN + 1]);
  }
}

__global__ void ll_pass2(const float* __restrict__ llp, const float* __restrict__ sc, float* __restrict__ outp)
{
  int i = blockIdx.x * blockDim.x + threadIdx.x;
  if (i < BATCH) outp[i] = llp[i] - sc[0] * (1.f / 1024.f);
}

extern "C" void kernel_launch(void* const* d_in, const int* in_sizes, int n_in,
                              void* d_out, int out_size, void* d_ws, size_t ws_size,
                              hipStream_t stream)
{
  const float* inputs = (const float*)d_in[0];
  const float* W_in = (const float*)d_in[1];
  const float* b_in = (const float*)d_in[2];
  const float* W_h1 = (const float*)d_in[3];
  const float* b_h1 = (const float*)d_in[4];
  const float* W_h2 = (const float*)d_in[5];
  const float* b_h2 = (const float*)d_in[6];
  const float* W_out = (const float*)d_in[7];
  const float* b_out = (const float*)d_in[8];
  const float* cw1 = (const float*)d_in[9];
  const float* g1 = (const float*)d_in[11];
  const float* be1 = (const float*)d_in[12];
  const float* cw2 = (const float*)d_in[13];
  const float* cb2 = (const float*)d_in[14];
  const float* g2 = (const float*)d_in[15];
  const float* be2 = (const float*)d_in[16];
  const float* cw3 = (const float*)d_in[17];
  const float* cb3 = (const float*)d_in[18];
  const float* g3 = (const float*)d_in[19];
  const float* be3 = (const float*)d_in[20];
  const float* cw4 = (const float*)d_in[21];
  const float* cb4 = (const float*)d_in[22];
  const float* g4 = (const float*)d_in[23];
  const float* be4 = (const float*)d_in[24];
  const float* cw5 = (const float*)d_in[25];
  const float* cb5 = (const float*)d_in[26];

  char* p = (char*)d_ws;
  short* Y = (short*)p;    p += (size_t)512 * 627 * 192 * 2;
  short* INB = (short*)p;  p += (size_t)512 * 640 * 2;
  short* HB1 = (short*)p;  p += (size_t)512 * 1024 * 2;
  short* HB2 = (short*)p;  p += (size_t)512 * 1024 * 2;
  short* HB3 = (short*)p;  p += (size_t)512 * 1024 * 2;
  short* WB1 = (short*)p;  p += (size_t)1024 * 640 * 2;
  short* WB2 = (short*)p;  p += (size_t)1024 * 1024 * 2;
  short* WB3 = (short*)p;  p += (size_t)1024 * 1024 * 2;
  short* WB4 = (short*)p;  p += (size_t)1280 * 1024 * 2;
  short* CW2B = (short*)p; p += (size_t)192 * 96 * 2;
  short* CW3B = (short*)p; p += (size_t)192 * 192 * 2;
  short* CW4B = (short*)p; p += (size_t)192 * 192 * 2;
  short* CW5B = (short*)p; p += (size_t)320 * 192 * 2;
  float* fp = (float*)p;
  float* OUTB = fp;  fp += (size_t)512 * 1254;
  float* NLLB = fp;  fp += 321028;  // 512*627 rounded up to multiple of 4 (16B alignment)
  float* LLP = fp;   fp += 512;
  float* A1 = fp;    fp += 96;
  float* B1g = fp;   fp += 96;
  float* A2 = fp;    fp += 192;
  float* B2g = fp;   fp += 192;
  float* A3 = fp;    fp += 192;
  float* B3g = fp;   fp += 192;
  float* A4 = fp;    fp += 192;
  float* B4g = fp;   fp += 192;
  float* CB2P = fp;  fp += 192;
  float* CB3P = fp;  fp += 192;
  float* CB4P = fp;  fp += 192;
  float* CB5P = fp;  fp += 320;
  float* STAT = fp;  // 4 + 6*NPART*180
  float* TST = STAT;
  float* SC = STAT + 2;
  float* S2P = STAT + 4;
  float* Q2P = S2P + NPART * 180;
  float* S3P = Q2P + NPART * 180;
  float* Q3P = S3P + NPART * 180;
  float* S4P = Q3P + NPART * 180;
  float* Q4P = S4P + NPART * 180;

  hipMemsetAsync(STAT, 0, (4 + 6 * (size_t)NPART * 180) * sizeof(float), stream);

  // prep: inputs, masked MLP weights, conv weights, padded biases
  prep_inputs<<<dim3((512 * 640 + 255) / 256), 256, 0, stream>>>(inputs, INB);
  prep_mlpw<<<dim3((1024 * 640 + 255) / 256), 256, 0, stream>>>(W_in, WB1, 1024, 627, 1024, 640, 0);
  prep_mlpw<<<dim3((1024 * 1024 + 255) / 256), 256, 0, stream>>>(W_h1, WB2, 1024, 1024, 1024, 1024, 1);
  prep_mlpw<<<dim3((1024 * 1024 + 255) / 256), 256, 0, stream>>>(W_h2, WB3, 1024, 1024, 1024, 1024, 1);
  prep_mlpw<<<dim3((1280 * 1024 + 255) / 256), 256, 0, stream>>>(W_out, WB4, 1254, 1024, 1280, 1024, 2);
  prep_convw<<<dim3((192 * 96 + 255) / 256), 256, 0, stream>>>(cw2, CW2B, 180, 90, 192, 96);
  prep_convw<<<dim3((192 * 192 + 255) / 256), 256, 0, stream>>>(cw3, CW3B, 180, 180, 192, 192);
  prep_convw<<<dim3((192 * 192 + 255) / 256), 256, 0, stream>>>(cw4, CW4B, 180, 180, 192, 192);
  prep_convw<<<dim3((320 * 192 + 255) / 256), 256, 0, stream>>>(cw5, CW5B, 300, 180, 320, 192);
  prep_cb<<<1, 320, 0, stream>>>(cb2, cb3, cb4, cb5, CB2P, CB3P, CB4P, CB5P);

  // masked MLP (MFMA)
  mlp_mfma<<<dim3(16, 8), 256, 0, stream>>>(INB, WB1, b_in, nullptr, HB1, 1024, 640, 1);
  mlp_mfma<<<dim3(16, 8), 256, 0, stream>>>(HB1, WB2, b_h1, nullptr, HB2, 1024, 1024, 1);
  mlp_mfma<<<dim3(16, 8), 256, 0, stream>>>(HB2, WB3, b_h2, nullptr, HB3, 1024, 1024, 0);
  mlp_mfma<<<dim3(20, 8), 256, 0, stream>>>(HB3, WB4, b_out, OUTB, nullptr, 1254, 1024, 0);

  // conv1+bn1 folded via theta stats
  theta_stats<<<dim3(BATCH), 256, 0, stream>>>(OUTB, TST);
  finalize_conv1<<<1, 96, 0, stream>>>(TST, cw1, g1, be1, A1, B1g);

  // conv2 stats, then fused conv2->conv3 -> Y (y3) + stats3
  conv2_stats<<<dim3(10, BATCH), 256, 0, stream>>>(OUTB, A1, B1g, CW2B, CB2P, S2P, Q2P);
  finalize_bn_part<<<1, 192, 0, stream>>>(S2P, Q2P, g2, be2, A2, B2g);
  fused_conv23<<<dim3(10, BATCH), 256, 0, stream>>>(OUTB, A1, B1g, CW2B, CB2P, A2, B2g, CW3B, CB3P, Y, S3P, Q3P);
  finalize_bn_part<<<1, 192, 0, stream>>>(S3P, Q3P, g3, be3, A3, B3g);

  // conv4 in place
  conv4_ip<<<dim3(10, BATCH), 256, 0, stream>>>(Y, A3, B3g, CW4B, CB4P, S4P, Q4P);
  finalize_bn_part<<<1, 192, 0, stream>>>(S4P, Q4P, g4, be4, A4, B4g);

  // conv5 + register log_softmax + nll
  conv5_nll<<<dim3(20, BATCH), 256, 0, stream>>>(Y, A4, B4g, CW5B, CB5P, inputs, NLLB);

  // final assembly
  ll_pass1<<<dim3(BATCH), 256, 0, stream>>>(OUTB, NLLB, inputs, LLP, SC);
  ll_pass2<<<dim3(2), 256, 0, stream>>>(LLP, SC, (float*)d_out);
}

// Round 8
// 710.306 us; speedup vs baseline: 5.5608x; 1.0915x over previous
//
#include <hip/hip_runtime.h>
#include <hip/hip_bf16.h>
#include <math.h>

#define BATCH 512
#define NI 627
#define NH 1024
#define NOUTF 1254
#define LLEN 627
#define NBL (512 * 627)
#define EPSBN 1e-5f
#define NSLOT 10240   // 2560 blocks * 4 wn-waves
#define NRED 40       // stage-1 reduction blocks (10240/256)

typedef __attribute__((ext_vector_type(8))) short bf16x8;
typedef __attribute__((ext_vector_type(4))) float f32x4;
typedef unsigned int uint32;
typedef unsigned short ushort16;

__device__ inline short f2b(float x) {
  __hip_bfloat16 h = __float2bfloat16(x);
  return *reinterpret_cast<short*>(&h);
}
__device__ inline float b2f(short s) {
  return __uint_as_float(((uint32)(ushort16)s) << 16);
}
__device__ inline f32x4 mfma16(bf16x8 a, bf16x8 b, f32x4 c) {
  return __builtin_amdgcn_mfma_f32_16x16x32_bf16(a, b, c, 0, 0, 0);
}
// 8 channels k0..k0+7 of relu(a1*th+b1), packed bf16
__device__ inline bf16x8 buildx1(const float* __restrict__ A1v, const float* __restrict__ B1v,
                                 int k0, float th) {
  float4 alo = *reinterpret_cast<const float4*>(&A1v[k0]);
  float4 ahi = *reinterpret_cast<const float4*>(&A1v[k0 + 4]);
  float4 blo = *reinterpret_cast<const float4*>(&B1v[k0]);
  float4 bhi = *reinterpret_cast<const float4*>(&B1v[k0 + 4]);
  bf16x8 r;
  r[0] = f2b(fmaxf(fmaf(alo.x, th, blo.x), 0.f));
  r[1] = f2b(fmaxf(fmaf(alo.y, th, blo.y), 0.f));
  r[2] = f2b(fmaxf(fmaf(alo.z, th, blo.z), 0.f));
  r[3] = f2b(fmaxf(fmaf(alo.w, th, blo.w), 0.f));
  r[4] = f2b(fmaxf(fmaf(ahi.x, th, bhi.x), 0.f));
  r[5] = f2b(fmaxf(fmaf(ahi.y, th, bhi.y), 0.f));
  r[6] = f2b(fmaxf(fmaf(ahi.z, th, bhi.z), 0.f));
  r[7] = f2b(fmaxf(fmaf(ahi.w, th, bhi.w), 0.f));
  return r;
}

// ================= prep kernels =================
__global__ __launch_bounds__(256) void prep_inputs(const float* __restrict__ in, short* __restrict__ outp) {
  int i = blockIdx.x * 256 + threadIdx.x;
  if (i >= 512 * 640) return;
  int m = i / 640, k = i - m * 640;
  outp[i] = (k < NI) ? f2b(in[m * NI + k]) : (short)0;
}

__global__ __launch_bounds__(256) void prep_mlpw(const float* __restrict__ W, short* __restrict__ Wb,
                                                 int Nreal, int Kreal, int Npad, int Kpad, int mode) {
  int i = blockIdx.x * 256 + threadIdx.x;
  if (i >= Npad * Kpad) return;
  int n = i / Kpad, k = i - n * Kpad;
  float w = 0.f;
  if (n < Nreal && k < Kreal) {
    int od = n >= 627 ? n - 627 : n;
    int kd = k >= 627 ? k - 627 : k;
    bool keep = (mode == 0) ? (od >= k) : (mode == 1) ? (od >= kd) : (od > kd);
    if (keep) w = W[n * Kreal + k];
  }
  Wb[i] = f2b(w);
}

__global__ __launch_bounds__(256) void prep_convw(const float* __restrict__ W, short* __restrict__ Wb,
                                                  int Oreal, int Kreal, int Opad, int Kpad) {
  int i = blockIdx.x * 256 + threadIdx.x;
  if (i >= Opad * Kpad) return;
  int o = i / Kpad, k = i - o * Kpad;
  Wb[i] = (o < Oreal && k < Kreal) ? f2b(W[o * Kreal + k]) : (short)0;
}

__global__ void prep_cb(const float* __restrict__ cb2, const float* __restrict__ cb3,
                        const float* __restrict__ cb4, const float* __restrict__ cb5,
                        float* __restrict__ cb2p, float* __restrict__ cb3p,
                        float* __restrict__ cb4p, float* __restrict__ cb5p) {
  int c = threadIdx.x;  // 320 threads
  if (c < 192) {
    cb2p[c] = (c < 180) ? cb2[c] : 0.f;
    cb3p[c] = (c < 180) ? cb3[c] : 0.f;
    cb4p[c] = (c < 180) ? cb4[c] : 0.f;
  }
  if (c < 320) cb5p[c] = (c < 300) ? cb5[c] : 0.f;
}

// ================= MLP MFMA GEMM =================
__global__ __launch_bounds__(256) void mlp_mfma(
    const short* __restrict__ A, const short* __restrict__ Wb, const float* __restrict__ bias,
    float* __restrict__ Cf, short* __restrict__ Cb, int Nreal, int Kpad, int relu)
{
  const int l = threadIdx.x & 63, wv = threadIdx.x >> 6;
  const int wm = wv >> 1, wn = wv & 1;
  const int m0 = blockIdx.y * 64 + wm * 32;
  const int n0 = blockIdx.x * 64 + wn * 32;
  const int lr = l & 15, lk = (l >> 4) * 8, lm4 = (l >> 4) * 4;
  f32x4 acc[2][2] = {};
  const int nk = Kpad >> 5;
  for (int ks = 0; ks < nk; ++ks) {
    int k0 = ks * 32 + lk;
    bf16x8 a0 = *reinterpret_cast<const bf16x8*>(&A[(size_t)(m0 + lr) * Kpad + k0]);
    bf16x8 a1 = *reinterpret_cast<const bf16x8*>(&A[(size_t)(m0 + 16 + lr) * Kpad + k0]);
    bf16x8 b0 = *reinterpret_cast<const bf16x8*>(&Wb[(size_t)(n0 + lr) * Kpad + k0]);
    bf16x8 b1 = *reinterpret_cast<const bf16x8*>(&Wb[(size_t)(n0 + 16 + lr) * Kpad + k0]);
    acc[0][0] = mfma16(a0, b0, acc[0][0]);
    acc[0][1] = mfma16(a0, b1, acc[0][1]);
    acc[1][0] = mfma16(a1, b0, acc[1][0]);
    acc[1][1] = mfma16(a1, b1, acc[1][1]);
  }
#pragma unroll
  for (int mi = 0; mi < 2; ++mi)
#pragma unroll
    for (int nj = 0; nj < 2; ++nj) {
      int n = n0 + nj * 16 + lr;
      if (n >= Nreal) continue;
      float bi = bias[n];
#pragma unroll
      for (int r = 0; r < 4; ++r) {
        int m = m0 + mi * 16 + lm4 + r;
        float v = acc[mi][nj][r] + bi;
        if (relu) v = fmaxf(v, 0.f);
        if (Cb) Cb[(size_t)m * Nreal + n] = f2b(v);
        else Cf[(size_t)m * Nreal + n] = v;
      }
    }
}

// ================= theta stats =================
__global__ __launch_bounds__(256) void theta_stats(const float* __restrict__ outb, float* __restrict__ tstat)
{
  int b = blockIdx.x;
  const float* th = outb + (size_t)b * NOUTF + NI;
  float s = 0.f, q = 0.f;
  for (int l = threadIdx.x; l < LLEN; l += 256) { float t = th[l]; s += t; q += t * t; }
  for (int off = 1; off < 64; off <<= 1) { s += __shfl_xor(s, off); q += __shfl_xor(q, off); }
  __shared__ float tmp[8];
  int w = threadIdx.x >> 6;
  if ((threadIdx.x & 63) == 0) { tmp[w] = s; tmp[4 + w] = q; }
  __syncthreads();
  if (threadIdx.x == 0) {
    atomicAdd(&tstat[0], tmp[0] + tmp[1] + tmp[2] + tmp[3]);
    atomicAdd(&tstat[1], tmp[4] + tmp[5] + tmp[6] + tmp[7]);
  }
}

__global__ void finalize_conv1(const float* __restrict__ tstat, const float* __restrict__ cw1,
                               const float* __restrict__ g1, const float* __restrict__ be1,
                               float* __restrict__ a1, float* __restrict__ b1)
{
  int c = threadIdx.x;  // 96
  if (c >= 96) return;
  if (c < 90) {
    float mt = tstat[0] / (float)NBL;
    float vt = tstat[1] / (float)NBL - mt * mt;
    float w = cw1[c];
    float rs = rsqrtf(w * w * vt + EPSBN);
    float a = w * g1[c] * rs;
    a1[c] = a;
    b1[c] = be1[c] - a * mt;
  } else { a1[c] = 0.f; b1[c] = 0.f; }
}

// ============ BN stats reduction: [NSLOT][180] -> [NRED][180] -> fold ============
__global__ __launch_bounds__(192) void bn_reduce1(const float* __restrict__ Sp, const float* __restrict__ Qp,
                                                  float* __restrict__ Sred, float* __restrict__ Qred)
{
  int c = threadIdx.x;
  if (c >= 180) return;
  int base = blockIdx.x * 256;
  float s = 0.f, q = 0.f;
  for (int r = 0; r < 256; ++r) {
    s += Sp[(size_t)(base + r) * 180 + c];
    q += Qp[(size_t)(base + r) * 180 + c];
  }
  Sred[blockIdx.x * 180 + c] = s;
  Qred[blockIdx.x * 180 + c] = q;
}

__global__ void finalize_bn2(const float* __restrict__ Sred, const float* __restrict__ Qred,
                             const float* __restrict__ g, const float* __restrict__ be,
                             float* __restrict__ aP, float* __restrict__ bP)
{
  int c = threadIdx.x;  // 192
  if (c >= 192) return;
  if (c < 180) {
    float s = 0.f, q = 0.f;
    for (int p = 0; p < NRED; ++p) { s += Sred[p * 180 + c]; q += Qred[p * 180 + c]; }
    float m = s / (float)NBL;
    float v = q / (float)NBL - m * m;
    float a = g[c] * rsqrtf(v + EPSBN);
    aP[c] = a;
    bP[c] = be[c] - m * a;
  } else { aP[c] = 0.f; bP[c] = 0.f; }
}

// ================= conv2 stats-only (512 threads, zero LDS, no atomics) =================
__global__ __launch_bounds__(512) void conv2_stats(
    const float* __restrict__ OUTB, const float* __restrict__ A1v, const float* __restrict__ B1v,
    const short* __restrict__ cw2b, const float* __restrict__ cb2p,
    float* __restrict__ Sp, float* __restrict__ Qp)
{
  const int tid = threadIdx.x;
  const int b = blockIdx.y, j0 = blockIdx.x * 128;
  const int l = tid & 63, wv = tid >> 6, wm = wv >> 2, wn = wv & 3;
  const int lr = l & 15, lk = (l >> 4) * 8, lm4 = (l >> 4) * 4;
  const int jj0 = j0 + wn * 32 + lr, jj1 = jj0 + 16;
  const float th0 = (jj0 < LLEN) ? OUTB[(size_t)b * NOUTF + NI + jj0] : 0.f;
  const float th1 = (jj1 < LLEN) ? OUTB[(size_t)b * NOUTF + NI + jj1] : 0.f;
  f32x4 acc[6][2] = {};
#pragma unroll
  for (int ks = 0; ks < 3; ++ks) {
    int k0 = ks * 32 + lk;
    bf16x8 b0 = buildx1(A1v, B1v, k0, th0);
    bf16x8 b1 = buildx1(A1v, B1v, k0, th1);
#pragma unroll
    for (int mi = 0; mi < 6; ++mi) {
      bf16x8 av = *reinterpret_cast<const bf16x8*>(&cw2b[(wm * 96 + mi * 16 + lr) * 96 + k0]);
      acc[mi][0] = mfma16(av, b0, acc[mi][0]);
      acc[mi][1] = mfma16(av, b1, acc[mi][1]);
    }
  }
  const size_t slot = (size_t)(blockIdx.y * gridDim.x + blockIdx.x) * 4 + wn;
#pragma unroll
  for (int mi = 0; mi < 6; ++mi) {
    int m0c = wm * 96 + mi * 16 + lm4;
    float s4[4] = {0.f, 0.f, 0.f, 0.f}, q4[4] = {0.f, 0.f, 0.f, 0.f};
#pragma unroll
    for (int nj = 0; nj < 2; ++nj) {
      int jj = j0 + wn * 32 + nj * 16 + lr;
      if (jj < LLEN) {
#pragma unroll
        for (int r = 0; r < 4; ++r) {
          float v = acc[mi][nj][r] + cb2p[m0c + r];
          s4[r] += v; q4[r] += v * v;
        }
      }
    }
#pragma unroll
    for (int off = 1; off < 16; off <<= 1)
#pragma unroll
      for (int r = 0; r < 4; ++r) { s4[r] += __shfl_xor(s4[r], off); q4[r] += __shfl_xor(q4[r], off); }
    if (lr == 0) {
#pragma unroll
      for (int r = 0; r < 4; ++r) {
        int o = m0c + r;
        if (o < 180) {
          Sp[slot * 180 + o] = s4[r];
          Qp[slot * 180 + o] = q4[r];
        }
      }
    }
  }
}

// ======== fused conv2 -> bn2 -> relu -> conv3 (512 threads, 128 cols, no atomics) ========
__global__ __launch_bounds__(512) void fused_conv23(
    const float* __restrict__ OUTB, const float* __restrict__ A1v, const float* __restrict__ B1v,
    const short* __restrict__ cw2b, const float* __restrict__ cb2p,
    const float* __restrict__ a2, const float* __restrict__ b2,
    const short* __restrict__ cw3b, const float* __restrict__ cb3p,
    short* __restrict__ Y, float* __restrict__ Sp, float* __restrict__ Qp)
{
  __shared__ short xT2[128][200];  // x2 staging, then y3 output staging
  const int tid = threadIdx.x;
  const int b = blockIdx.y, j0 = blockIdx.x * 128;
  const int l = tid & 63, wv = tid >> 6, wm = wv >> 2, wn = wv & 3;
  const int lr = l & 15, lk = (l >> 4) * 8, lm4 = (l >> 4) * 4;
  const int jj0 = j0 + wn * 32 + lr, jj1 = jj0 + 16;
  const float th0 = (jj0 < LLEN) ? OUTB[(size_t)b * NOUTF + NI + jj0] : 0.f;
  const float th1 = (jj1 < LLEN) ? OUTB[(size_t)b * NOUTF + NI + jj1] : 0.f;
  // conv2
  f32x4 acc[6][2] = {};
#pragma unroll
  for (int ks = 0; ks < 3; ++ks) {
    int k0 = ks * 32 + lk;
    bf16x8 b0 = buildx1(A1v, B1v, k0, th0);
    bf16x8 b1 = buildx1(A1v, B1v, k0, th1);
#pragma unroll
    for (int mi = 0; mi < 6; ++mi) {
      bf16x8 av = *reinterpret_cast<const bf16x8*>(&cw2b[(wm * 96 + mi * 16 + lr) * 96 + k0]);
      acc[mi][0] = mfma16(av, b0, acc[mi][0]);
      acc[mi][1] = mfma16(av, b1, acc[mi][1]);
    }
  }
  // x2 = relu(a2*(y2+cb2)+b2) -> xT2
#pragma unroll
  for (int mi = 0; mi < 6; ++mi) {
    int m0c = wm * 96 + mi * 16 + lm4;
#pragma unroll
    for (int nj = 0; nj < 2; ++nj) {
      int col = wn * 32 + nj * 16 + lr;
      float y0 = acc[mi][nj][0] + cb2p[m0c + 0];
      float y1 = acc[mi][nj][1] + cb2p[m0c + 1];
      float y2v = acc[mi][nj][2] + cb2p[m0c + 2];
      float y3v = acc[mi][nj][3] + cb2p[m0c + 3];
      float x0 = fmaxf(fmaf(a2[m0c + 0], y0, b2[m0c + 0]), 0.f);
      float x1 = fmaxf(fmaf(a2[m0c + 1], y1, b2[m0c + 1]), 0.f);
      float x2 = fmaxf(fmaf(a2[m0c + 2], y2v, b2[m0c + 2]), 0.f);
      float x3 = fmaxf(fmaf(a2[m0c + 3], y3v, b2[m0c + 3]), 0.f);
      uint2 w2;
      w2.x = (uint32)(ushort16)f2b(x0) | ((uint32)(ushort16)f2b(x1) << 16);
      w2.y = (uint32)(ushort16)f2b(x2) | ((uint32)(ushort16)f2b(x3) << 16);
      *reinterpret_cast<uint2*>(&xT2[col][m0c]) = w2;
    }
  }
  __syncthreads();
  // conv3
  f32x4 acc2[6][2] = {};
#pragma unroll
  for (int ks = 0; ks < 6; ++ks) {
    int k0 = ks * 32 + lk;
    bf16x8 b0 = *reinterpret_cast<const bf16x8*>(&xT2[wn * 32 + lr][k0]);
    bf16x8 b1 = *reinterpret_cast<const bf16x8*>(&xT2[wn * 32 + 16 + lr][k0]);
#pragma unroll
    for (int mi = 0; mi < 6; ++mi) {
      bf16x8 av = *reinterpret_cast<const bf16x8*>(&cw3b[(wm * 96 + mi * 16 + lr) * 192 + k0]);
      acc2[mi][0] = mfma16(av, b0, acc2[mi][0]);
      acc2[mi][1] = mfma16(av, b1, acc2[mi][1]);
    }
  }
  __syncthreads();  // conv3 reads done; reuse xT2 as y3 staging
  const size_t slot = (size_t)(blockIdx.y * gridDim.x + blockIdx.x) * 4 + wn;
#pragma unroll
  for (int mi = 0; mi < 6; ++mi) {
    int m0c = wm * 96 + mi * 16 + lm4;
    float s4[4] = {0.f, 0.f, 0.f, 0.f}, q4[4] = {0.f, 0.f, 0.f, 0.f};
#pragma unroll
    for (int nj = 0; nj < 2; ++nj) {
      int col = wn * 32 + nj * 16 + lr;
      int jj = j0 + col;
      float v0 = acc2[mi][nj][0] + cb3p[m0c + 0];
      float v1 = acc2[mi][nj][1] + cb3p[m0c + 1];
      float v2 = acc2[mi][nj][2] + cb3p[m0c + 2];
      float v3 = acc2[mi][nj][3] + cb3p[m0c + 3];
      if (jj < LLEN) {
        s4[0] += v0; q4[0] += v0 * v0;
        s4[1] += v1; q4[1] += v1 * v1;
        s4[2] += v2; q4[2] += v2 * v2;
        s4[3] += v3; q4[3] += v3 * v3;
      }
      uint2 w2;
      w2.x = (uint32)(ushort16)f2b(v0) | ((uint32)(ushort16)f2b(v1) << 16);
      w2.y = (uint32)(ushort16)f2b(v2) | ((uint32)(ushort16)f2b(v3) << 16);
      *reinterpret_cast<uint2*>(&xT2[col][m0c]) = w2;
    }
#pragma unroll
    for (int off = 1; off < 16; off <<= 1)
#pragma unroll
      for (int r = 0; r < 4; ++r) { s4[r] += __shfl_xor(s4[r], off); q4[r] += __shfl_xor(q4[r], off); }
    if (lr == 0) {
#pragma unroll
      for (int r = 0; r < 4; ++r) {
        int o = m0c + r;
        if (o < 180) {
          Sp[slot * 180 + o] = s4[r];
          Qp[slot * 180 + o] = q4[r];
        }
      }
    }
  }
  __syncthreads();
  // coalesced copy out: 128 rows x 192 shorts
  for (int f = tid; f < 128 * 24; f += 512) {
    int row = f / 24, c0 = (f - row * 24) * 8;
    int jj = j0 + row;
    if (jj < LLEN) {
      bf16x8 v = *reinterpret_cast<const bf16x8*>(&xT2[row][c0]);
      *reinterpret_cast<bf16x8*>(&Y[((size_t)b * 627 + jj) * 192 + c0]) = v;
    }
  }
}

// ================= conv4 in place on Y (512 threads, 128 cols, no atomics) =================
__global__ __launch_bounds__(512) void conv4_ip(
    short* __restrict__ Y, const float* __restrict__ a3, const float* __restrict__ b3,
    const short* __restrict__ cw4b, const float* __restrict__ cb4p,
    float* __restrict__ Sp, float* __restrict__ Qp)
{
  __shared__ short xT[128][200];  // x3 staging, then y4 output staging
  const int tid = threadIdx.x;
  const int b = blockIdx.y, j0 = blockIdx.x * 128;
  for (int t = tid; t < 128 * 24; t += 512) {
    int col = t / 24, oct = t - col * 24;
    int jj = j0 + col;
    int c0 = oct * 8;
    bf16x8 pk;
    if (jj < LLEN) {
      bf16x8 raw = *reinterpret_cast<const bf16x8*>(&Y[((size_t)b * 627 + jj) * 192 + c0]);
      float4 alo = *reinterpret_cast<const float4*>(&a3[c0]);
      float4 ahi = *reinterpret_cast<const float4*>(&a3[c0 + 4]);
      float4 blo = *reinterpret_cast<const float4*>(&b3[c0]);
      float4 bhi = *reinterpret_cast<const float4*>(&b3[c0 + 4]);
      pk[0] = f2b(fmaxf(fmaf(alo.x, b2f(raw[0]), blo.x), 0.f));
      pk[1] = f2b(fmaxf(fmaf(alo.y, b2f(raw[1]), blo.y), 0.f));
      pk[2] = f2b(fmaxf(fmaf(alo.z, b2f(raw[2]), blo.z), 0.f));
      pk[3] = f2b(fmaxf(fmaf(alo.w, b2f(raw[3]), blo.w), 0.f));
      pk[4] = f2b(fmaxf(fmaf(ahi.x, b2f(raw[4]), bhi.x), 0.f));
      pk[5] = f2b(fmaxf(fmaf(ahi.y, b2f(raw[5]), bhi.y), 0.f));
      pk[6] = f2b(fmaxf(fmaf(ahi.z, b2f(raw[6]), bhi.z), 0.f));
      pk[7] = f2b(fmaxf(fmaf(ahi.w, b2f(raw[7]), bhi.w), 0.f));
    } else {
#pragma unroll
      for (int i = 0; i < 8; ++i) pk[i] = 0;
    }
    *reinterpret_cast<bf16x8*>(&xT[col][c0]) = pk;
  }
  __syncthreads();
  const int l = tid & 63, wv = tid >> 6, wm = wv >> 2, wn = wv & 3;
  const int lr = l & 15, lk = (l >> 4) * 8, lm4 = (l >> 4) * 4;
  f32x4 acc[6][2] = {};
#pragma unroll
  for (int ks = 0; ks < 6; ++ks) {
    int k0 = ks * 32 + lk;
    bf16x8 b0 = *reinterpret_cast<const bf16x8*>(&xT[wn * 32 + lr][k0]);
    bf16x8 b1 = *reinterpret_cast<const bf16x8*>(&xT[wn * 32 + 16 + lr][k0]);
#pragma unroll
    for (int mi = 0; mi < 6; ++mi) {
      bf16x8 av = *reinterpret_cast<const bf16x8*>(&cw4b[(wm * 96 + mi * 16 + lr) * 192 + k0]);
      acc[mi][0] = mfma16(av, b0, acc[mi][0]);
      acc[mi][1] = mfma16(av, b1, acc[mi][1]);
    }
  }
  __syncthreads();  // input reads done; reuse xT as y4 staging
  const size_t slot = (size_t)(blockIdx.y * gridDim.x + blockIdx.x) * 4 + wn;
#pragma unroll
  for (int mi = 0; mi < 6; ++mi) {
    int m0c = wm * 96 + mi * 16 + lm4;
    float s4[4] = {0.f, 0.f, 0.f, 0.f}, q4[4] = {0.f, 0.f, 0.f, 0.f};
#pragma unroll
    for (int nj = 0; nj < 2; ++nj) {
      int col = wn * 32 + nj * 16 + lr;
      int jj = j0 + col;
      float v0 = acc[mi][nj][0] + cb4p[m0c + 0];
      float v1 = acc[mi][nj][1] + cb4p[m0c + 1];
      float v2 = acc[mi][nj][2] + cb4p[m0c + 2];
      float v3 = acc[mi][nj][3] + cb4p[m0c + 3];
      if (jj < LLEN) {
        s4[0] += v0; q4[0] += v0 * v0;
        s4[1] += v1; q4[1] += v1 * v1;
        s4[2] += v2; q4[2] += v2 * v2;
        s4[3] += v3; q4[3] += v3 * v3;
      }
      uint2 w2;
      w2.x = (uint32)(ushort16)f2b(v0) | ((uint32)(ushort16)f2b(v1) << 16);
      w2.y = (uint32)(ushort16)f2b(v2) | ((uint32)(ushort16)f2b(v3) << 16);
      *reinterpret_cast<uint2*>(&xT[col][m0c]) = w2;
    }
#pragma unroll
    for (int off = 1; off < 16; off <<= 1)
#pragma unroll
      for (int r = 0; r < 4; ++r) { s4[r] += __shfl_xor(s4[r], off); q4[r] += __shfl_xor(q4[r], off); }
    if (lr == 0) {
#pragma unroll
      for (int r = 0; r < 4; ++r) {
        int o = m0c + r;
        if (o < 180) {
          Sp[slot * 180 + o] = s4[r];
          Qp[slot * 180 + o] = q4[r];
        }
      }
    }
  }
  __syncthreads();
  for (int f = tid; f < 128 * 24; f += 512) {
    int row = f / 24, c0 = (f - row * 24) * 8;
    int jj = j0 + row;
    if (jj < LLEN) {
      bf16x8 v = *reinterpret_cast<const bf16x8*>(&xT[row][c0]);
      *reinterpret_cast<bf16x8*>(&Y[((size_t)b * 627 + jj) * 192 + c0]) = v;
    }
  }
}

// ================= conv5 (MFMA) + register log_softmax + NLL =================
__global__ __launch_bounds__(256) void conv5_nll(
    const short* __restrict__ Y, const float* __restrict__ a4, const float* __restrict__ b4,
    const short* __restrict__ cw5b, const float* __restrict__ cb5p,
    const float* __restrict__ inputs, float* __restrict__ nll)
{
  __shared__ float ab[384];
  __shared__ short xT[32][200];
  __shared__ float wmax[4][32];
  __shared__ float wsum[4][32];
  __shared__ float ptgt[32];
  __shared__ int tg[32];
  const int tid = threadIdx.x;
  const int b = blockIdx.y, l0 = blockIdx.x * 32;
  for (int t = tid; t < 384; t += 256) ab[t] = (t < 192) ? a4[t] : b4[t - 192];
  if (tid < 32) {
    int jj = l0 + tid;
    tg[tid] = (jj < LLEN) ? (int)inputs[(size_t)b * NI + jj] : 0;
  }
  __syncthreads();
  for (int t = tid; t < 32 * 24; t += 256) {
    int col = t / 24, oct = t - col * 24;
    int jj = l0 + col;
    int c0 = oct * 8;
    bf16x8 pk;
    if (jj < LLEN) {
      bf16x8 raw = *reinterpret_cast<const bf16x8*>(&Y[((size_t)b * 627 + jj) * 192 + c0]);
#pragma unroll
      for (int i = 0; i < 8; ++i)
        pk[i] = f2b(fmaxf(fmaf(ab[c0 + i], b2f(raw[i]), ab[192 + c0 + i]), 0.f));
    } else {
#pragma unroll
      for (int i = 0; i < 8; ++i) pk[i] = 0;
    }
    *reinterpret_cast<bf16x8*>(&xT[col][c0]) = pk;
  }
  __syncthreads();
  const int l = tid & 63, wv = tid >> 6;
  const int lr = l & 15, lk = (l >> 4) * 8, lm4 = (l >> 4) * 4;
  const int mf0 = wv * 5;
  f32x4 acc[5][2] = {};
#pragma unroll
  for (int ks = 0; ks < 6; ++ks) {
    int k0 = ks * 32 + lk;
    bf16x8 b0 = *reinterpret_cast<const bf16x8*>(&xT[lr][k0]);
    bf16x8 b1 = *reinterpret_cast<const bf16x8*>(&xT[16 + lr][k0]);
#pragma unroll
    for (int mi = 0; mi < 5; ++mi) {
      bf16x8 av = *reinterpret_cast<const bf16x8*>(&cw5b[((mf0 + mi) * 16 + lr) * 192 + k0]);
      acc[mi][0] = mfma16(av, b0, acc[mi][0]);
      acc[mi][1] = mfma16(av, b1, acc[mi][1]);
    }
  }
  float vv[5][2][4];
  float vmax0 = -1e30f, vmax1 = -1e30f;
#pragma unroll
  for (int mi = 0; mi < 5; ++mi) {
#pragma unroll
    for (int r = 0; r < 4; ++r) {
      int m = (mf0 + mi) * 16 + lm4 + r;
      float bi = cb5p[m];
      float v0 = (m < 300) ? (acc[mi][0][r] + bi) : -1e30f;
      float v1 = (m < 300) ? (acc[mi][1][r] + bi) : -1e30f;
      vv[mi][0][r] = v0;
      vv[mi][1][r] = v1;
      vmax0 = fmaxf(vmax0, v0);
      vmax1 = fmaxf(vmax1, v1);
    }
  }
  {
    int t0 = tg[lr], t1 = tg[16 + lr];
#pragma unroll
    for (int mi = 0; mi < 5; ++mi) {
#pragma unroll
      for (int r = 0; r < 4; ++r) {
        int m = (mf0 + mi) * 16 + lm4 + r;
        if (m == t0) ptgt[lr] = vv[mi][0][r];
        if (m == t1) ptgt[16 + lr] = vv[mi][1][r];
      }
    }
  }
  vmax0 = fmaxf(vmax0, __shfl_xor(vmax0, 16)); vmax0 = fmaxf(vmax0, __shfl_xor(vmax0, 32));
  vmax1 = fmaxf(vmax1, __shfl_xor(vmax1, 16)); vmax1 = fmaxf(vmax1, __shfl_xor(vmax1, 32));
  if (l < 16) { wmax[wv][lr] = vmax0; wmax[wv][16 + lr] = vmax1; }
  __syncthreads();
  float gmax0 = fmaxf(fmaxf(wmax[0][lr], wmax[1][lr]), fmaxf(wmax[2][lr], wmax[3][lr]));
  float gmax1 = fmaxf(fmaxf(wmax[0][16 + lr], wmax[1][16 + lr]), fmaxf(wmax[2][16 + lr], wmax[3][16 + lr]));
  float vs0 = 0.f, vs1 = 0.f;
#pragma unroll
  for (int mi = 0; mi < 5; ++mi) {
#pragma unroll
    for (int r = 0; r < 4; ++r) {
      vs0 += __expf(vv[mi][0][r] - gmax0);
      vs1 += __expf(vv[mi][1][r] - gmax1);
    }
  }
  vs0 += __shfl_xor(vs0, 16); vs0 += __shfl_xor(vs0, 32);
  vs1 += __shfl_xor(vs1, 16); vs1 += __shfl_xor(vs1, 32);
  if (l < 16) { wsum[wv][lr] = vs0; wsum[wv][16 + lr] = vs1; }
  __syncthreads();
  if (tid < 32) {
    int jj = l0 + tid;
    if (jj < LLEN) {
      float gm = fmaxf(fmaxf(wmax[0][tid], wmax[1][tid]), fmaxf(wmax[2][tid], wmax[3][tid]));
      float gs = wsum[0][tid] + wsum[1][tid] + wsum[2][tid] + wsum[3][tid];
      nll[(size_t)b * LLEN + jj] = gm + logf(gs) - ptgt[tid];
    }
  }
}

// ================= final assembly =================
__global__ __launch_bounds__(256) void ll_pass1(
    const float* __restrict__ outb, const float* __restrict__ nll,
    const float* __restrict__ inputs, float* __restrict__ llp, float* __restrict__ sc)
{
  int b = blockIdx.x;
  float s = 0.f;
  for (int l = 2 + (int)threadIdx.x; l < LLEN; l += 256) {
    float graw = outb[(size_t)b * NOUTF + l];
    float sg = 1.f / (1.f + expf(-graw));
    float term;
    if (inputs[(size_t)b * NI + l] > 0.f)
      term = 0.1f * logf(sg + 1e-10f) - nll[(size_t)b * LLEN + l];
    else
      term = 0.1f * logf(1.f - sg + 1e-10f);
    s += term;
  }
  for (int off = 1; off < 64; off <<= 1) s += __shfl_xor(s, off);
  __shared__ float tmp[4];
  if ((threadIdx.x & 63) == 0) tmp[threadIdx.x >> 6] = s;
  __syncthreads();
  if (threadIdx.x == 0) {
    llp[b] = tmp[0] + tmp[1] + tmp[2] + tmp[3];
    atomicAdd(sc, nll[(size_t)b * LLEN] + nll[(size_t)b * LLEN + 1]);
  }
}

__global__ void ll_pass2(const float* __restrict__ llp, const float* __restrict__ sc, float* __restrict__ outp)
{
  int i = blockIdx.x * blockDim.x + threadIdx.x;
  if (i < BATCH) outp[i] = llp[i] - sc[0] * (1.f / 1024.f);
}

extern "C" void kernel_launch(void* const* d_in, const int* in_sizes, int n_in,
                              void* d_out, int out_size, void* d_ws, size_t ws_size,
                              hipStream_t stream)
{
  const float* inputs = (const float*)d_in[0];
  const float* W_in = (const float*)d_in[1];
  const float* b_in = (const float*)d_in[2];
  const float* W_h1 = (const float*)d_in[3];
  const float* b_h1 = (const float*)d_in[4];
  const float* W_h2 = (const float*)d_in[5];
  const float* b_h2 = (const float*)d_in[6];
  const float* W_out = (const float*)d_in[7];
  const float* b_out = (const float*)d_in[8];
  const float* cw1 = (const float*)d_in[9];
  const float* g1 = (const float*)d_in[11];
  const float* be1 = (const float*)d_in[12];
  const float* cw2 = (const float*)d_in[13];
  const float* cb2 = (const float*)d_in[14];
  const float* g2 = (const float*)d_in[15];
  const float* be2 = (const float*)d_in[16];
  const float* cw3 = (const float*)d_in[17];
  const float* cb3 = (const float*)d_in[18];
  const float* g3 = (const float*)d_in[19];
  const float* be3 = (const float*)d_in[20];
  const float* cw4 = (const float*)d_in[21];
  const float* cb4 = (const float*)d_in[22];
  const float* g4 = (const float*)d_in[23];
  const float* be4 = (const float*)d_in[24];
  const float* cw5 = (const float*)d_in[25];
  const float* cb5 = (const float*)d_in[26];

  char* p = (char*)d_ws;
  short* Y = (short*)p;    p += (size_t)512 * 627 * 192 * 2;
  short* INB = (short*)p;  p += (size_t)512 * 640 * 2;
  short* HB1 = (short*)p;  p += (size_t)512 * 1024 * 2;
  short* HB2 = (short*)p;  p += (size_t)512 * 1024 * 2;
  short* HB3 = (short*)p;  p += (size_t)512 * 1024 * 2;
  short* WB1 = (short*)p;  p += (size_t)1024 * 640 * 2;
  short* WB2 = (short*)p;  p += (size_t)1024 * 1024 * 2;
  short* WB3 = (short*)p;  p += (size_t)1024 * 1024 * 2;
  short* WB4 = (short*)p;  p += (size_t)1280 * 1024 * 2;
  short* CW2B = (short*)p; p += (size_t)192 * 96 * 2;
  short* CW3B = (short*)p; p += (size_t)192 * 192 * 2;
  short* CW4B = (short*)p; p += (size_t)192 * 192 * 2;
  short* CW5B = (short*)p; p += (size_t)320 * 192 * 2;
  float* fp = (float*)p;
  float* OUTB = fp;  fp += (size_t)512 * 1254;
  float* NLLB = fp;  fp += 321028;
  float* LLP = fp;   fp += 512;
  float* A1 = fp;    fp += 96;
  float* B1g = fp;   fp += 96;
  float* A2 = fp;    fp += 192;
  float* B2g = fp;   fp += 192;
  float* A3 = fp;    fp += 192;
  float* B3g = fp;   fp += 192;
  float* A4 = fp;    fp += 192;
  float* B4g = fp;   fp += 192;
  float* CB2P = fp;  fp += 192;
  float* CB3P = fp;  fp += 192;
  float* CB4P = fp;  fp += 192;
  float* CB5P = fp;  fp += 320;
  float* TST = fp;   fp += 2;
  float* SC = fp;    fp += 2;
  float* SPP = fp;   fp += (size_t)NSLOT * 180;
  float* QPP = fp;   fp += (size_t)NSLOT * 180;
  float* SRED = fp;  fp += NRED * 180;
  float* QRED = fp;  fp += NRED * 180;

  hipMemsetAsync(TST, 0, 4 * sizeof(float), stream);

  // prep: inputs, masked MLP weights, conv weights, padded biases
  prep_inputs<<<dim3((512 * 640 + 255) / 256), 256, 0, stream>>>(inputs, INB);
  prep_mlpw<<<dim3((1024 * 640 + 255) / 256), 256, 0, stream>>>(W_in, WB1, 1024, 627, 1024, 640, 0);
  prep_mlpw<<<dim3((1024 * 1024 + 255) / 256), 256, 0, stream>>>(W_h1, WB2, 1024, 1024, 1024, 1024, 1);
  prep_mlpw<<<dim3((1024 * 1024 + 255) / 256), 256, 0, stream>>>(W_h2, WB3, 1024, 1024, 1024, 1024, 1);
  prep_mlpw<<<dim3((1280 * 1024 + 255) / 256), 256, 0, stream>>>(W_out, WB4, 1254, 1024, 1280, 1024, 2);
  prep_convw<<<dim3((192 * 96 + 255) / 256), 256, 0, stream>>>(cw2, CW2B, 180, 90, 192, 96);
  prep_convw<<<dim3((192 * 192 + 255) / 256), 256, 0, stream>>>(cw3, CW3B, 180, 180, 192, 192);
  prep_convw<<<dim3((192 * 192 + 255) / 256), 256, 0, stream>>>(cw4, CW4B, 180, 180, 192, 192);
  prep_convw<<<dim3((320 * 192 + 255) / 256), 256, 0, stream>>>(cw5, CW5B, 300, 180, 320, 192);
  prep_cb<<<1, 320, 0, stream>>>(cb2, cb3, cb4, cb5, CB2P, CB3P, CB4P, CB5P);

  // masked MLP (MFMA)
  mlp_mfma<<<dim3(16, 8), 256, 0, stream>>>(INB, WB1, b_in, nullptr, HB1, 1024, 640, 1);
  mlp_mfma<<<dim3(16, 8), 256, 0, stream>>>(HB1, WB2, b_h1, nullptr, HB2, 1024, 1024, 1);
  mlp_mfma<<<dim3(16, 8), 256, 0, stream>>>(HB2, WB3, b_h2, nullptr, HB3, 1024, 1024, 0);
  mlp_mfma<<<dim3(20, 8), 256, 0, stream>>>(HB3, WB4, b_out, OUTB, nullptr, 1254, 1024, 0);

  // conv1+bn1 folded via theta stats
  theta_stats<<<dim3(BATCH), 256, 0, stream>>>(OUTB, TST);
  finalize_conv1<<<1, 96, 0, stream>>>(TST, cw1, g1, be1, A1, B1g);

  // conv2 stats -> bn2 fold
  conv2_stats<<<dim3(5, BATCH), 512, 0, stream>>>(OUTB, A1, B1g, CW2B, CB2P, SPP, QPP);
  bn_reduce1<<<dim3(NRED), 192, 0, stream>>>(SPP, QPP, SRED, QRED);
  finalize_bn2<<<1, 192, 0, stream>>>(SRED, QRED, g2, be2, A2, B2g);

  // fused conv2->conv3 -> Y (y3) + stats3 -> bn3 fold
  fused_conv23<<<dim3(5, BATCH), 512, 0, stream>>>(OUTB, A1, B1g, CW2B, CB2P, A2, B2g, CW3B, CB3P, Y, SPP, QPP);
  bn_reduce1<<<dim3(NRED), 192, 0, stream>>>(SPP, QPP, SRED, QRED);
  finalize_bn2<<<1, 192, 0, stream>>>(SRED, QRED, g3, be3, A3, B3g);

  // conv4 in place + stats4 -> bn4 fold
  conv4_ip<<<dim3(5, BATCH), 512, 0, stream>>>(Y, A3, B3g, CW4B, CB4P, SPP, QPP);
  bn_reduce1<<<dim3(NRED), 192, 0, stream>>>(SPP, QPP, SRED, QRED);
  finalize_bn2<<<1, 192, 0, stream>>>(SRED, QRED, g4, be4, A4, B4g);

  // conv5 + register log_softmax + nll
  conv5_nll<<<dim3(20, BATCH), 256, 0, stream>>>(Y, A4, B4g, CW5B, CB5P, inputs, NLLB);

  // final assembly
  ll_pass1<<<dim3(BATCH), 256, 0, stream>>>(OUTB, NLLB, inputs, LLP, SC);
  ll_pass2<<<dim3(2), 256, 0, stream>>>(LLP, SC, (float*)d_out);
}

// Round 9
// 677.030 us; speedup vs baseline: 5.8341x; 1.0492x over previous
//
#include <hip/hip_runtime.h>
#include <hip/hip_bf16.h>
#include <math.h>

#define BATCH 512
#define NI 627
#define NH 1024
#define NOUTF 1254
#define LLEN 627
#define NBL (512 * 627)
#define EPSBN 1e-5f
#define NSLOT 10240   // 2560 blocks * 4 wn-waves
#define NRED 40       // stage-1 reduction blocks (10240/256)

typedef __attribute__((ext_vector_type(8))) short bf16x8;
typedef __attribute__((ext_vector_type(4))) float f32x4;
typedef unsigned int uint32;
typedef unsigned short ushort16;

__device__ inline short f2b(float x) {
  __hip_bfloat16 h = __float2bfloat16(x);
  return *reinterpret_cast<short*>(&h);
}
__device__ inline float b2f(short s) {
  return __uint_as_float(((uint32)(ushort16)s) << 16);
}
__device__ inline f32x4 mfma16(bf16x8 a, bf16x8 b, f32x4 c) {
  return __builtin_amdgcn_mfma_f32_16x16x32_bf16(a, b, c, 0, 0, 0);
}
// 8 channels k0..k0+7 of relu(a1*th+b1), packed bf16
__device__ inline bf16x8 buildx1(const float* __restrict__ A1v, const float* __restrict__ B1v,
                                 int k0, float th) {
  float4 alo = *reinterpret_cast<const float4*>(&A1v[k0]);
  float4 ahi = *reinterpret_cast<const float4*>(&A1v[k0 + 4]);
  float4 blo = *reinterpret_cast<const float4*>(&B1v[k0]);
  float4 bhi = *reinterpret_cast<const float4*>(&B1v[k0 + 4]);
  bf16x8 r;
  r[0] = f2b(fmaxf(fmaf(alo.x, th, blo.x), 0.f));
  r[1] = f2b(fmaxf(fmaf(alo.y, th, blo.y), 0.f));
  r[2] = f2b(fmaxf(fmaf(alo.z, th, blo.z), 0.f));
  r[3] = f2b(fmaxf(fmaf(alo.w, th, blo.w), 0.f));
  r[4] = f2b(fmaxf(fmaf(ahi.x, th, bhi.x), 0.f));
  r[5] = f2b(fmaxf(fmaf(ahi.y, th, bhi.y), 0.f));
  r[6] = f2b(fmaxf(fmaf(ahi.z, th, bhi.z), 0.f));
  r[7] = f2b(fmaxf(fmaf(ahi.w, th, bhi.w), 0.f));
  return r;
}

// ================= prep kernels =================
__global__ __launch_bounds__(256) void prep_inputs(const float* __restrict__ in, short* __restrict__ outp) {
  int i = blockIdx.x * 256 + threadIdx.x;
  if (i >= 512 * 640) return;
  int m = i / 640, k = i - m * 640;
  outp[i] = (k < NI) ? f2b(in[m * NI + k]) : (short)0;
}

__global__ __launch_bounds__(256) void prep_mlpw(const float* __restrict__ W, short* __restrict__ Wb,
                                                 int Nreal, int Kreal, int Npad, int Kpad, int mode) {
  int i = blockIdx.x * 256 + threadIdx.x;
  if (i >= Npad * Kpad) return;
  int n = i / Kpad, k = i - n * Kpad;
  float w = 0.f;
  if (n < Nreal && k < Kreal) {
    int od = n >= 627 ? n - 627 : n;
    int kd = k >= 627 ? k - 627 : k;
    bool keep = (mode == 0) ? (od >= k) : (mode == 1) ? (od >= kd) : (od > kd);
    if (keep) w = W[n * Kreal + k];
  }
  Wb[i] = f2b(w);
}

__global__ __launch_bounds__(256) void prep_convw(const float* __restrict__ W, short* __restrict__ Wb,
                                                  int Oreal, int Kreal, int Opad, int Kpad) {
  int i = blockIdx.x * 256 + threadIdx.x;
  if (i >= Opad * Kpad) return;
  int o = i / Kpad, k = i - o * Kpad;
  Wb[i] = (o < Oreal && k < Kreal) ? f2b(W[o * Kreal + k]) : (short)0;
}

__global__ void prep_cb(const float* __restrict__ cb2, const float* __restrict__ cb3,
                        const float* __restrict__ cb4, const float* __restrict__ cb5,
                        float* __restrict__ cb2p, float* __restrict__ cb3p,
                        float* __restrict__ cb4p, float* __restrict__ cb5p) {
  int c = threadIdx.x;  // 320 threads
  if (c < 192) {
    cb2p[c] = (c < 180) ? cb2[c] : 0.f;
    cb3p[c] = (c < 180) ? cb3[c] : 0.f;
    cb4p[c] = (c < 180) ? cb4[c] : 0.f;
  }
  if (c < 320) cb5p[c] = (c < 300) ? cb5[c] : 0.f;
}

// ====== MLP MFMA GEMM: 32x64 tile, K-split-2 across waves (grid covers all CUs) ======
__global__ __launch_bounds__(256) void mlp_mfma(
    const short* __restrict__ A, const short* __restrict__ Wb, const float* __restrict__ bias,
    float* __restrict__ Cf, short* __restrict__ Cb, int Nreal, int Kpad, int relu)
{
  __shared__ float red[2][2][2][4][64];  // [wn][mi][nj][r][lane] = 16 KB
  const int tid = threadIdx.x;
  const int l = tid & 63, wv = tid >> 6;
  const int wn = wv >> 1, kh = wv & 1;
  const int m0 = blockIdx.y * 32;
  const int n0 = blockIdx.x * 64 + wn * 32;
  const int lr = l & 15, lk = (l >> 4) * 8, lm4 = (l >> 4) * 4;
  f32x4 acc[2][2] = {};
  const int khalf = Kpad >> 1;
  const int nk = khalf >> 5;
  for (int ks = 0; ks < nk; ++ks) {
    int k0 = kh * khalf + ks * 32 + lk;
    bf16x8 a0 = *reinterpret_cast<const bf16x8*>(&A[(size_t)(m0 + lr) * Kpad + k0]);
    bf16x8 a1 = *reinterpret_cast<const bf16x8*>(&A[(size_t)(m0 + 16 + lr) * Kpad + k0]);
    bf16x8 b0 = *reinterpret_cast<const bf16x8*>(&Wb[(size_t)(n0 + lr) * Kpad + k0]);
    bf16x8 b1 = *reinterpret_cast<const bf16x8*>(&Wb[(size_t)(n0 + 16 + lr) * Kpad + k0]);
    acc[0][0] = mfma16(a0, b0, acc[0][0]);
    acc[0][1] = mfma16(a0, b1, acc[0][1]);
    acc[1][0] = mfma16(a1, b0, acc[1][0]);
    acc[1][1] = mfma16(a1, b1, acc[1][1]);
  }
  if (kh == 1) {
#pragma unroll
    for (int mi = 0; mi < 2; ++mi)
#pragma unroll
      for (int nj = 0; nj < 2; ++nj)
#pragma unroll
        for (int r = 0; r < 4; ++r) red[wn][mi][nj][r][l] = acc[mi][nj][r];
  }
  __syncthreads();
  if (kh == 0) {
#pragma unroll
    for (int mi = 0; mi < 2; ++mi)
#pragma unroll
      for (int nj = 0; nj < 2; ++nj) {
        int n = n0 + nj * 16 + lr;
        if (n >= Nreal) continue;
        float bi = bias[n];
#pragma unroll
        for (int r = 0; r < 4; ++r) {
          int m = m0 + mi * 16 + lm4 + r;
          float v = acc[mi][nj][r] + red[wn][mi][nj][r][l] + bi;
          if (relu) v = fmaxf(v, 0.f);
          if (Cb) Cb[(size_t)m * Nreal + n] = f2b(v);
          else Cf[(size_t)m * Nreal + n] = v;
        }
      }
  }
}

// ================= theta stats =================
__global__ __launch_bounds__(256) void theta_stats(const float* __restrict__ outb, float* __restrict__ tstat)
{
  int b = blockIdx.x;
  const float* th = outb + (size_t)b * NOUTF + NI;
  float s = 0.f, q = 0.f;
  for (int l = threadIdx.x; l < LLEN; l += 256) { float t = th[l]; s += t; q += t * t; }
  for (int off = 1; off < 64; off <<= 1) { s += __shfl_xor(s, off); q += __shfl_xor(q, off); }
  __shared__ float tmp[8];
  int w = threadIdx.x >> 6;
  if ((threadIdx.x & 63) == 0) { tmp[w] = s; tmp[4 + w] = q; }
  __syncthreads();
  if (threadIdx.x == 0) {
    atomicAdd(&tstat[0], tmp[0] + tmp[1] + tmp[2] + tmp[3]);
    atomicAdd(&tstat[1], tmp[4] + tmp[5] + tmp[6] + tmp[7]);
  }
}

__global__ void finalize_conv1(const float* __restrict__ tstat, const float* __restrict__ cw1,
                               const float* __restrict__ g1, const float* __restrict__ be1,
                               float* __restrict__ a1, float* __restrict__ b1)
{
  int c = threadIdx.x;  // 96
  if (c >= 96) return;
  if (c < 90) {
    float mt = tstat[0] / (float)NBL;
    float vt = tstat[1] / (float)NBL - mt * mt;
    float w = cw1[c];
    float rs = rsqrtf(w * w * vt + EPSBN);
    float a = w * g1[c] * rs;
    a1[c] = a;
    b1[c] = be1[c] - a * mt;
  } else { a1[c] = 0.f; b1[c] = 0.f; }
}

// ============ BN stats reduction: [NSLOT][180] -> [NRED][180] -> fold ============
__global__ __launch_bounds__(192) void bn_reduce1(const float* __restrict__ Sp, const float* __restrict__ Qp,
                                                  float* __restrict__ Sred, float* __restrict__ Qred)
{
  int c = threadIdx.x;
  if (c >= 180) return;
  int base = blockIdx.x * 256;
  float s = 0.f, q = 0.f;
  for (int r = 0; r < 256; ++r) {
    s += Sp[(size_t)(base + r) * 180 + c];
    q += Qp[(size_t)(base + r) * 180 + c];
  }
  Sred[blockIdx.x * 180 + c] = s;
  Qred[blockIdx.x * 180 + c] = q;
}

__global__ void finalize_bn2(const float* __restrict__ Sred, const float* __restrict__ Qred,
                             const float* __restrict__ g, const float* __restrict__ be,
                             float* __restrict__ aP, float* __restrict__ bP)
{
  int c = threadIdx.x;  // 192
  if (c >= 192) return;
  if (c < 180) {
    float s = 0.f, q = 0.f;
    for (int p = 0; p < NRED; ++p) { s += Sred[p * 180 + c]; q += Qred[p * 180 + c]; }
    float m = s / (float)NBL;
    float v = q / (float)NBL - m * m;
    float a = g[c] * rsqrtf(v + EPSBN);
    aP[c] = a;
    bP[c] = be[c] - m * a;
  } else { aP[c] = 0.f; bP[c] = 0.f; }
}

// ================= conv2 stats-only (512 threads, zero LDS, no atomics) =================
__global__ __launch_bounds__(512) void conv2_stats(
    const float* __restrict__ OUTB, const float* __restrict__ A1v, const float* __restrict__ B1v,
    const short* __restrict__ cw2b, const float* __restrict__ cb2p,
    float* __restrict__ Sp, float* __restrict__ Qp)
{
  const int tid = threadIdx.x;
  const int b = blockIdx.y, j0 = blockIdx.x * 128;
  const int l = tid & 63, wv = tid >> 6, wm = wv >> 2, wn = wv & 3;
  const int lr = l & 15, lk = (l >> 4) * 8, lm4 = (l >> 4) * 4;
  const int jj0 = j0 + wn * 32 + lr, jj1 = jj0 + 16;
  const float th0 = (jj0 < LLEN) ? OUTB[(size_t)b * NOUTF + NI + jj0] : 0.f;
  const float th1 = (jj1 < LLEN) ? OUTB[(size_t)b * NOUTF + NI + jj1] : 0.f;
  f32x4 acc[6][2] = {};
#pragma unroll
  for (int ks = 0; ks < 3; ++ks) {
    int k0 = ks * 32 + lk;
    bf16x8 b0 = buildx1(A1v, B1v, k0, th0);
    bf16x8 b1 = buildx1(A1v, B1v, k0, th1);
#pragma unroll
    for (int mi = 0; mi < 6; ++mi) {
      bf16x8 av = *reinterpret_cast<const bf16x8*>(&cw2b[(wm * 96 + mi * 16 + lr) * 96 + k0]);
      acc[mi][0] = mfma16(av, b0, acc[mi][0]);
      acc[mi][1] = mfma16(av, b1, acc[mi][1]);
    }
  }
  const size_t slot = (size_t)(blockIdx.y * gridDim.x + blockIdx.x) * 4 + wn;
#pragma unroll
  for (int mi = 0; mi < 6; ++mi) {
    int m0c = wm * 96 + mi * 16 + lm4;
    float s4[4] = {0.f, 0.f, 0.f, 0.f}, q4[4] = {0.f, 0.f, 0.f, 0.f};
#pragma unroll
    for (int nj = 0; nj < 2; ++nj) {
      int jj = j0 + wn * 32 + nj * 16 + lr;
      if (jj < LLEN) {
#pragma unroll
        for (int r = 0; r < 4; ++r) {
          float v = acc[mi][nj][r] + cb2p[m0c + r];
          s4[r] += v; q4[r] += v * v;
        }
      }
    }
#pragma unroll
    for (int off = 1; off < 16; off <<= 1)
#pragma unroll
      for (int r = 0; r < 4; ++r) { s4[r] += __shfl_xor(s4[r], off); q4[r] += __shfl_xor(q4[r], off); }
    if (lr == 0) {
#pragma unroll
      for (int r = 0; r < 4; ++r) {
        int o = m0c + r;
        if (o < 180) {
          Sp[slot * 180 + o] = s4[r];
          Qp[slot * 180 + o] = q4[r];
        }
      }
    }
  }
}

// ======== fused conv2 -> bn2 -> relu -> conv3 (512 threads, 128 cols, no atomics) ========
__global__ __launch_bounds__(512) void fused_conv23(
    const float* __restrict__ OUTB, const float* __restrict__ A1v, const float* __restrict__ B1v,
    const short* __restrict__ cw2b, const float* __restrict__ cb2p,
    const float* __restrict__ a2, const float* __restrict__ b2,
    const short* __restrict__ cw3b, const float* __restrict__ cb3p,
    short* __restrict__ Y, float* __restrict__ Sp, float* __restrict__ Qp)
{
  __shared__ short xT2[128][200];  // x2 staging, then y3 output staging
  const int tid = threadIdx.x;
  const int b = blockIdx.y, j0 = blockIdx.x * 128;
  const int l = tid & 63, wv = tid >> 6, wm = wv >> 2, wn = wv & 3;
  const int lr = l & 15, lk = (l >> 4) * 8, lm4 = (l >> 4) * 4;
  const int jj0 = j0 + wn * 32 + lr, jj1 = jj0 + 16;
  const float th0 = (jj0 < LLEN) ? OUTB[(size_t)b * NOUTF + NI + jj0] : 0.f;
  const float th1 = (jj1 < LLEN) ? OUTB[(size_t)b * NOUTF + NI + jj1] : 0.f;
  // conv2
  f32x4 acc[6][2] = {};
#pragma unroll
  for (int ks = 0; ks < 3; ++ks) {
    int k0 = ks * 32 + lk;
    bf16x8 b0 = buildx1(A1v, B1v, k0, th0);
    bf16x8 b1 = buildx1(A1v, B1v, k0, th1);
#pragma unroll
    for (int mi = 0; mi < 6; ++mi) {
      bf16x8 av = *reinterpret_cast<const bf16x8*>(&cw2b[(wm * 96 + mi * 16 + lr) * 96 + k0]);
      acc[mi][0] = mfma16(av, b0, acc[mi][0]);
      acc[mi][1] = mfma16(av, b1, acc[mi][1]);
    }
  }
  // x2 = relu(a2*(y2+cb2)+b2) -> xT2
#pragma unroll
  for (int mi = 0; mi < 6; ++mi) {
    int m0c = wm * 96 + mi * 16 + lm4;
#pragma unroll
    for (int nj = 0; nj < 2; ++nj) {
      int col = wn * 32 + nj * 16 + lr;
      float y0 = acc[mi][nj][0] + cb2p[m0c + 0];
      float y1 = acc[mi][nj][1] + cb2p[m0c + 1];
      float y2v = acc[mi][nj][2] + cb2p[m0c + 2];
      float y3v = acc[mi][nj][3] + cb2p[m0c + 3];
      float x0 = fmaxf(fmaf(a2[m0c + 0], y0, b2[m0c + 0]), 0.f);
      float x1 = fmaxf(fmaf(a2[m0c + 1], y1, b2[m0c + 1]), 0.f);
      float x2 = fmaxf(fmaf(a2[m0c + 2], y2v, b2[m0c + 2]), 0.f);
      float x3 = fmaxf(fmaf(a2[m0c + 3], y3v, b2[m0c + 3]), 0.f);
      uint2 w2;
      w2.x = (uint32)(ushort16)f2b(x0) | ((uint32)(ushort16)f2b(x1) << 16);
      w2.y = (uint32)(ushort16)f2b(x2) | ((uint32)(ushort16)f2b(x3) << 16);
      *reinterpret_cast<uint2*>(&xT2[col][m0c]) = w2;
    }
  }
  __syncthreads();
  // conv3
  f32x4 acc2[6][2] = {};
#pragma unroll
  for (int ks = 0; ks < 6; ++ks) {
    int k0 = ks * 32 + lk;
    bf16x8 b0 = *reinterpret_cast<const bf16x8*>(&xT2[wn * 32 + lr][k0]);
    bf16x8 b1 = *reinterpret_cast<const bf16x8*>(&xT2[wn * 32 + 16 + lr][k0]);
#pragma unroll
    for (int mi = 0; mi < 6; ++mi) {
      bf16x8 av = *reinterpret_cast<const bf16x8*>(&cw3b[(wm * 96 + mi * 16 + lr) * 192 + k0]);
      acc2[mi][0] = mfma16(av, b0, acc2[mi][0]);
      acc2[mi][1] = mfma16(av, b1, acc2[mi][1]);
    }
  }
  __syncthreads();  // conv3 reads done; reuse xT2 as y3 staging
  const size_t slot = (size_t)(blockIdx.y * gridDim.x + blockIdx.x) * 4 + wn;
#pragma unroll
  for (int mi = 0; mi < 6; ++mi) {
    int m0c = wm * 96 + mi * 16 + lm4;
    float s4[4] = {0.f, 0.f, 0.f, 0.f}, q4[4] = {0.f, 0.f, 0.f, 0.f};
#pragma unroll
    for (int nj = 0; nj < 2; ++nj) {
      int col = wn * 32 + nj * 16 + lr;
      int jj = j0 + col;
      float v0 = acc2[mi][nj][0] + cb3p[m0c + 0];
      float v1 = acc2[mi][nj][1] + cb3p[m0c + 1];
      float v2 = acc2[mi][nj][2] + cb3p[m0c + 2];
      float v3 = acc2[mi][nj][3] + cb3p[m0c + 3];
      if (jj < LLEN) {
        s4[0] += v0; q4[0] += v0 * v0;
        s4[1] += v1; q4[1] += v1 * v1;
        s4[2] += v2; q4[2] += v2 * v2;
        s4[3] += v3; q4[3] += v3 * v3;
      }
      uint2 w2;
      w2.x = (uint32)(ushort16)f2b(v0) | ((uint32)(ushort16)f2b(v1) << 16);
      w2.y = (uint32)(ushort16)f2b(v2) | ((uint32)(ushort16)f2b(v3) << 16);
      *reinterpret_cast<uint2*>(&xT2[col][m0c]) = w2;
    }
#pragma unroll
    for (int off = 1; off < 16; off <<= 1)
#pragma unroll
      for (int r = 0; r < 4; ++r) { s4[r] += __shfl_xor(s4[r], off); q4[r] += __shfl_xor(q4[r], off); }
    if (lr == 0) {
#pragma unroll
      for (int r = 0; r < 4; ++r) {
        int o = m0c + r;
        if (o < 180) {
          Sp[slot * 180 + o] = s4[r];
          Qp[slot * 180 + o] = q4[r];
        }
      }
    }
  }
  __syncthreads();
  // coalesced copy out: 128 rows x 192 shorts
  for (int f = tid; f < 128 * 24; f += 512) {
    int row = f / 24, c0 = (f - row * 24) * 8;
    int jj = j0 + row;
    if (jj < LLEN) {
      bf16x8 v = *reinterpret_cast<const bf16x8*>(&xT2[row][c0]);
      *reinterpret_cast<bf16x8*>(&Y[((size_t)b * 627 + jj) * 192 + c0]) = v;
    }
  }
}

// ================= conv4 in place on Y (512 threads, 128 cols, no atomics) =================
__global__ __launch_bounds__(512) void conv4_ip(
    short* __restrict__ Y, const float* __restrict__ a3, const float* __restrict__ b3,
    const short* __restrict__ cw4b, const float* __restrict__ cb4p,
    float* __restrict__ Sp, float* __restrict__ Qp)
{
  __shared__ short xT[128][200];  // x3 staging, then y4 output staging
  const int tid = threadIdx.x;
  const int b = blockIdx.y, j0 = blockIdx.x * 128;
  for (int t = tid; t < 128 * 24; t += 512) {
    int col = t / 24, oct = t - col * 24;
    int jj = j0 + col;
    int c0 = oct * 8;
    bf16x8 pk;
    if (jj < LLEN) {
      bf16x8 raw = *reinterpret_cast<const bf16x8*>(&Y[((size_t)b * 627 + jj) * 192 + c0]);
      float4 alo = *reinterpret_cast<const float4*>(&a3[c0]);
      float4 ahi = *reinterpret_cast<const float4*>(&a3[c0 + 4]);
      float4 blo = *reinterpret_cast<const float4*>(&b3[c0]);
      float4 bhi = *reinterpret_cast<const float4*>(&b3[c0 + 4]);
      pk[0] = f2b(fmaxf(fmaf(alo.x, b2f(raw[0]), blo.x), 0.f));
      pk[1] = f2b(fmaxf(fmaf(alo.y, b2f(raw[1]), blo.y), 0.f));
      pk[2] = f2b(fmaxf(fmaf(alo.z, b2f(raw[2]), blo.z), 0.f));
      pk[3] = f2b(fmaxf(fmaf(alo.w, b2f(raw[3]), blo.w), 0.f));
      pk[4] = f2b(fmaxf(fmaf(ahi.x, b2f(raw[4]), bhi.x), 0.f));
      pk[5] = f2b(fmaxf(fmaf(ahi.y, b2f(raw[5]), bhi.y), 0.f));
      pk[6] = f2b(fmaxf(fmaf(ahi.z, b2f(raw[6]), bhi.z), 0.f));
      pk[7] = f2b(fmaxf(fmaf(ahi.w, b2f(raw[7]), bhi.w), 0.f));
    } else {
#pragma unroll
      for (int i = 0; i < 8; ++i) pk[i] = 0;
    }
    *reinterpret_cast<bf16x8*>(&xT[col][c0]) = pk;
  }
  __syncthreads();
  const int l = tid & 63, wv = tid >> 6, wm = wv >> 2, wn = wv & 3;
  const int lr = l & 15, lk = (l >> 4) * 8, lm4 = (l >> 4) * 4;
  f32x4 acc[6][2] = {};
#pragma unroll
  for (int ks = 0; ks < 6; ++ks) {
    int k0 = ks * 32 + lk;
    bf16x8 b0 = *reinterpret_cast<const bf16x8*>(&xT[wn * 32 + lr][k0]);
    bf16x8 b1 = *reinterpret_cast<const bf16x8*>(&xT[wn * 32 + 16 + lr][k0]);
#pragma unroll
    for (int mi = 0; mi < 6; ++mi) {
      bf16x8 av = *reinterpret_cast<const bf16x8*>(&cw4b[(wm * 96 + mi * 16 + lr) * 192 + k0]);
      acc[mi][0] = mfma16(av, b0, acc[mi][0]);
      acc[mi][1] = mfma16(av, b1, acc[mi][1]);
    }
  }
  __syncthreads();  // input reads done; reuse xT as y4 staging
  const size_t slot = (size_t)(blockIdx.y * gridDim.x + blockIdx.x) * 4 + wn;
#pragma unroll
  for (int mi = 0; mi < 6; ++mi) {
    int m0c = wm * 96 + mi * 16 + lm4;
    float s4[4] = {0.f, 0.f, 0.f, 0.f}, q4[4] = {0.f, 0.f, 0.f, 0.f};
#pragma unroll
    for (int nj = 0; nj < 2; ++nj) {
      int col = wn * 32 + nj * 16 + lr;
      int jj = j0 + col;
      float v0 = acc[mi][nj][0] + cb4p[m0c + 0];
      float v1 = acc[mi][nj][1] + cb4p[m0c + 1];
      float v2 = acc[mi][nj][2] + cb4p[m0c + 2];
      float v3 = acc[mi][nj][3] + cb4p[m0c + 3];
      if (jj < LLEN) {
        s4[0] += v0; q4[0] += v0 * v0;
        s4[1] += v1; q4[1] += v1 * v1;
        s4[2] += v2; q4[2] += v2 * v2;
        s4[3] += v3; q4[3] += v3 * v3;
      }
      uint2 w2;
      w2.x = (uint32)(ushort16)f2b(v0) | ((uint32)(ushort16)f2b(v1) << 16);
      w2.y = (uint32)(ushort16)f2b(v2) | ((uint32)(ushort16)f2b(v3) << 16);
      *reinterpret_cast<uint2*>(&xT[col][m0c]) = w2;
    }
#pragma unroll
    for (int off = 1; off < 16; off <<= 1)
#pragma unroll
      for (int r = 0; r < 4; ++r) { s4[r] += __shfl_xor(s4[r], off); q4[r] += __shfl_xor(q4[r], off); }
    if (lr == 0) {
#pragma unroll
      for (int r = 0; r < 4; ++r) {
        int o = m0c + r;
        if (o < 180) {
          Sp[slot * 180 + o] = s4[r];
          Qp[slot * 180 + o] = q4[r];
        }
      }
    }
  }
  __syncthreads();
  for (int f = tid; f < 128 * 24; f += 512) {
    int row = f / 24, c0 = (f - row * 24) * 8;
    int jj = j0 + row;
    if (jj < LLEN) {
      bf16x8 v = *reinterpret_cast<const bf16x8*>(&xT[row][c0]);
      *reinterpret_cast<bf16x8*>(&Y[((size_t)b * 627 + jj) * 192 + c0]) = v;
    }
  }
}

// ======= conv5 (MFMA) + register log_softmax + NLL; 64 cols/block, bias in place =======
__global__ __launch_bounds__(256) void conv5_nll(
    const short* __restrict__ Y, const float* __restrict__ a4, const float* __restrict__ b4,
    const short* __restrict__ cw5b, const float* __restrict__ cb5p,
    const float* __restrict__ inputs, float* __restrict__ nll)
{
  __shared__ float ab[384];
  __shared__ short xT[64][200];
  __shared__ float wmax[4][64];
  __shared__ float wsum[4][64];
  __shared__ float ptgt[64];
  __shared__ int tg[64];
  const int tid = threadIdx.x;
  const int b = blockIdx.y, l0 = blockIdx.x * 64;
  for (int t = tid; t < 384; t += 256) ab[t] = (t < 192) ? a4[t] : b4[t - 192];
  if (tid < 64) {
    int jj = l0 + tid;
    tg[tid] = (jj < LLEN) ? (int)inputs[(size_t)b * NI + jj] : 0;
  }
  __syncthreads();
  for (int t = tid; t < 64 * 24; t += 256) {
    int col = t / 24, oct = t - col * 24;
    int jj = l0 + col;
    int c0 = oct * 8;
    bf16x8 pk;
    if (jj < LLEN) {
      bf16x8 raw = *reinterpret_cast<const bf16x8*>(&Y[((size_t)b * 627 + jj) * 192 + c0]);
#pragma unroll
      for (int i = 0; i < 8; ++i)
        pk[i] = f2b(fmaxf(fmaf(ab[c0 + i], b2f(raw[i]), ab[192 + c0 + i]), 0.f));
    } else {
#pragma unroll
      for (int i = 0; i < 8; ++i) pk[i] = 0;
    }
    *reinterpret_cast<bf16x8*>(&xT[col][c0]) = pk;
  }
  __syncthreads();
  const int l = tid & 63, wv = tid >> 6;
  const int lr = l & 15, lk = (l >> 4) * 8, lm4 = (l >> 4) * 4;
  const int mf0 = wv * 5;
  f32x4 acc[5][4] = {};
#pragma unroll
  for (int ks = 0; ks < 6; ++ks) {
    int k0 = ks * 32 + lk;
    bf16x8 bb0 = *reinterpret_cast<const bf16x8*>(&xT[lr][k0]);
    bf16x8 bb1 = *reinterpret_cast<const bf16x8*>(&xT[16 + lr][k0]);
    bf16x8 bb2 = *reinterpret_cast<const bf16x8*>(&xT[32 + lr][k0]);
    bf16x8 bb3 = *reinterpret_cast<const bf16x8*>(&xT[48 + lr][k0]);
#pragma unroll
    for (int mi = 0; mi < 5; ++mi) {
      bf16x8 av = *reinterpret_cast<const bf16x8*>(&cw5b[((mf0 + mi) * 16 + lr) * 192 + k0]);
      acc[mi][0] = mfma16(av, bb0, acc[mi][0]);
      acc[mi][1] = mfma16(av, bb1, acc[mi][1]);
      acc[mi][2] = mfma16(av, bb2, acc[mi][2]);
      acc[mi][3] = mfma16(av, bb3, acc[mi][3]);
    }
  }
  // bias in place + per-col max (each lane: 4 cols x 20 rows)
  float vmax[4] = {-1e30f, -1e30f, -1e30f, -1e30f};
#pragma unroll
  for (int mi = 0; mi < 5; ++mi) {
#pragma unroll
    for (int r = 0; r < 4; ++r) {
      int m = (mf0 + mi) * 16 + lm4 + r;
      float bi = cb5p[m];
      bool ok = (m < 300);
#pragma unroll
      for (int nj = 0; nj < 4; ++nj) {
        float v = ok ? (acc[mi][nj][r] + bi) : -1e30f;
        acc[mi][nj][r] = v;
        vmax[nj] = fmaxf(vmax[nj], v);
      }
    }
  }
  // target gather (each (row,col) has exactly one owner lane)
  {
    int t0 = tg[lr], t1 = tg[16 + lr], t2 = tg[32 + lr], t3 = tg[48 + lr];
#pragma unroll
    for (int mi = 0; mi < 5; ++mi) {
#pragma unroll
      for (int r = 0; r < 4; ++r) {
        int m = (mf0 + mi) * 16 + lm4 + r;
        if (m == t0) ptgt[lr] = acc[mi][0][r];
        if (m == t1) ptgt[16 + lr] = acc[mi][1][r];
        if (m == t2) ptgt[32 + lr] = acc[mi][2][r];
        if (m == t3) ptgt[48 + lr] = acc[mi][3][r];
      }
    }
  }
#pragma unroll
  for (int nj = 0; nj < 4; ++nj) {
    vmax[nj] = fmaxf(vmax[nj], __shfl_xor(vmax[nj], 16));
    vmax[nj] = fmaxf(vmax[nj], __shfl_xor(vmax[nj], 32));
  }
  if (l < 16) {
#pragma unroll
    for (int nj = 0; nj < 4; ++nj) wmax[wv][nj * 16 + lr] = vmax[nj];
  }
  __syncthreads();
  float gmax[4], vs[4] = {0.f, 0.f, 0.f, 0.f};
#pragma unroll
  for (int nj = 0; nj < 4; ++nj) {
    int cc = nj * 16 + lr;
    gmax[nj] = fmaxf(fmaxf(wmax[0][cc], wmax[1][cc]), fmaxf(wmax[2][cc], wmax[3][cc]));
  }
#pragma unroll
  for (int mi = 0; mi < 5; ++mi)
#pragma unroll
    for (int r = 0; r < 4; ++r)
#pragma unroll
      for (int nj = 0; nj < 4; ++nj)
        vs[nj] += __expf(acc[mi][nj][r] - gmax[nj]);
#pragma unroll
  for (int nj = 0; nj < 4; ++nj) {
    vs[nj] += __shfl_xor(vs[nj], 16);
    vs[nj] += __shfl_xor(vs[nj], 32);
  }
  if (l < 16) {
#pragma unroll
    for (int nj = 0; nj < 4; ++nj) wsum[wv][nj * 16 + lr] = vs[nj];
  }
  __syncthreads();
  if (tid < 64) {
    int jj = l0 + tid;
    if (jj < LLEN) {
      float gm = fmaxf(fmaxf(wmax[0][tid], wmax[1][tid]), fmaxf(wmax[2][tid], wmax[3][tid]));
      float gs = wsum[0][tid] + wsum[1][tid] + wsum[2][tid] + wsum[3][tid];
      nll[(size_t)b * LLEN + jj] = gm + logf(gs) - ptgt[tid];
    }
  }
}

// ================= final assembly =================
__global__ __launch_bounds__(256) void ll_pass1(
    const float* __restrict__ outb, const float* __restrict__ nll,
    const float* __restrict__ inputs, float* __restrict__ llp, float* __restrict__ sc)
{
  int b = blockIdx.x;
  float s = 0.f;
  for (int l = 2 + (int)threadIdx.x; l < LLEN; l += 256) {
    float graw = outb[(size_t)b * NOUTF + l];
    float sg = 1.f / (1.f + expf(-graw));
    float term;
    if (inputs[(size_t)b * NI + l] > 0.f)
      term = 0.1f * logf(sg + 1e-10f) - nll[(size_t)b * LLEN + l];
    else
      term = 0.1f * logf(1.f - sg + 1e-10f);
    s += term;
  }
  for (int off = 1; off < 64; off <<= 1) s += __shfl_xor(s, off);
  __shared__ float tmp[4];
  if ((threadIdx.x & 63) == 0) tmp[threadIdx.x >> 6] = s;
  __syncthreads();
  if (threadIdx.x == 0) {
    llp[b] = tmp[0] + tmp[1] + tmp[2] + tmp[3];
    atomicAdd(sc, nll[(size_t)b * LLEN] + nll[(size_t)b * LLEN + 1]);
  }
}

__global__ void ll_pass2(const float* __restrict__ llp, const float* __restrict__ sc, float* __restrict__ outp)
{
  int i = blockIdx.x * blockDim.x + threadIdx.x;
  if (i < BATCH) outp[i] = llp[i] - sc[0] * (1.f / 1024.f);
}

extern "C" void kernel_launch(void* const* d_in, const int* in_sizes, int n_in,
                              void* d_out, int out_size, void* d_ws, size_t ws_size,
                              hipStream_t stream)
{
  const float* inputs = (const float*)d_in[0];
  const float* W_in = (const float*)d_in[1];
  const float* b_in = (const float*)d_in[2];
  const float* W_h1 = (const float*)d_in[3];
  const float* b_h1 = (const float*)d_in[4];
  const float* W_h2 = (const float*)d_in[5];
  const float* b_h2 = (const float*)d_in[6];
  const float* W_out = (const float*)d_in[7];
  const float* b_out = (const float*)d_in[8];
  const float* cw1 = (const float*)d_in[9];
  const float* g1 = (const float*)d_in[11];
  const float* be1 = (const float*)d_in[12];
  const float* cw2 = (const float*)d_in[13];
  const float* cb2 = (const float*)d_in[14];
  const float* g2 = (const float*)d_in[15];
  const float* be2 = (const float*)d_in[16];
  const float* cw3 = (const float*)d_in[17];
  const float* cb3 = (const float*)d_in[18];
  const float* g3 = (const float*)d_in[19];
  const float* be3 = (const float*)d_in[20];
  const float* cw4 = (const float*)d_in[21];
  const float* cb4 = (const float*)d_in[22];
  const float* g4 = (const float*)d_in[23];
  const float* be4 = (const float*)d_in[24];
  const float* cw5 = (const float*)d_in[25];
  const float* cb5 = (const float*)d_in[26];

  char* p = (char*)d_ws;
  short* Y = (short*)p;    p += (size_t)512 * 627 * 192 * 2;
  short* INB = (short*)p;  p += (size_t)512 * 640 * 2;
  short* HB1 = (short*)p;  p += (size_t)512 * 1024 * 2;
  short* HB2 = (short*)p;  p += (size_t)512 * 1024 * 2;
  short* HB3 = (short*)p;  p += (size_t)512 * 1024 * 2;
  short* WB1 = (short*)p;  p += (size_t)1024 * 640 * 2;
  short* WB2 = (short*)p;  p += (size_t)1024 * 1024 * 2;
  short* WB3 = (short*)p;  p += (size_t)1024 * 1024 * 2;
  short* WB4 = (short*)p;  p += (size_t)1280 * 1024 * 2;
  short* CW2B = (short*)p; p += (size_t)192 * 96 * 2;
  short* CW3B = (short*)p; p += (size_t)192 * 192 * 2;
  short* CW4B = (short*)p; p += (size_t)192 * 192 * 2;
  short* CW5B = (short*)p; p += (size_t)320 * 192 * 2;
  float* fp = (float*)p;
  float* OUTB = fp;  fp += (size_t)512 * 1254;
  float* NLLB = fp;  fp += 321028;
  float* LLP = fp;   fp += 512;
  float* A1 = fp;    fp += 96;
  float* B1g = fp;   fp += 96;
  float* A2 = fp;    fp += 192;
  float* B2g = fp;   fp += 192;
  float* A3 = fp;    fp += 192;
  float* B3g = fp;   fp += 192;
  float* A4 = fp;    fp += 192;
  float* B4g = fp;   fp += 192;
  float* CB2P = fp;  fp += 192;
  float* CB3P = fp;  fp += 192;
  float* CB4P = fp;  fp += 192;
  float* CB5P = fp;  fp += 320;
  float* TST = fp;   fp += 2;
  float* SC = fp;    fp += 2;
  float* SPP = fp;   fp += (size_t)NSLOT * 180;
  float* QPP = fp;   fp += (size_t)NSLOT * 180;
  float* SRED = fp;  fp += NRED * 180;
  float* QRED = fp;  fp += NRED * 180;

  hipMemsetAsync(TST, 0, 4 * sizeof(float), stream);

  // prep: inputs, masked MLP weights, conv weights, padded biases
  prep_inputs<<<dim3((512 * 640 + 255) / 256), 256, 0, stream>>>(inputs, INB);
  prep_mlpw<<<dim3((1024 * 640 + 255) / 256), 256, 0, stream>>>(W_in, WB1, 1024, 627, 1024, 640, 0);
  prep_mlpw<<<dim3((1024 * 1024 + 255) / 256), 256, 0, stream>>>(W_h1, WB2, 1024, 1024, 1024, 1024, 1);
  prep_mlpw<<<dim3((1024 * 1024 + 255) / 256), 256, 0, stream>>>(W_h2, WB3, 1024, 1024, 1024, 1024, 1);
  prep_mlpw<<<dim3((1280 * 1024 + 255) / 256), 256, 0, stream>>>(W_out, WB4, 1254, 1024, 1280, 1024, 2);
  prep_convw<<<dim3((192 * 96 + 255) / 256), 256, 0, stream>>>(cw2, CW2B, 180, 90, 192, 96);
  prep_convw<<<dim3((192 * 192 + 255) / 256), 256, 0, stream>>>(cw3, CW3B, 180, 180, 192, 192);
  prep_convw<<<dim3((192 * 192 + 255) / 256), 256, 0, stream>>>(cw4, CW4B, 180, 180, 192, 192);
  prep_convw<<<dim3((320 * 192 + 255) / 256), 256, 0, stream>>>(cw5, CW5B, 300, 180, 320, 192);
  prep_cb<<<1, 320, 0, stream>>>(cb2, cb3, cb4, cb5, CB2P, CB3P, CB4P, CB5P);

  // masked MLP (MFMA, 32x64 tiles, K-split-2)
  mlp_mfma<<<dim3(16, 16), 256, 0, stream>>>(INB, WB1, b_in, nullptr, HB1, 1024, 640, 1);
  mlp_mfma<<<dim3(16, 16), 256, 0, stream>>>(HB1, WB2, b_h1, nullptr, HB2, 1024, 1024, 1);
  mlp_mfma<<<dim3(16, 16), 256, 0, stream>>>(HB2, WB3, b_h2, nullptr, HB3, 1024, 1024, 0);
  mlp_mfma<<<dim3(20, 16), 256, 0, stream>>>(HB3, WB4, b_out, OUTB, nullptr, 1254, 1024, 0);

  // conv1+bn1 folded via theta stats
  theta_stats<<<dim3(BATCH), 256, 0, stream>>>(OUTB, TST);
  finalize_conv1<<<1, 96, 0, stream>>>(TST, cw1, g1, be1, A1, B1g);

  // conv2 stats -> bn2 fold
  conv2_stats<<<dim3(5, BATCH), 512, 0, stream>>>(OUTB, A1, B1g, CW2B, CB2P, SPP, QPP);
  bn_reduce1<<<dim3(NRED), 192, 0, stream>>>(SPP, QPP, SRED, QRED);
  finalize_bn2<<<1, 192, 0, stream>>>(SRED, QRED, g2, be2, A2, B2g);

  // fused conv2->conv3 -> Y (y3) + stats3 -> bn3 fold
  fused_conv23<<<dim3(5, BATCH), 512, 0, stream>>>(OUTB, A1, B1g, CW2B, CB2P, A2, B2g, CW3B, CB3P, Y, SPP, QPP);
  bn_reduce1<<<dim3(NRED), 192, 0, stream>>>(SPP, QPP, SRED, QRED);
  finalize_bn2<<<1, 192, 0, stream>>>(SRED, QRED, g3, be3, A3, B3g);

  // conv4 in place + stats4 -> bn4 fold
  conv4_ip<<<dim3(5, BATCH), 512, 0, stream>>>(Y, A3, B3g, CW4B, CB4P, SPP, QPP);
  bn_reduce1<<<dim3(NRED), 192, 0, stream>>>(SPP, QPP, SRED, QRED);
  finalize_bn2<<<1, 192, 0, stream>>>(SRED, QRED, g4, be4, A4, B4g);

  // conv5 + register log_softmax + nll (64 cols/block)
  conv5_nll<<<dim3(10, BATCH), 256, 0, stream>>>(Y, A4, B4g, CW5B, CB5P, inputs, NLLB);

  // final assembly
  ll_pass1<<<dim3(BATCH), 256, 0, stream>>>(OUTB, NLLB, inputs, LLP, SC);
  ll_pass2<<<dim3(2), 256, 0, stream>>>(LLP, SC, (float*)d_out);
}

// Round 10
// 665.865 us; speedup vs baseline: 5.9319x; 1.0168x over previous
//
#include <hip/hip_runtime.h>
#include <hip/hip_bf16.h>
#include <math.h>

#define BATCH 512
#define NI 627
#define NH 1024
#define NOUTF 1254
#define LLEN 627
#define NBL (512 * 627)
#define EPSBN 1e-5f
#define NSLOT 10240   // conv2: 2560 blocks*4 waves; conv3/4: 5120 blocks*2 waves
#define NRED 40       // stage-1 reduction blocks (10240/256)

typedef __attribute__((ext_vector_type(8))) short bf16x8;
typedef __attribute__((ext_vector_type(4))) float f32x4;
typedef unsigned int uint32;
typedef unsigned short ushort16;

__device__ inline short f2b(float x) {
  __hip_bfloat16 h = __float2bfloat16(x);
  return *reinterpret_cast<short*>(&h);
}
__device__ inline float b2f(short s) {
  return __uint_as_float(((uint32)(ushort16)s) << 16);
}
__device__ inline f32x4 mfma16(bf16x8 a, bf16x8 b, f32x4 c) {
  return __builtin_amdgcn_mfma_f32_16x16x32_bf16(a, b, c, 0, 0, 0);
}
// 8 channels k0..k0+7 of relu(a1*th+b1), packed bf16
__device__ inline bf16x8 buildx1(const float* __restrict__ A1v, const float* __restrict__ B1v,
                                 int k0, float th) {
  float4 alo = *reinterpret_cast<const float4*>(&A1v[k0]);
  float4 ahi = *reinterpret_cast<const float4*>(&A1v[k0 + 4]);
  float4 blo = *reinterpret_cast<const float4*>(&B1v[k0]);
  float4 bhi = *reinterpret_cast<const float4*>(&B1v[k0 + 4]);
  bf16x8 r;
  r[0] = f2b(fmaxf(fmaf(alo.x, th, blo.x), 0.f));
  r[1] = f2b(fmaxf(fmaf(alo.y, th, blo.y), 0.f));
  r[2] = f2b(fmaxf(fmaf(alo.z, th, blo.z), 0.f));
  r[3] = f2b(fmaxf(fmaf(alo.w, th, blo.w), 0.f));
  r[4] = f2b(fmaxf(fmaf(ahi.x, th, bhi.x), 0.f));
  r[5] = f2b(fmaxf(fmaf(ahi.y, th, bhi.y), 0.f));
  r[6] = f2b(fmaxf(fmaf(ahi.z, th, bhi.z), 0.f));
  r[7] = f2b(fmaxf(fmaf(ahi.w, th, bhi.w), 0.f));
  return r;
}

// ================= prep kernels =================
__global__ __launch_bounds__(256) void prep_inputs(const float* __restrict__ in, short* __restrict__ outp) {
  int i = blockIdx.x * 256 + threadIdx.x;
  if (i >= 512 * 640) return;
  int m = i / 640, k = i - m * 640;
  outp[i] = (k < NI) ? f2b(in[m * NI + k]) : (short)0;
}

__global__ __launch_bounds__(256) void prep_mlpw(const float* __restrict__ W, short* __restrict__ Wb,
                                                 int Nreal, int Kreal, int Npad, int Kpad, int mode) {
  int i = blockIdx.x * 256 + threadIdx.x;
  if (i >= Npad * Kpad) return;
  int n = i / Kpad, k = i - n * Kpad;
  float w = 0.f;
  if (n < Nreal && k < Kreal) {
    int od = n >= 627 ? n - 627 : n;
    int kd = k >= 627 ? k - 627 : k;
    bool keep = (mode == 0) ? (od >= k) : (mode == 1) ? (od >= kd) : (od > kd);
    if (keep) w = W[n * Kreal + k];
  }
  Wb[i] = f2b(w);
}

__global__ __launch_bounds__(256) void prep_convw(const float* __restrict__ W, short* __restrict__ Wb,
                                                  int Oreal, int Kreal, int Opad, int Kpad) {
  int i = blockIdx.x * 256 + threadIdx.x;
  if (i >= Opad * Kpad) return;
  int o = i / Kpad, k = i - o * Kpad;
  Wb[i] = (o < Oreal && k < Kreal) ? f2b(W[o * Kreal + k]) : (short)0;
}

__global__ void prep_cb(const float* __restrict__ cb2, const float* __restrict__ cb3,
                        const float* __restrict__ cb4, const float* __restrict__ cb5,
                        float* __restrict__ cb2p, float* __restrict__ cb3p,
                        float* __restrict__ cb4p, float* __restrict__ cb5p) {
  int c = threadIdx.x;  // 320 threads
  if (c < 192) {
    cb2p[c] = (c < 180) ? cb2[c] : 0.f;
    cb3p[c] = (c < 180) ? cb3[c] : 0.f;
    cb4p[c] = (c < 180) ? cb4[c] : 0.f;
  }
  if (c < 320) cb5p[c] = (c < 300) ? cb5[c] : 0.f;
}

// ====== MLP MFMA GEMM: 32x64 tile, K-split-2 across waves ======
__global__ __launch_bounds__(256) void mlp_mfma(
    const short* __restrict__ A, const short* __restrict__ Wb, const float* __restrict__ bias,
    float* __restrict__ Cf, short* __restrict__ Cb, int Nreal, int Kpad, int relu)
{
  __shared__ float red[2][2][2][4][64];  // [wn][mi][nj][r][lane] = 16 KB
  const int tid = threadIdx.x;
  const int l = tid & 63, wv = tid >> 6;
  const int wn = wv >> 1, kh = wv & 1;
  const int m0 = blockIdx.y * 32;
  const int n0 = blockIdx.x * 64 + wn * 32;
  const int lr = l & 15, lk = (l >> 4) * 8, lm4 = (l >> 4) * 4;
  f32x4 acc[2][2] = {};
  const int khalf = Kpad >> 1;
  const int nk = khalf >> 5;
  for (int ks = 0; ks < nk; ++ks) {
    int k0 = kh * khalf + ks * 32 + lk;
    bf16x8 a0 = *reinterpret_cast<const bf16x8*>(&A[(size_t)(m0 + lr) * Kpad + k0]);
    bf16x8 a1 = *reinterpret_cast<const bf16x8*>(&A[(size_t)(m0 + 16 + lr) * Kpad + k0]);
    bf16x8 b0 = *reinterpret_cast<const bf16x8*>(&Wb[(size_t)(n0 + lr) * Kpad + k0]);
    bf16x8 b1 = *reinterpret_cast<const bf16x8*>(&Wb[(size_t)(n0 + 16 + lr) * Kpad + k0]);
    acc[0][0] = mfma16(a0, b0, acc[0][0]);
    acc[0][1] = mfma16(a0, b1, acc[0][1]);
    acc[1][0] = mfma16(a1, b0, acc[1][0]);
    acc[1][1] = mfma16(a1, b1, acc[1][1]);
  }
  if (kh == 1) {
#pragma unroll
    for (int mi = 0; mi < 2; ++mi)
#pragma unroll
      for (int nj = 0; nj < 2; ++nj)
#pragma unroll
        for (int r = 0; r < 4; ++r) red[wn][mi][nj][r][l] = acc[mi][nj][r];
  }
  __syncthreads();
  if (kh == 0) {
#pragma unroll
    for (int mi = 0; mi < 2; ++mi)
#pragma unroll
      for (int nj = 0; nj < 2; ++nj) {
        int n = n0 + nj * 16 + lr;
        if (n >= Nreal) continue;
        float bi = bias[n];
#pragma unroll
        for (int r = 0; r < 4; ++r) {
          int m = m0 + mi * 16 + lm4 + r;
          float v = acc[mi][nj][r] + red[wn][mi][nj][r][l] + bi;
          if (relu) v = fmaxf(v, 0.f);
          if (Cb) Cb[(size_t)m * Nreal + n] = f2b(v);
          else Cf[(size_t)m * Nreal + n] = v;
        }
      }
  }
}

// ================= theta stats =================
__global__ __launch_bounds__(256) void theta_stats(const float* __restrict__ outb, float* __restrict__ tstat)
{
  int b = blockIdx.x;
  const float* th = outb + (size_t)b * NOUTF + NI;
  float s = 0.f, q = 0.f;
  for (int l = threadIdx.x; l < LLEN; l += 256) { float t = th[l]; s += t; q += t * t; }
  for (int off = 1; off < 64; off <<= 1) { s += __shfl_xor(s, off); q += __shfl_xor(q, off); }
  __shared__ float tmp[8];
  int w = threadIdx.x >> 6;
  if ((threadIdx.x & 63) == 0) { tmp[w] = s; tmp[4 + w] = q; }
  __syncthreads();
  if (threadIdx.x == 0) {
    atomicAdd(&tstat[0], tmp[0] + tmp[1] + tmp[2] + tmp[3]);
    atomicAdd(&tstat[1], tmp[4] + tmp[5] + tmp[6] + tmp[7]);
  }
}

__global__ void finalize_conv1(const float* __restrict__ tstat, const float* __restrict__ cw1,
                               const float* __restrict__ g1, const float* __restrict__ be1,
                               float* __restrict__ a1, float* __restrict__ b1)
{
  int c = threadIdx.x;  // 96
  if (c >= 96) return;
  if (c < 90) {
    float mt = tstat[0] / (float)NBL;
    float vt = tstat[1] / (float)NBL - mt * mt;
    float w = cw1[c];
    float rs = rsqrtf(w * w * vt + EPSBN);
    float a = w * g1[c] * rs;
    a1[c] = a;
    b1[c] = be1[c] - a * mt;
  } else { a1[c] = 0.f; b1[c] = 0.f; }
}

// ============ BN stats reduction: [NSLOT][180] -> [NRED][180] -> fold ============
__global__ __launch_bounds__(192) void bn_reduce1(const float* __restrict__ Sp, const float* __restrict__ Qp,
                                                  float* __restrict__ Sred, float* __restrict__ Qred)
{
  int c = threadIdx.x;
  if (c >= 180) return;
  int base = blockIdx.x * 256;
  float s = 0.f, q = 0.f;
  for (int r = 0; r < 256; ++r) {
    s += Sp[(size_t)(base + r) * 180 + c];
    q += Qp[(size_t)(base + r) * 180 + c];
  }
  Sred[blockIdx.x * 180 + c] = s;
  Qred[blockIdx.x * 180 + c] = q;
}

__global__ void finalize_bn2(const float* __restrict__ Sred, const float* __restrict__ Qred,
                             const float* __restrict__ g, const float* __restrict__ be,
                             float* __restrict__ aP, float* __restrict__ bP)
{
  int c = threadIdx.x;  // 192
  if (c >= 192) return;
  if (c < 180) {
    float s = 0.f, q = 0.f;
    for (int p = 0; p < NRED; ++p) { s += Sred[p * 180 + c]; q += Qred[p * 180 + c]; }
    float m = s / (float)NBL;
    float v = q / (float)NBL - m * m;
    float a = g[c] * rsqrtf(v + EPSBN);
    aP[c] = a;
    bP[c] = be[c] - m * a;
  } else { aP[c] = 0.f; bP[c] = 0.f; }
}

// ================= conv2 stats-only (512 threads, zero LDS, no atomics) =================
__global__ __launch_bounds__(512) void conv2_stats(
    const float* __restrict__ OUTB, const float* __restrict__ A1v, const float* __restrict__ B1v,
    const short* __restrict__ cw2b, const float* __restrict__ cb2p,
    float* __restrict__ Sp, float* __restrict__ Qp)
{
  const int tid = threadIdx.x;
  const int b = blockIdx.y, j0 = blockIdx.x * 128;
  const int l = tid & 63, wv = tid >> 6, wm = wv >> 2, wn = wv & 3;
  const int lr = l & 15, lk = (l >> 4) * 8, lm4 = (l >> 4) * 4;
  const int jj0 = j0 + wn * 32 + lr, jj1 = jj0 + 16;
  const float th0 = (jj0 < LLEN) ? OUTB[(size_t)b * NOUTF + NI + jj0] : 0.f;
  const float th1 = (jj1 < LLEN) ? OUTB[(size_t)b * NOUTF + NI + jj1] : 0.f;
  f32x4 acc[6][2] = {};
#pragma unroll
  for (int ks = 0; ks < 3; ++ks) {
    int k0 = ks * 32 + lk;
    bf16x8 b0 = buildx1(A1v, B1v, k0, th0);
    bf16x8 b1 = buildx1(A1v, B1v, k0, th1);
#pragma unroll
    for (int mi = 0; mi < 6; ++mi) {
      bf16x8 av = *reinterpret_cast<const bf16x8*>(&cw2b[(wm * 96 + mi * 16 + lr) * 96 + k0]);
      acc[mi][0] = mfma16(av, b0, acc[mi][0]);
      acc[mi][1] = mfma16(av, b1, acc[mi][1]);
    }
  }
  const size_t slot = (size_t)(blockIdx.y * gridDim.x + blockIdx.x) * 4 + wn;
#pragma unroll
  for (int mi = 0; mi < 6; ++mi) {
    int m0c = wm * 96 + mi * 16 + lm4;
    float s4[4] = {0.f, 0.f, 0.f, 0.f}, q4[4] = {0.f, 0.f, 0.f, 0.f};
#pragma unroll
    for (int nj = 0; nj < 2; ++nj) {
      int jj = j0 + wn * 32 + nj * 16 + lr;
      if (jj < LLEN) {
#pragma unroll
        for (int r = 0; r < 4; ++r) {
          float v = acc[mi][nj][r] + cb2p[m0c + r];
          s4[r] += v; q4[r] += v * v;
        }
      }
    }
#pragma unroll
    for (int off = 1; off < 16; off <<= 1)
#pragma unroll
      for (int r = 0; r < 4; ++r) { s4[r] += __shfl_xor(s4[r], off); q4[r] += __shfl_xor(q4[r], off); }
    if (lr == 0) {
#pragma unroll
      for (int r = 0; r < 4; ++r) {
        int o = m0c + r;
        if (o < 180) {
          Sp[slot * 180 + o] = s4[r];
          Qp[slot * 180 + o] = q4[r];
        }
      }
    }
  }
}

// ==== fused conv2 -> bn2 -> relu -> conv3: 64 cols, 8 waves (wm 4-way), 25.6 KB LDS ====
__global__ __launch_bounds__(512) void fused_conv23(
    const float* __restrict__ OUTB, const float* __restrict__ A1v, const float* __restrict__ B1v,
    const short* __restrict__ cw2b, const float* __restrict__ cb2p,
    const float* __restrict__ a2, const float* __restrict__ b2,
    const short* __restrict__ cw3b, const float* __restrict__ cb3p,
    short* __restrict__ Y, float* __restrict__ Sp, float* __restrict__ Qp)
{
  __shared__ short xT2[64][200];  // x2 staging, then y3 output staging
  const int tid = threadIdx.x;
  const int b = blockIdx.y, j0 = blockIdx.x * 64;
  const int l = tid & 63, wv = tid >> 6, wm = wv >> 1, wn = wv & 1;
  const int lr = l & 15, lk = (l >> 4) * 8, lm4 = (l >> 4) * 4;
  const int jj0 = j0 + wn * 32 + lr, jj1 = jj0 + 16;
  const float th0 = (jj0 < LLEN) ? OUTB[(size_t)b * NOUTF + NI + jj0] : 0.f;
  const float th1 = (jj1 < LLEN) ? OUTB[(size_t)b * NOUTF + NI + jj1] : 0.f;
  // conv2: channels wm*48 .. wm*48+47 (3 m-frags)
  f32x4 acc[3][2] = {};
#pragma unroll
  for (int ks = 0; ks < 3; ++ks) {
    int k0 = ks * 32 + lk;
    bf16x8 b0 = buildx1(A1v, B1v, k0, th0);
    bf16x8 b1 = buildx1(A1v, B1v, k0, th1);
#pragma unroll
    for (int mi = 0; mi < 3; ++mi) {
      bf16x8 av = *reinterpret_cast<const bf16x8*>(&cw2b[(wm * 48 + mi * 16 + lr) * 96 + k0]);
      acc[mi][0] = mfma16(av, b0, acc[mi][0]);
      acc[mi][1] = mfma16(av, b1, acc[mi][1]);
    }
  }
  // x2 = relu(a2*(y2+cb2)+b2) -> xT2
#pragma unroll
  for (int mi = 0; mi < 3; ++mi) {
    int m0c = wm * 48 + mi * 16 + lm4;
#pragma unroll
    for (int nj = 0; nj < 2; ++nj) {
      int col = wn * 32 + nj * 16 + lr;
      float y0 = acc[mi][nj][0] + cb2p[m0c + 0];
      float y1 = acc[mi][nj][1] + cb2p[m0c + 1];
      float y2v = acc[mi][nj][2] + cb2p[m0c + 2];
      float y3v = acc[mi][nj][3] + cb2p[m0c + 3];
      float x0 = fmaxf(fmaf(a2[m0c + 0], y0, b2[m0c + 0]), 0.f);
      float x1 = fmaxf(fmaf(a2[m0c + 1], y1, b2[m0c + 1]), 0.f);
      float x2 = fmaxf(fmaf(a2[m0c + 2], y2v, b2[m0c + 2]), 0.f);
      float x3 = fmaxf(fmaf(a2[m0c + 3], y3v, b2[m0c + 3]), 0.f);
      uint2 w2;
      w2.x = (uint32)(ushort16)f2b(x0) | ((uint32)(ushort16)f2b(x1) << 16);
      w2.y = (uint32)(ushort16)f2b(x2) | ((uint32)(ushort16)f2b(x3) << 16);
      *reinterpret_cast<uint2*>(&xT2[col][m0c]) = w2;
    }
  }
  __syncthreads();
  // conv3
  f32x4 acc2[3][2] = {};
#pragma unroll
  for (int ks = 0; ks < 6; ++ks) {
    int k0 = ks * 32 + lk;
    bf16x8 b0 = *reinterpret_cast<const bf16x8*>(&xT2[wn * 32 + lr][k0]);
    bf16x8 b1 = *reinterpret_cast<const bf16x8*>(&xT2[wn * 32 + 16 + lr][k0]);
#pragma unroll
    for (int mi = 0; mi < 3; ++mi) {
      bf16x8 av = *reinterpret_cast<const bf16x8*>(&cw3b[(wm * 48 + mi * 16 + lr) * 192 + k0]);
      acc2[mi][0] = mfma16(av, b0, acc2[mi][0]);
      acc2[mi][1] = mfma16(av, b1, acc2[mi][1]);
    }
  }
  __syncthreads();  // conv3 reads done; reuse xT2 as y3 staging
  const size_t slot = (size_t)(blockIdx.y * gridDim.x + blockIdx.x) * 2 + wn;
#pragma unroll
  for (int mi = 0; mi < 3; ++mi) {
    int m0c = wm * 48 + mi * 16 + lm4;
    float s4[4] = {0.f, 0.f, 0.f, 0.f}, q4[4] = {0.f, 0.f, 0.f, 0.f};
#pragma unroll
    for (int nj = 0; nj < 2; ++nj) {
      int col = wn * 32 + nj * 16 + lr;
      int jj = j0 + col;
      float v0 = acc2[mi][nj][0] + cb3p[m0c + 0];
      float v1 = acc2[mi][nj][1] + cb3p[m0c + 1];
      float v2 = acc2[mi][nj][2] + cb3p[m0c + 2];
      float v3 = acc2[mi][nj][3] + cb3p[m0c + 3];
      if (jj < LLEN) {
        s4[0] += v0; q4[0] += v0 * v0;
        s4[1] += v1; q4[1] += v1 * v1;
        s4[2] += v2; q4[2] += v2 * v2;
        s4[3] += v3; q4[3] += v3 * v3;
      }
      uint2 w2;
      w2.x = (uint32)(ushort16)f2b(v0) | ((uint32)(ushort16)f2b(v1) << 16);
      w2.y = (uint32)(ushort16)f2b(v2) | ((uint32)(ushort16)f2b(v3) << 16);
      *reinterpret_cast<uint2*>(&xT2[col][m0c]) = w2;
    }
#pragma unroll
    for (int off = 1; off < 16; off <<= 1)
#pragma unroll
      for (int r = 0; r < 4; ++r) { s4[r] += __shfl_xor(s4[r], off); q4[r] += __shfl_xor(q4[r], off); }
    if (lr == 0) {
#pragma unroll
      for (int r = 0; r < 4; ++r) {
        int o = m0c + r;
        if (o < 180) {
          Sp[slot * 180 + o] = s4[r];
          Qp[slot * 180 + o] = q4[r];
        }
      }
    }
  }
  __syncthreads();
  // coalesced copy out: 64 rows x 192 shorts
  for (int f = tid; f < 64 * 24; f += 512) {
    int row = f / 24, c0 = (f - row * 24) * 8;
    int jj = j0 + row;
    if (jj < LLEN) {
      bf16x8 v = *reinterpret_cast<const bf16x8*>(&xT2[row][c0]);
      *reinterpret_cast<bf16x8*>(&Y[((size_t)b * 627 + jj) * 192 + c0]) = v;
    }
  }
}

// ====== conv4 in place on Y: 64 cols, 8 waves (wm 4-way), 25.6 KB LDS ======
__global__ __launch_bounds__(512) void conv4_ip(
    short* __restrict__ Y, const float* __restrict__ a3, const float* __restrict__ b3,
    const short* __restrict__ cw4b, const float* __restrict__ cb4p,
    float* __restrict__ Sp, float* __restrict__ Qp)
{
  __shared__ short xT[64][200];  // x3 staging, then y4 output staging
  const int tid = threadIdx.x;
  const int b = blockIdx.y, j0 = blockIdx.x * 64;
  for (int t = tid; t < 64 * 24; t += 512) {
    int col = t / 24, oct = t - col * 24;
    int jj = j0 + col;
    int c0 = oct * 8;
    bf16x8 pk;
    if (jj < LLEN) {
      bf16x8 raw = *reinterpret_cast<const bf16x8*>(&Y[((size_t)b * 627 + jj) * 192 + c0]);
      float4 alo = *reinterpret_cast<const float4*>(&a3[c0]);
      float4 ahi = *reinterpret_cast<const float4*>(&a3[c0 + 4]);
      float4 blo = *reinterpret_cast<const float4*>(&b3[c0]);
      float4 bhi = *reinterpret_cast<const float4*>(&b3[c0 + 4]);
      pk[0] = f2b(fmaxf(fmaf(alo.x, b2f(raw[0]), blo.x), 0.f));
      pk[1] = f2b(fmaxf(fmaf(alo.y, b2f(raw[1]), blo.y), 0.f));
      pk[2] = f2b(fmaxf(fmaf(alo.z, b2f(raw[2]), blo.z), 0.f));
      pk[3] = f2b(fmaxf(fmaf(alo.w, b2f(raw[3]), blo.w), 0.f));
      pk[4] = f2b(fmaxf(fmaf(ahi.x, b2f(raw[4]), bhi.x), 0.f));
      pk[5] = f2b(fmaxf(fmaf(ahi.y, b2f(raw[5]), bhi.y), 0.f));
      pk[6] = f2b(fmaxf(fmaf(ahi.z, b2f(raw[6]), bhi.z), 0.f));
      pk[7] = f2b(fmaxf(fmaf(ahi.w, b2f(raw[7]), bhi.w), 0.f));
    } else {
#pragma unroll
      for (int i = 0; i < 8; ++i) pk[i] = 0;
    }
    *reinterpret_cast<bf16x8*>(&xT[col][c0]) = pk;
  }
  __syncthreads();
  const int l = tid & 63, wv = tid >> 6, wm = wv >> 1, wn = wv & 1;
  const int lr = l & 15, lk = (l >> 4) * 8, lm4 = (l >> 4) * 4;
  f32x4 acc[3][2] = {};
#pragma unroll
  for (int ks = 0; ks < 6; ++ks) {
    int k0 = ks * 32 + lk;
    bf16x8 b0 = *reinterpret_cast<const bf16x8*>(&xT[wn * 32 + lr][k0]);
    bf16x8 b1 = *reinterpret_cast<const bf16x8*>(&xT[wn * 32 + 16 + lr][k0]);
#pragma unroll
    for (int mi = 0; mi < 3; ++mi) {
      bf16x8 av = *reinterpret_cast<const bf16x8*>(&cw4b[(wm * 48 + mi * 16 + lr) * 192 + k0]);
      acc[mi][0] = mfma16(av, b0, acc[mi][0]);
      acc[mi][1] = mfma16(av, b1, acc[mi][1]);
    }
  }
  __syncthreads();  // input reads done; reuse xT as y4 staging
  const size_t slot = (size_t)(blockIdx.y * gridDim.x + blockIdx.x) * 2 + wn;
#pragma unroll
  for (int mi = 0; mi < 3; ++mi) {
    int m0c = wm * 48 + mi * 16 + lm4;
    float s4[4] = {0.f, 0.f, 0.f, 0.f}, q4[4] = {0.f, 0.f, 0.f, 0.f};
#pragma unroll
    for (int nj = 0; nj < 2; ++nj) {
      int col = wn * 32 + nj * 16 + lr;
      int jj = j0 + col;
      float v0 = acc[mi][nj][0] + cb4p[m0c + 0];
      float v1 = acc[mi][nj][1] + cb4p[m0c + 1];
      float v2 = acc[mi][nj][2] + cb4p[m0c + 2];
      float v3 = acc[mi][nj][3] + cb4p[m0c + 3];
      if (jj < LLEN) {
        s4[0] += v0; q4[0] += v0 * v0;
        s4[1] += v1; q4[1] += v1 * v1;
        s4[2] += v2; q4[2] += v2 * v2;
        s4[3] += v3; q4[3] += v3 * v3;
      }
      uint2 w2;
      w2.x = (uint32)(ushort16)f2b(v0) | ((uint32)(ushort16)f2b(v1) << 16);
      w2.y = (uint32)(ushort16)f2b(v2) | ((uint32)(ushort16)f2b(v3) << 16);
      *reinterpret_cast<uint2*>(&xT[col][m0c]) = w2;
    }
#pragma unroll
    for (int off = 1; off < 16; off <<= 1)
#pragma unroll
      for (int r = 0; r < 4; ++r) { s4[r] += __shfl_xor(s4[r], off); q4[r] += __shfl_xor(q4[r], off); }
    if (lr == 0) {
#pragma unroll
      for (int r = 0; r < 4; ++r) {
        int o = m0c + r;
        if (o < 180) {
          Sp[slot * 180 + o] = s4[r];
          Qp[slot * 180 + o] = q4[r];
        }
      }
    }
  }
  __syncthreads();
  for (int f = tid; f < 64 * 24; f += 512) {
    int row = f / 24, c0 = (f - row * 24) * 8;
    int jj = j0 + row;
    if (jj < LLEN) {
      bf16x8 v = *reinterpret_cast<const bf16x8*>(&xT[row][c0]);
      *reinterpret_cast<bf16x8*>(&Y[((size_t)b * 627 + jj) * 192 + c0]) = v;
    }
  }
}

// ======= conv5 (MFMA) + register log_softmax + NLL; 64 cols/block =======
__global__ __launch_bounds__(256) void conv5_nll(
    const short* __restrict__ Y, const float* __restrict__ a4, const float* __restrict__ b4,
    const short* __restrict__ cw5b, const float* __restrict__ cb5p,
    const float* __restrict__ inputs, float* __restrict__ nll)
{
  __shared__ float ab[384];
  __shared__ short xT[64][200];
  __shared__ float wmax[4][64];
  __shared__ float wsum[4][64];
  __shared__ float ptgt[64];
  __shared__ int tg[64];
  const int tid = threadIdx.x;
  const int b = blockIdx.y, l0 = blockIdx.x * 64;
  for (int t = tid; t < 384; t += 256) ab[t] = (t < 192) ? a4[t] : b4[t - 192];
  if (tid < 64) {
    int jj = l0 + tid;
    tg[tid] = (jj < LLEN) ? (int)inputs[(size_t)b * NI + jj] : 0;
  }
  __syncthreads();
  for (int t = tid; t < 64 * 24; t += 256) {
    int col = t / 24, oct = t - col * 24;
    int jj = l0 + col;
    int c0 = oct * 8;
    bf16x8 pk;
    if (jj < LLEN) {
      bf16x8 raw = *reinterpret_cast<const bf16x8*>(&Y[((size_t)b * 627 + jj) * 192 + c0]);
#pragma unroll
      for (int i = 0; i < 8; ++i)
        pk[i] = f2b(fmaxf(fmaf(ab[c0 + i], b2f(raw[i]), ab[192 + c0 + i]), 0.f));
    } else {
#pragma unroll
      for (int i = 0; i < 8; ++i) pk[i] = 0;
    }
    *reinterpret_cast<bf16x8*>(&xT[col][c0]) = pk;
  }
  __syncthreads();
  const int l = tid & 63, wv = tid >> 6;
  const int lr = l & 15, lk = (l >> 4) * 8, lm4 = (l >> 4) * 4;
  const int mf0 = wv * 5;
  f32x4 acc[5][4] = {};
#pragma unroll
  for (int ks = 0; ks < 6; ++ks) {
    int k0 = ks * 32 + lk;
    bf16x8 bb0 = *reinterpret_cast<const bf16x8*>(&xT[lr][k0]);
    bf16x8 bb1 = *reinterpret_cast<const bf16x8*>(&xT[16 + lr][k0]);
    bf16x8 bb2 = *reinterpret_cast<const bf16x8*>(&xT[32 + lr][k0]);
    bf16x8 bb3 = *reinterpret_cast<const bf16x8*>(&xT[48 + lr][k0]);
#pragma unroll
    for (int mi = 0; mi < 5; ++mi) {
      bf16x8 av = *reinterpret_cast<const bf16x8*>(&cw5b[((mf0 + mi) * 16 + lr) * 192 + k0]);
      acc[mi][0] = mfma16(av, bb0, acc[mi][0]);
      acc[mi][1] = mfma16(av, bb1, acc[mi][1]);
      acc[mi][2] = mfma16(av, bb2, acc[mi][2]);
      acc[mi][3] = mfma16(av, bb3, acc[mi][3]);
    }
  }
  // bias in place + per-col max (each lane: 4 cols x 20 rows)
  float vmax[4] = {-1e30f, -1e30f, -1e30f, -1e30f};
#pragma unroll
  for (int mi = 0; mi < 5; ++mi) {
#pragma unroll
    for (int r = 0; r < 4; ++r) {
      int m = (mf0 + mi) * 16 + lm4 + r;
      float bi = cb5p[m];
      bool ok = (m < 300);
#pragma unroll
      for (int nj = 0; nj < 4; ++nj) {
        float v = ok ? (acc[mi][nj][r] + bi) : -1e30f;
        acc[mi][nj][r] = v;
        vmax[nj] = fmaxf(vmax[nj], v);
      }
    }
  }
  // target gather (each (row,col) has exactly one owner lane)
  {
    int t0 = tg[lr], t1 = tg[16 + lr], t2 = tg[32 + lr], t3 = tg[48 + lr];
#pragma unroll
    for (int mi = 0; mi < 5; ++mi) {
#pragma unroll
      for (int r = 0; r < 4; ++r) {
        int m = (mf0 + mi) * 16 + lm4 + r;
        if (m == t0) ptgt[lr] = acc[mi][0][r];
        if (m == t1) ptgt[16 + lr] = acc[mi][1][r];
        if (m == t2) ptgt[32 + lr] = acc[mi][2][r];
        if (m == t3) ptgt[48 + lr] = acc[mi][3][r];
      }
    }
  }
#pragma unroll
  for (int nj = 0; nj < 4; ++nj) {
    vmax[nj] = fmaxf(vmax[nj], __shfl_xor(vmax[nj], 16));
    vmax[nj] = fmaxf(vmax[nj], __shfl_xor(vmax[nj], 32));
  }
  if (l < 16) {
#pragma unroll
    for (int nj = 0; nj < 4; ++nj) wmax[wv][nj * 16 + lr] = vmax[nj];
  }
  __syncthreads();
  float gmax[4], vs[4] = {0.f, 0.f, 0.f, 0.f};
#pragma unroll
  for (int nj = 0; nj < 4; ++nj) {
    int cc = nj * 16 + lr;
    gmax[nj] = fmaxf(fmaxf(wmax[0][cc], wmax[1][cc]), fmaxf(wmax[2][cc], wmax[3][cc]));
  }
#pragma unroll
  for (int mi = 0; mi < 5; ++mi)
#pragma unroll
    for (int r = 0; r < 4; ++r)
#pragma unroll
      for (int nj = 0; nj < 4; ++nj)
        vs[nj] += __expf(acc[mi][nj][r] - gmax[nj]);
#pragma unroll
  for (int nj = 0; nj < 4; ++nj) {
    vs[nj] += __shfl_xor(vs[nj], 16);
    vs[nj] += __shfl_xor(vs[nj], 32);
  }
  if (l < 16) {
#pragma unroll
    for (int nj = 0; nj < 4; ++nj) wsum[wv][nj * 16 + lr] = vs[nj];
  }
  __syncthreads();
  if (tid < 64) {
    int jj = l0 + tid;
    if (jj < LLEN) {
      float gm = fmaxf(fmaxf(wmax[0][tid], wmax[1][tid]), fmaxf(wmax[2][tid], wmax[3][tid]));
      float gs = wsum[0][tid] + wsum[1][tid] + wsum[2][tid] + wsum[3][tid];
      nll[(size_t)b * LLEN + jj] = gm + logf(gs) - ptgt[tid];
    }
  }
}

// ================= final assembly =================
__global__ __launch_bounds__(256) void ll_pass1(
    const float* __restrict__ outb, const float* __restrict__ nll,
    const float* __restrict__ inputs, float* __restrict__ llp, float* __restrict__ sc)
{
  int b = blockIdx.x;
  float s = 0.f;
  for (int l = 2 + (int)threadIdx.x; l < LLEN; l += 256) {
    float graw = outb[(size_t)b * NOUTF + l];
    float sg = 1.f / (1.f + expf(-graw));
    float term;
    if (inputs[(size_t)b * NI + l] > 0.f)
      term = 0.1f * logf(sg + 1e-10f) - nll[(size_t)b * LLEN + l];
    else
      term = 0.1f * logf(1.f - sg + 1e-10f);
    s += term;
  }
  for (int off = 1; off < 64; off <<= 1) s += __shfl_xor(s, off);
  __shared__ float tmp[4];
  if ((threadIdx.x & 63) == 0) tmp[threadIdx.x >> 6] = s;
  __syncthreads();
  if (threadIdx.x == 0) {
    llp[b] = tmp[0] + tmp[1] + tmp[2] + tmp[3];
    atomicAdd(sc, nll[(size_t)b * LLEN] + nll[(size_t)b * LLEN + 1]);
  }
}

__global__ void ll_pass2(const float* __restrict__ llp, const float* __restrict__ sc, float* __restrict__ outp)
{
  int i = blockIdx.x * blockDim.x + threadIdx.x;
  if (i < BATCH) outp[i] = llp[i] - sc[0] * (1.f / 1024.f);
}

extern "C" void kernel_launch(void* const* d_in, const int* in_sizes, int n_in,
                              void* d_out, int out_size, void* d_ws, size_t ws_size,
                              hipStream_t stream)
{
  const float* inputs = (const float*)d_in[0];
  const float* W_in = (const float*)d_in[1];
  const float* b_in = (const float*)d_in[2];
  const float* W_h1 = (const float*)d_in[3];
  const float* b_h1 = (const float*)d_in[4];
  const float* W_h2 = (const float*)d_in[5];
  const float* b_h2 = (const float*)d_in[6];
  const float* W_out = (const float*)d_in[7];
  const float* b_out = (const float*)d_in[8];
  const float* cw1 = (const float*)d_in[9];
  const float* g1 = (const float*)d_in[11];
  const float* be1 = (const float*)d_in[12];
  const float* cw2 = (const float*)d_in[13];
  const float* cb2 = (const float*)d_in[14];
  const float* g2 = (const float*)d_in[15];
  const float* be2 = (const float*)d_in[16];
  const float* cw3 = (const float*)d_in[17];
  const float* cb3 = (const float*)d_in[18];
  const float* g3 = (const float*)d_in[19];
  const float* be3 = (const float*)d_in[20];
  const float* cw4 = (const float*)d_in[21];
  const float* cb4 = (const float*)d_in[22];
  const float* g4 = (const float*)d_in[23];
  const float* be4 = (const float*)d_in[24];
  const float* cw5 = (const float*)d_in[25];
  const float* cb5 = (const float*)d_in[26];

  char* p = (char*)d_ws;
  short* Y = (short*)p;    p += (size_t)512 * 627 * 192 * 2;
  short* INB = (short*)p;  p += (size_t)512 * 640 * 2;
  short* HB1 = (short*)p;  p += (size_t)512 * 1024 * 2;
  short* HB2 = (short*)p;  p += (size_t)512 * 1024 * 2;
  short* HB3 = (short*)p;  p += (size_t)512 * 1024 * 2;
  short* WB1 = (short*)p;  p += (size_t)1024 * 640 * 2;
  short* WB2 = (short*)p;  p += (size_t)1024 * 1024 * 2;
  short* WB3 = (short*)p;  p += (size_t)1024 * 1024 * 2;
  short* WB4 = (short*)p;  p += (size_t)1280 * 1024 * 2;
  short* CW2B = (short*)p; p += (size_t)192 * 96 * 2;
  short* CW3B = (short*)p; p += (size_t)192 * 192 * 2;
  short* CW4B = (short*)p; p += (size_t)192 * 192 * 2;
  short* CW5B = (short*)p; p += (size_t)320 * 192 * 2;
  float* fp = (float*)p;
  float* OUTB = fp;  fp += (size_t)512 * 1254;
  float* NLLB = fp;  fp += 321028;
  float* LLP = fp;   fp += 512;
  float* A1 = fp;    fp += 96;
  float* B1g = fp;   fp += 96;
  float* A2 = fp;    fp += 192;
  float* B2g = fp;   fp += 192;
  float* A3 = fp;    fp += 192;
  float* B3g = fp;   fp += 192;
  float* A4 = fp;    fp += 192;
  float* B4g = fp;   fp += 192;
  float* CB2P = fp;  fp += 192;
  float* CB3P = fp;  fp += 192;
  float* CB4P = fp;  fp += 192;
  float* CB5P = fp;  fp += 320;
  float* TST = fp;   fp += 2;
  float* SC = fp;    fp += 2;
  float* SPP = fp;   fp += (size_t)NSLOT * 180;
  float* QPP = fp;   fp += (size_t)NSLOT * 180;
  float* SRED = fp;  fp += NRED * 180;
  float* QRED = fp;  fp += NRED * 180;

  hipMemsetAsync(TST, 0, 4 * sizeof(float), stream);

  // prep: inputs, masked MLP weights, conv weights, padded biases
  prep_inputs<<<dim3((512 * 640 + 255) / 256), 256, 0, stream>>>(inputs, INB);
  prep_mlpw<<<dim3((1024 * 640 + 255) / 256), 256, 0, stream>>>(W_in, WB1, 1024, 627, 1024, 640, 0);
  prep_mlpw<<<dim3((1024 * 1024 + 255) / 256), 256, 0, stream>>>(W_h1, WB2, 1024, 1024, 1024, 1024, 1);
  prep_mlpw<<<dim3((1024 * 1024 + 255) / 256), 256, 0, stream>>>(W_h2, WB3, 1024, 1024, 1024, 1024, 1);
  prep_mlpw<<<dim3((1280 * 1024 + 255) / 256), 256, 0, stream>>>(W_out, WB4, 1254, 1024, 1280, 1024, 2);
  prep_convw<<<dim3((192 * 96 + 255) / 256), 256, 0, stream>>>(cw2, CW2B, 180, 90, 192, 96);
  prep_convw<<<dim3((192 * 192 + 255) / 256), 256, 0, stream>>>(cw3, CW3B, 180, 180, 192, 192);
  prep_convw<<<dim3((192 * 192 + 255) / 256), 256, 0, stream>>>(cw4, CW4B, 180, 180, 192, 192);
  prep_convw<<<dim3((320 * 192 + 255) / 256), 256, 0, stream>>>(cw5, CW5B, 300, 180, 320, 192);
  prep_cb<<<1, 320, 0, stream>>>(cb2, cb3, cb4, cb5, CB2P, CB3P, CB4P, CB5P);

  // masked MLP (MFMA, 32x64 tiles, K-split-2)
  mlp_mfma<<<dim3(16, 16), 256, 0, stream>>>(INB, WB1, b_in, nullptr, HB1, 1024, 640, 1);
  mlp_mfma<<<dim3(16, 16), 256, 0, stream>>>(HB1, WB2, b_h1, nullptr, HB2, 1024, 1024, 1);
  mlp_mfma<<<dim3(16, 16), 256, 0, stream>>>(HB2, WB3, b_h2, nullptr, HB3, 1024, 1024, 0);
  mlp_mfma<<<dim3(20, 16), 256, 0, stream>>>(HB3, WB4, b_out, OUTB, nullptr, 1254, 1024, 0);

  // conv1+bn1 folded via theta stats
  theta_stats<<<dim3(BATCH), 256, 0, stream>>>(OUTB, TST);
  finalize_conv1<<<1, 96, 0, stream>>>(TST, cw1, g1, be1, A1, B1g);

  // conv2 stats -> bn2 fold
  conv2_stats<<<dim3(5, BATCH), 512, 0, stream>>>(OUTB, A1, B1g, CW2B, CB2P, SPP, QPP);
  bn_reduce1<<<dim3(NRED), 192, 0, stream>>>(SPP, QPP, SRED, QRED);
  finalize_bn2<<<1, 192, 0, stream>>>(SRED, QRED, g2, be2, A2, B2g);

  // fused conv2->conv3 -> Y (y3) + stats3 -> bn3 fold
  fused_conv23<<<dim3(10, BATCH), 512, 0, stream>>>(OUTB, A1, B1g, CW2B, CB2P, A2, B2g, CW3B, CB3P, Y, SPP, QPP);
  bn_reduce1<<<dim3(NRED), 192, 0, stream>>>(SPP, QPP, SRED, QRED);
  finalize_bn2<<<1, 192, 0, stream>>>(SRED, QRED, g3, be3, A3, B3g);

  // conv4 in place + stats4 -> bn4 fold
  conv4_ip<<<dim3(10, BATCH), 512, 0, stream>>>(Y, A3, B3g, CW4B, CB4P, SPP, QPP);
  bn_reduce1<<<dim3(NRED), 192, 0, stream>>>(SPP, QPP, SRED, QRED);
  finalize_bn2<<<1, 192, 0, stream>>>(SRED, QRED, g4, be4, A4, B4g);

  // conv5 + register log_softmax + nll (64 cols/block)
  conv5_nll<<<dim3(10, BATCH), 256, 0, stream>>>(Y, A4, B4g, CW5B, CB5P, inputs, NLLB);

  // final assembly
  ll_pass1<<<dim3(BATCH), 256, 0, stream>>>(OUTB, NLLB, inputs, LLP, SC);
  ll_pass2<<<dim3(2), 256, 0, stream>>>(LLP, SC, (float*)d_out);
}

// Round 11
// 586.465 us; speedup vs baseline: 6.7350x; 1.1354x over previous
//
#include <hip/hip_runtime.h>
#include <hip/hip_bf16.h>
#include <math.h>

#define BATCH 512
#define NI 627
#define NH 1024
#define NOUTF 1254
#define LLEN 627
#define NBL (512 * 627)
#define EPSBN 1e-5f
#define NSLOT 10240   // conv2: 2560 blocks*4 waves (conv3/4 use 5120)
#define NRED2 40      // conv2 reduction blocks (10240/256)
#define NRED34 20     // conv3/conv4 reduction blocks (5120/256)

typedef __attribute__((ext_vector_type(8))) short bf16x8;
typedef __attribute__((ext_vector_type(4))) float f32x4;
typedef unsigned int uint32;
typedef unsigned short ushort16;

__device__ inline short f2b(float x) {
  __hip_bfloat16 h = __float2bfloat16(x);
  return *reinterpret_cast<short*>(&h);
}
__device__ inline float b2f(short s) {
  return __uint_as_float(((uint32)(ushort16)s) << 16);
}
__device__ inline f32x4 mfma16(bf16x8 a, bf16x8 b, f32x4 c) {
  return __builtin_amdgcn_mfma_f32_16x16x32_bf16(a, b, c, 0, 0, 0);
}
// x1 fragment from preloaded coefficient registers
__device__ inline bf16x8 buildx1r(float4 alo, float4 ahi, float4 blo, float4 bhi, float th) {
  bf16x8 r;
  r[0] = f2b(fmaxf(fmaf(alo.x, th, blo.x), 0.f));
  r[1] = f2b(fmaxf(fmaf(alo.y, th, blo.y), 0.f));
  r[2] = f2b(fmaxf(fmaf(alo.z, th, blo.z), 0.f));
  r[3] = f2b(fmaxf(fmaf(alo.w, th, blo.w), 0.f));
  r[4] = f2b(fmaxf(fmaf(ahi.x, th, bhi.x), 0.f));
  r[5] = f2b(fmaxf(fmaf(ahi.y, th, bhi.y), 0.f));
  r[6] = f2b(fmaxf(fmaf(ahi.z, th, bhi.z), 0.f));
  r[7] = f2b(fmaxf(fmaf(ahi.w, th, bhi.w), 0.f));
  return r;
}
__device__ inline bf16x8 buildx1(const float* __restrict__ A1v, const float* __restrict__ B1v,
                                 int k0, float th) {
  float4 alo = *reinterpret_cast<const float4*>(&A1v[k0]);
  float4 ahi = *reinterpret_cast<const float4*>(&A1v[k0 + 4]);
  float4 blo = *reinterpret_cast<const float4*>(&B1v[k0]);
  float4 bhi = *reinterpret_cast<const float4*>(&B1v[k0 + 4]);
  return buildx1r(alo, ahi, blo, bhi, th);
}

// ================= prep kernels =================
__global__ __launch_bounds__(256) void prep_inputs(const float* __restrict__ in, short* __restrict__ outp) {
  int i = blockIdx.x * 256 + threadIdx.x;
  if (i >= 512 * 640) return;
  int m = i / 640, k = i - m * 640;
  outp[i] = (k < NI) ? f2b(in[m * NI + k]) : (short)0;
}

__global__ __launch_bounds__(256) void prep_mlpw(const float* __restrict__ W, short* __restrict__ Wb,
                                                 int Nreal, int Kreal, int Npad, int Kpad, int mode) {
  int i = blockIdx.x * 256 + threadIdx.x;
  if (i >= Npad * Kpad) return;
  int n = i / Kpad, k = i - n * Kpad;
  float w = 0.f;
  if (n < Nreal && k < Kreal) {
    int od = n >= 627 ? n - 627 : n;
    int kd = k >= 627 ? k - 627 : k;
    bool keep = (mode == 0) ? (od >= k) : (mode == 1) ? (od >= kd) : (od > kd);
    if (keep) w = W[n * Kreal + k];
  }
  Wb[i] = f2b(w);
}

__global__ __launch_bounds__(256) void prep_convw(const float* __restrict__ W, short* __restrict__ Wb,
                                                  int Oreal, int Kreal, int Opad, int Kpad) {
  int i = blockIdx.x * 256 + threadIdx.x;
  if (i >= Opad * Kpad) return;
  int o = i / Kpad, k = i - o * Kpad;
  Wb[i] = (o < Oreal && k < Kreal) ? f2b(W[o * Kreal + k]) : (short)0;
}

__global__ void prep_cb(const float* __restrict__ cb2, const float* __restrict__ cb3,
                        const float* __restrict__ cb4, const float* __restrict__ cb5,
                        float* __restrict__ cb2p, float* __restrict__ cb3p,
                        float* __restrict__ cb4p, float* __restrict__ cb5p) {
  int c = threadIdx.x;  // 320 threads
  if (c < 192) {
    cb2p[c] = (c < 180) ? cb2[c] : 0.f;
    cb3p[c] = (c < 180) ? cb3[c] : 0.f;
    cb4p[c] = (c < 180) ? cb4[c] : 0.f;
  }
  if (c < 320) cb5p[c] = (c < 300) ? cb5[c] : 0.f;
}

// ====== MLP MFMA GEMM: 32x64 tile, K-split-2 across waves ======
__global__ __launch_bounds__(256) void mlp_mfma(
    const short* __restrict__ A, const short* __restrict__ Wb, const float* __restrict__ bias,
    float* __restrict__ Cf, short* __restrict__ Cb, int Nreal, int Kpad, int relu)
{
  __shared__ float red[2][2][2][4][64];  // [wn][mi][nj][r][lane] = 16 KB
  const int tid = threadIdx.x;
  const int l = tid & 63, wv = tid >> 6;
  const int wn = wv >> 1, kh = wv & 1;
  const int m0 = blockIdx.y * 32;
  const int n0 = blockIdx.x * 64 + wn * 32;
  const int lr = l & 15, lk = (l >> 4) * 8, lm4 = (l >> 4) * 4;
  f32x4 acc[2][2] = {};
  const int khalf = Kpad >> 1;
  const int nk = khalf >> 5;
  for (int ks = 0; ks < nk; ++ks) {
    int k0 = kh * khalf + ks * 32 + lk;
    bf16x8 a0 = *reinterpret_cast<const bf16x8*>(&A[(size_t)(m0 + lr) * Kpad + k0]);
    bf16x8 a1 = *reinterpret_cast<const bf16x8*>(&A[(size_t)(m0 + 16 + lr) * Kpad + k0]);
    bf16x8 b0 = *reinterpret_cast<const bf16x8*>(&Wb[(size_t)(n0 + lr) * Kpad + k0]);
    bf16x8 b1 = *reinterpret_cast<const bf16x8*>(&Wb[(size_t)(n0 + 16 + lr) * Kpad + k0]);
    acc[0][0] = mfma16(a0, b0, acc[0][0]);
    acc[0][1] = mfma16(a0, b1, acc[0][1]);
    acc[1][0] = mfma16(a1, b0, acc[1][0]);
    acc[1][1] = mfma16(a1, b1, acc[1][1]);
  }
  if (kh == 1) {
#pragma unroll
    for (int mi = 0; mi < 2; ++mi)
#pragma unroll
      for (int nj = 0; nj < 2; ++nj)
#pragma unroll
        for (int r = 0; r < 4; ++r) red[wn][mi][nj][r][l] = acc[mi][nj][r];
  }
  __syncthreads();
  if (kh == 0) {
#pragma unroll
    for (int mi = 0; mi < 2; ++mi)
#pragma unroll
      for (int nj = 0; nj < 2; ++nj) {
        int n = n0 + nj * 16 + lr;
        if (n >= Nreal) continue;
        float bi = bias[n];
#pragma unroll
        for (int r = 0; r < 4; ++r) {
          int m = m0 + mi * 16 + lm4 + r;
          float v = acc[mi][nj][r] + red[wn][mi][nj][r][l] + bi;
          if (relu) v = fmaxf(v, 0.f);
          if (Cb) Cb[(size_t)m * Nreal + n] = f2b(v);
          else Cf[(size_t)m * Nreal + n] = v;
        }
      }
  }
}

// ================= theta stats =================
__global__ __launch_bounds__(256) void theta_stats(const float* __restrict__ outb, float* __restrict__ tstat)
{
  int b = blockIdx.x;
  const float* th = outb + (size_t)b * NOUTF + NI;
  float s = 0.f, q = 0.f;
  for (int l = threadIdx.x; l < LLEN; l += 256) { float t = th[l]; s += t; q += t * t; }
  for (int off = 1; off < 64; off <<= 1) { s += __shfl_xor(s, off); q += __shfl_xor(q, off); }
  __shared__ float tmp[8];
  int w = threadIdx.x >> 6;
  if ((threadIdx.x & 63) == 0) { tmp[w] = s; tmp[4 + w] = q; }
  __syncthreads();
  if (threadIdx.x == 0) {
    atomicAdd(&tstat[0], tmp[0] + tmp[1] + tmp[2] + tmp[3]);
    atomicAdd(&tstat[1], tmp[4] + tmp[5] + tmp[6] + tmp[7]);
  }
}

__global__ void finalize_conv1(const float* __restrict__ tstat, const float* __restrict__ cw1,
                               const float* __restrict__ g1, const float* __restrict__ be1,
                               float* __restrict__ a1, float* __restrict__ b1)
{
  int c = threadIdx.x;  // 96
  if (c >= 96) return;
  if (c < 90) {
    float mt = tstat[0] / (float)NBL;
    float vt = tstat[1] / (float)NBL - mt * mt;
    float w = cw1[c];
    float rs = rsqrtf(w * w * vt + EPSBN);
    float a = w * g1[c] * rs;
    a1[c] = a;
    b1[c] = be1[c] - a * mt;
  } else { a1[c] = 0.f; b1[c] = 0.f; }
}

// ============ BN stats reduction: [nslot][180] -> [nred][180] -> fold ============
__global__ __launch_bounds__(192) void bn_reduce1(const float* __restrict__ Sp, const float* __restrict__ Qp,
                                                  float* __restrict__ Sred, float* __restrict__ Qred)
{
  int c = threadIdx.x;
  if (c >= 180) return;
  int base = blockIdx.x * 256;
  float s = 0.f, q = 0.f;
  for (int r = 0; r < 256; ++r) {
    s += Sp[(size_t)(base + r) * 180 + c];
    q += Qp[(size_t)(base + r) * 180 + c];
  }
  Sred[blockIdx.x * 180 + c] = s;
  Qred[blockIdx.x * 180 + c] = q;
}

__global__ void finalize_bn2(const float* __restrict__ Sred, const float* __restrict__ Qred,
                             const float* __restrict__ g, const float* __restrict__ be,
                             float* __restrict__ aP, float* __restrict__ bP, int nred)
{
  int c = threadIdx.x;  // 192
  if (c >= 192) return;
  if (c < 180) {
    float s = 0.f, q = 0.f;
    for (int p = 0; p < nred; ++p) { s += Sred[p * 180 + c]; q += Qred[p * 180 + c]; }
    float m = s / (float)NBL;
    float v = q / (float)NBL - m * m;
    float a = g[c] * rsqrtf(v + EPSBN);
    aP[c] = a;
    bP[c] = be[c] - m * a;
  } else { aP[c] = 0.f; bP[c] = 0.f; }
}

// ================= conv2 stats-only (512 threads, zero LDS, no atomics) =================
__global__ __launch_bounds__(512) void conv2_stats(
    const float* __restrict__ OUTB, const float* __restrict__ A1v, const float* __restrict__ B1v,
    const short* __restrict__ cw2b, const float* __restrict__ cb2p,
    float* __restrict__ Sp, float* __restrict__ Qp)
{
  const int tid = threadIdx.x;
  const int b = blockIdx.y, j0 = blockIdx.x * 128;
  const int l = tid & 63, wv = tid >> 6, wm = wv >> 2, wn = wv & 3;
  const int lr = l & 15, lk = (l >> 4) * 8, lm4 = (l >> 4) * 4;
  const int jj0 = j0 + wn * 32 + lr, jj1 = jj0 + 16;
  const float th0 = (jj0 < LLEN) ? OUTB[(size_t)b * NOUTF + NI + jj0] : 0.f;
  const float th1 = (jj1 < LLEN) ? OUTB[(size_t)b * NOUTF + NI + jj1] : 0.f;
  f32x4 acc[6][2] = {};
#pragma unroll
  for (int ks = 0; ks < 3; ++ks) {
    int k0 = ks * 32 + lk;
    bf16x8 b0 = buildx1(A1v, B1v, k0, th0);
    bf16x8 b1 = buildx1(A1v, B1v, k0, th1);
#pragma unroll
    for (int mi = 0; mi < 6; ++mi) {
      bf16x8 av = *reinterpret_cast<const bf16x8*>(&cw2b[(wm * 96 + mi * 16 + lr) * 96 + k0]);
      acc[mi][0] = mfma16(av, b0, acc[mi][0]);
      acc[mi][1] = mfma16(av, b1, acc[mi][1]);
    }
  }
  const size_t slot = (size_t)(blockIdx.y * gridDim.x + blockIdx.x) * 4 + wn;
#pragma unroll
  for (int mi = 0; mi < 6; ++mi) {
    int m0c = wm * 96 + mi * 16 + lm4;
    float s4[4] = {0.f, 0.f, 0.f, 0.f}, q4[4] = {0.f, 0.f, 0.f, 0.f};
#pragma unroll
    for (int nj = 0; nj < 2; ++nj) {
      int jj = j0 + wn * 32 + nj * 16 + lr;
      if (jj < LLEN) {
#pragma unroll
        for (int r = 0; r < 4; ++r) {
          float v = acc[mi][nj][r] + cb2p[m0c + r];
          s4[r] += v; q4[r] += v * v;
        }
      }
    }
#pragma unroll
    for (int off = 1; off < 16; off <<= 1)
#pragma unroll
      for (int r = 0; r < 4; ++r) { s4[r] += __shfl_xor(s4[r], off); q4[r] += __shfl_xor(q4[r], off); }
    if (lr == 0) {
#pragma unroll
      for (int r = 0; r < 4; ++r) {
        int o = m0c + r;
        if (o < 180) {
          Sp[slot * 180 + o] = s4[r];
          Qp[slot * 180 + o] = q4[r];
        }
      }
    }
  }
}

// ==== fused conv2->bn2->relu->conv3: 128 cols, 8 waves = 4wm x 2wn, nj=4 (1:4 reuse) ====
__global__ __launch_bounds__(512) void fused_conv23(
    const float* __restrict__ OUTB, const float* __restrict__ A1v, const float* __restrict__ B1v,
    const short* __restrict__ cw2b, const float* __restrict__ cb2p,
    const float* __restrict__ a2, const float* __restrict__ b2,
    const short* __restrict__ cw3b, const float* __restrict__ cb3p,
    short* __restrict__ Y, float* __restrict__ Sp, float* __restrict__ Qp)
{
  __shared__ short xT2[128][200];  // x2 staging, then y3 output staging
  const int tid = threadIdx.x;
  const int b = blockIdx.y, j0 = blockIdx.x * 128;
  const int l = tid & 63, wv = tid >> 6, wm = wv >> 1, wn = wv & 1;
  const int lr = l & 15, lk = (l >> 4) * 8, lm4 = (l >> 4) * 4;
  float th[4];
#pragma unroll
  for (int nj = 0; nj < 4; ++nj) {
    int jj = j0 + wn * 64 + nj * 16 + lr;
    th[nj] = (jj < LLEN) ? OUTB[(size_t)b * NOUTF + NI + jj] : 0.f;
  }
  // conv2: channels wm*48..wm*48+47, columns wn*64..wn*64+63
  f32x4 acc[3][4] = {};
#pragma unroll
  for (int ks = 0; ks < 3; ++ks) {
    int k0 = ks * 32 + lk;
    float4 alo = *reinterpret_cast<const float4*>(&A1v[k0]);
    float4 ahi = *reinterpret_cast<const float4*>(&A1v[k0 + 4]);
    float4 blo = *reinterpret_cast<const float4*>(&B1v[k0]);
    float4 bhi = *reinterpret_cast<const float4*>(&B1v[k0 + 4]);
    bf16x8 bb[4];
#pragma unroll
    for (int nj = 0; nj < 4; ++nj) bb[nj] = buildx1r(alo, ahi, blo, bhi, th[nj]);
    bf16x8 av[3];
#pragma unroll
    for (int mi = 0; mi < 3; ++mi)
      av[mi] = *reinterpret_cast<const bf16x8*>(&cw2b[(wm * 48 + mi * 16 + lr) * 96 + k0]);
#pragma unroll
    for (int mi = 0; mi < 3; ++mi)
#pragma unroll
      for (int nj = 0; nj < 4; ++nj)
        acc[mi][nj] = mfma16(av[mi], bb[nj], acc[mi][nj]);
  }
  // x2 = relu(a2*(y2+cb2)+b2) -> xT2
#pragma unroll
  for (int mi = 0; mi < 3; ++mi) {
    int m0c = wm * 48 + mi * 16 + lm4;
    float cb0 = cb2p[m0c + 0], cb1 = cb2p[m0c + 1], cb2v = cb2p[m0c + 2], cb3v = cb2p[m0c + 3];
    float a20 = a2[m0c + 0], a21 = a2[m0c + 1], a22 = a2[m0c + 2], a23 = a2[m0c + 3];
    float b20 = b2[m0c + 0], b21 = b2[m0c + 1], b22 = b2[m0c + 2], b23 = b2[m0c + 3];
#pragma unroll
    for (int nj = 0; nj < 4; ++nj) {
      int col = wn * 64 + nj * 16 + lr;
      float x0 = fmaxf(fmaf(a20, acc[mi][nj][0] + cb0, b20), 0.f);
      float x1 = fmaxf(fmaf(a21, acc[mi][nj][1] + cb1, b21), 0.f);
      float x2 = fmaxf(fmaf(a22, acc[mi][nj][2] + cb2v, b22), 0.f);
      float x3 = fmaxf(fmaf(a23, acc[mi][nj][3] + cb3v, b23), 0.f);
      uint2 w2;
      w2.x = (uint32)(ushort16)f2b(x0) | ((uint32)(ushort16)f2b(x1) << 16);
      w2.y = (uint32)(ushort16)f2b(x2) | ((uint32)(ushort16)f2b(x3) << 16);
      *reinterpret_cast<uint2*>(&xT2[col][m0c]) = w2;
    }
  }
  __syncthreads();
  // conv3
  f32x4 acc2[3][4] = {};
#pragma unroll
  for (int ks = 0; ks < 6; ++ks) {
    int k0 = ks * 32 + lk;
    bf16x8 bb[4];
#pragma unroll
    for (int nj = 0; nj < 4; ++nj)
      bb[nj] = *reinterpret_cast<const bf16x8*>(&xT2[wn * 64 + nj * 16 + lr][k0]);
    bf16x8 av[3];
#pragma unroll
    for (int mi = 0; mi < 3; ++mi)
      av[mi] = *reinterpret_cast<const bf16x8*>(&cw3b[(wm * 48 + mi * 16 + lr) * 192 + k0]);
#pragma unroll
    for (int mi = 0; mi < 3; ++mi)
#pragma unroll
      for (int nj = 0; nj < 4; ++nj)
        acc2[mi][nj] = mfma16(av[mi], bb[nj], acc2[mi][nj]);
  }
  __syncthreads();  // conv3 reads done; reuse xT2 as y3 staging
  const size_t slot = (size_t)(blockIdx.y * gridDim.x + blockIdx.x) * 2 + wn;
#pragma unroll
  for (int mi = 0; mi < 3; ++mi) {
    int m0c = wm * 48 + mi * 16 + lm4;
    float cb0 = cb3p[m0c + 0], cb1 = cb3p[m0c + 1], cb2v = cb3p[m0c + 2], cb3v = cb3p[m0c + 3];
    float s4[4] = {0.f, 0.f, 0.f, 0.f}, q4[4] = {0.f, 0.f, 0.f, 0.f};
#pragma unroll
    for (int nj = 0; nj < 4; ++nj) {
      int col = wn * 64 + nj * 16 + lr;
      int jj = j0 + col;
      float v0 = acc2[mi][nj][0] + cb0;
      float v1 = acc2[mi][nj][1] + cb1;
      float v2 = acc2[mi][nj][2] + cb2v;
      float v3 = acc2[mi][nj][3] + cb3v;
      if (jj < LLEN) {
        s4[0] += v0; q4[0] += v0 * v0;
        s4[1] += v1; q4[1] += v1 * v1;
        s4[2] += v2; q4[2] += v2 * v2;
        s4[3] += v3; q4[3] += v3 * v3;
      }
      uint2 w2;
      w2.x = (uint32)(ushort16)f2b(v0) | ((uint32)(ushort16)f2b(v1) << 16);
      w2.y = (uint32)(ushort16)f2b(v2) | ((uint32)(ushort16)f2b(v3) << 16);
      *reinterpret_cast<uint2*>(&xT2[col][m0c]) = w2;
    }
#pragma unroll
    for (int off = 1; off < 16; off <<= 1)
#pragma unroll
      for (int r = 0; r < 4; ++r) { s4[r] += __shfl_xor(s4[r], off); q4[r] += __shfl_xor(q4[r], off); }
    if (lr == 0) {
#pragma unroll
      for (int r = 0; r < 4; ++r) {
        int o = m0c + r;
        if (o < 180) {
          Sp[slot * 180 + o] = s4[r];
          Qp[slot * 180 + o] = q4[r];
        }
      }
    }
  }
  __syncthreads();
  // coalesced copy out: 128 rows x 192 shorts
  for (int f = tid; f < 128 * 24; f += 512) {
    int row = f / 24, c0 = (f - row * 24) * 8;
    int jj = j0 + row;
    if (jj < LLEN) {
      bf16x8 v = *reinterpret_cast<const bf16x8*>(&xT2[row][c0]);
      *reinterpret_cast<bf16x8*>(&Y[((size_t)b * 627 + jj) * 192 + c0]) = v;
    }
  }
}

// ====== conv4 in place on Y: 128 cols, 8 waves = 4wm x 2wn, nj=4 ======
__global__ __launch_bounds__(512) void conv4_ip(
    short* __restrict__ Y, const float* __restrict__ a3, const float* __restrict__ b3,
    const short* __restrict__ cw4b, const float* __restrict__ cb4p,
    float* __restrict__ Sp, float* __restrict__ Qp)
{
  __shared__ short xT[128][200];  // x3 staging, then y4 output staging
  const int tid = threadIdx.x;
  const int b = blockIdx.y, j0 = blockIdx.x * 128;
  for (int t = tid; t < 128 * 24; t += 512) {
    int col = t / 24, oct = t - col * 24;
    int jj = j0 + col;
    int c0 = oct * 8;
    bf16x8 pk;
    if (jj < LLEN) {
      bf16x8 raw = *reinterpret_cast<const bf16x8*>(&Y[((size_t)b * 627 + jj) * 192 + c0]);
      float4 alo = *reinterpret_cast<const float4*>(&a3[c0]);
      float4 ahi = *reinterpret_cast<const float4*>(&a3[c0 + 4]);
      float4 blo = *reinterpret_cast<const float4*>(&b3[c0]);
      float4 bhi = *reinterpret_cast<const float4*>(&b3[c0 + 4]);
      pk[0] = f2b(fmaxf(fmaf(alo.x, b2f(raw[0]), blo.x), 0.f));
      pk[1] = f2b(fmaxf(fmaf(alo.y, b2f(raw[1]), blo.y), 0.f));
      pk[2] = f2b(fmaxf(fmaf(alo.z, b2f(raw[2]), blo.z), 0.f));
      pk[3] = f2b(fmaxf(fmaf(alo.w, b2f(raw[3]), blo.w), 0.f));
      pk[4] = f2b(fmaxf(fmaf(ahi.x, b2f(raw[4]), bhi.x), 0.f));
      pk[5] = f2b(fmaxf(fmaf(ahi.y, b2f(raw[5]), bhi.y), 0.f));
      pk[6] = f2b(fmaxf(fmaf(ahi.z, b2f(raw[6]), bhi.z), 0.f));
      pk[7] = f2b(fmaxf(fmaf(ahi.w, b2f(raw[7]), bhi.w), 0.f));
    } else {
#pragma unroll
      for (int i = 0; i < 8; ++i) pk[i] = 0;
    }
    *reinterpret_cast<bf16x8*>(&xT[col][c0]) = pk;
  }
  __syncthreads();
  const int l = tid & 63, wv = tid >> 6, wm = wv >> 1, wn = wv & 1;
  const int lr = l & 15, lk = (l >> 4) * 8, lm4 = (l >> 4) * 4;
  f32x4 acc[3][4] = {};
#pragma unroll
  for (int ks = 0; ks < 6; ++ks) {
    int k0 = ks * 32 + lk;
    bf16x8 bb[4];
#pragma unroll
    for (int nj = 0; nj < 4; ++nj)
      bb[nj] = *reinterpret_cast<const bf16x8*>(&xT[wn * 64 + nj * 16 + lr][k0]);
    bf16x8 av[3];
#pragma unroll
    for (int mi = 0; mi < 3; ++mi)
      av[mi] = *reinterpret_cast<const bf16x8*>(&cw4b[(wm * 48 + mi * 16 + lr) * 192 + k0]);
#pragma unroll
    for (int mi = 0; mi < 3; ++mi)
#pragma unroll
      for (int nj = 0; nj < 4; ++nj)
        acc[mi][nj] = mfma16(av[mi], bb[nj], acc[mi][nj]);
  }
  __syncthreads();  // input reads done; reuse xT as y4 staging
  const size_t slot = (size_t)(blockIdx.y * gridDim.x + blockIdx.x) * 2 + wn;
#pragma unroll
  for (int mi = 0; mi < 3; ++mi) {
    int m0c = wm * 48 + mi * 16 + lm4;
    float cb0 = cb4p[m0c + 0], cb1 = cb4p[m0c + 1], cb2v = cb4p[m0c + 2], cb3v = cb4p[m0c + 3];
    float s4[4] = {0.f, 0.f, 0.f, 0.f}, q4[4] = {0.f, 0.f, 0.f, 0.f};
#pragma unroll
    for (int nj = 0; nj < 4; ++nj) {
      int col = wn * 64 + nj * 16 + lr;
      int jj = j0 + col;
      float v0 = acc[mi][nj][0] + cb0;
      float v1 = acc[mi][nj][1] + cb1;
      float v2 = acc[mi][nj][2] + cb2v;
      float v3 = acc[mi][nj][3] + cb3v;
      if (jj < LLEN) {
        s4[0] += v0; q4[0] += v0 * v0;
        s4[1] += v1; q4[1] += v1 * v1;
        s4[2] += v2; q4[2] += v2 * v2;
        s4[3] += v3; q4[3] += v3 * v3;
      }
      uint2 w2;
      w2.x = (uint32)(ushort16)f2b(v0) | ((uint32)(ushort16)f2b(v1) << 16);
      w2.y = (uint32)(ushort16)f2b(v2) | ((uint32)(ushort16)f2b(v3) << 16);
      *reinterpret_cast<uint2*>(&xT[col][m0c]) = w2;
    }
#pragma unroll
    for (int off = 1; off < 16; off <<= 1)
#pragma unroll
      for (int r = 0; r < 4; ++r) { s4[r] += __shfl_xor(s4[r], off); q4[r] += __shfl_xor(q4[r], off); }
    if (lr == 0) {
#pragma unroll
      for (int r = 0; r < 4; ++r) {
        int o = m0c + r;
        if (o < 180) {
          Sp[slot * 180 + o] = s4[r];
          Qp[slot * 180 + o] = q4[r];
        }
      }
    }
  }
  __syncthreads();
  for (int f = tid; f < 128 * 24; f += 512) {
    int row = f / 24, c0 = (f - row * 24) * 8;
    int jj = j0 + row;
    if (jj < LLEN) {
      bf16x8 v = *reinterpret_cast<const bf16x8*>(&xT[row][c0]);
      *reinterpret_cast<bf16x8*>(&Y[((size_t)b * 627 + jj) * 192 + c0]) = v;
    }
  }
}

// ======= conv5 (MFMA) + register log_softmax + NLL; 64 cols/block =======
__global__ __launch_bounds__(256) void conv5_nll(
    const short* __restrict__ Y, const float* __restrict__ a4, const float* __restrict__ b4,
    const short* __restrict__ cw5b, const float* __restrict__ cb5p,
    const float* __restrict__ inputs, float* __restrict__ nll)
{
  __shared__ float ab[384];
  __shared__ short xT[64][200];
  __shared__ float wmax[4][64];
  __shared__ float wsum[4][64];
  __shared__ float ptgt[64];
  __shared__ int tg[64];
  const int tid = threadIdx.x;
  const int b = blockIdx.y, l0 = blockIdx.x * 64;
  for (int t = tid; t < 384; t += 256) ab[t] = (t < 192) ? a4[t] : b4[t - 192];
  if (tid < 64) {
    int jj = l0 + tid;
    tg[tid] = (jj < LLEN) ? (int)inputs[(size_t)b * NI + jj] : 0;
  }
  __syncthreads();
  for (int t = tid; t < 64 * 24; t += 256) {
    int col = t / 24, oct = t - col * 24;
    int jj = l0 + col;
    int c0 = oct * 8;
    bf16x8 pk;
    if (jj < LLEN) {
      bf16x8 raw = *reinterpret_cast<const bf16x8*>(&Y[((size_t)b * 627 + jj) * 192 + c0]);
#pragma unroll
      for (int i = 0; i < 8; ++i)
        pk[i] = f2b(fmaxf(fmaf(ab[c0 + i], b2f(raw[i]), ab[192 + c0 + i]), 0.f));
    } else {
#pragma unroll
      for (int i = 0; i < 8; ++i) pk[i] = 0;
    }
    *reinterpret_cast<bf16x8*>(&xT[col][c0]) = pk;
  }
  __syncthreads();
  const int l = tid & 63, wv = tid >> 6;
  const int lr = l & 15, lk = (l >> 4) * 8, lm4 = (l >> 4) * 4;
  const int mf0 = wv * 5;
  f32x4 acc[5][4] = {};
#pragma unroll
  for (int ks = 0; ks < 6; ++ks) {
    int k0 = ks * 32 + lk;
    bf16x8 bb0 = *reinterpret_cast<const bf16x8*>(&xT[lr][k0]);
    bf16x8 bb1 = *reinterpret_cast<const bf16x8*>(&xT[16 + lr][k0]);
    bf16x8 bb2 = *reinterpret_cast<const bf16x8*>(&xT[32 + lr][k0]);
    bf16x8 bb3 = *reinterpret_cast<const bf16x8*>(&xT[48 + lr][k0]);
#pragma unroll
    for (int mi = 0; mi < 5; ++mi) {
      bf16x8 av = *reinterpret_cast<const bf16x8*>(&cw5b[((mf0 + mi) * 16 + lr) * 192 + k0]);
      acc[mi][0] = mfma16(av, bb0, acc[mi][0]);
      acc[mi][1] = mfma16(av, bb1, acc[mi][1]);
      acc[mi][2] = mfma16(av, bb2, acc[mi][2]);
      acc[mi][3] = mfma16(av, bb3, acc[mi][3]);
    }
  }
  float vmax[4] = {-1e30f, -1e30f, -1e30f, -1e30f};
#pragma unroll
  for (int mi = 0; mi < 5; ++mi) {
#pragma unroll
    for (int r = 0; r < 4; ++r) {
      int m = (mf0 + mi) * 16 + lm4 + r;
      float bi = cb5p[m];
      bool ok = (m < 300);
#pragma unroll
      for (int nj = 0; nj < 4; ++nj) {
        float v = ok ? (acc[mi][nj][r] + bi) : -1e30f;
        acc[mi][nj][r] = v;
        vmax[nj] = fmaxf(vmax[nj], v);
      }
    }
  }
  {
    int t0 = tg[lr], t1 = tg[16 + lr], t2 = tg[32 + lr], t3 = tg[48 + lr];
#pragma unroll
    for (int mi = 0; mi < 5; ++mi) {
#pragma unroll
      for (int r = 0; r < 4; ++r) {
        int m = (mf0 + mi) * 16 + lm4 + r;
        if (m == t0) ptgt[lr] = acc[mi][0][r];
        if (m == t1) ptgt[16 + lr] = acc[mi][1][r];
        if (m == t2) ptgt[32 + lr] = acc[mi][2][r];
        if (m == t3) ptgt[48 + lr] = acc[mi][3][r];
      }
    }
  }
#pragma unroll
  for (int nj = 0; nj < 4; ++nj) {
    vmax[nj] = fmaxf(vmax[nj], __shfl_xor(vmax[nj], 16));
    vmax[nj] = fmaxf(vmax[nj], __shfl_xor(vmax[nj], 32));
  }
  if (l < 16) {
#pragma unroll
    for (int nj = 0; nj < 4; ++nj) wmax[wv][nj * 16 + lr] = vmax[nj];
  }
  __syncthreads();
  float gmax[4], vs[4] = {0.f, 0.f, 0.f, 0.f};
#pragma unroll
  for (int nj = 0; nj < 4; ++nj) {
    int cc = nj * 16 + lr;
    gmax[nj] = fmaxf(fmaxf(wmax[0][cc], wmax[1][cc]), fmaxf(wmax[2][cc], wmax[3][cc]));
  }
#pragma unroll
  for (int mi = 0; mi < 5; ++mi)
#pragma unroll
    for (int r = 0; r < 4; ++r)
#pragma unroll
      for (int nj = 0; nj < 4; ++nj)
        vs[nj] += __expf(acc[mi][nj][r] - gmax[nj]);
#pragma unroll
  for (int nj = 0; nj < 4; ++nj) {
    vs[nj] += __shfl_xor(vs[nj], 16);
    vs[nj] += __shfl_xor(vs[nj], 32);
  }
  if (l < 16) {
#pragma unroll
    for (int nj = 0; nj < 4; ++nj) wsum[wv][nj * 16 + lr] = vs[nj];
  }
  __syncthreads();
  if (tid < 64) {
    int jj = l0 + tid;
    if (jj < LLEN) {
      float gm = fmaxf(fmaxf(wmax[0][tid], wmax[1][tid]), fmaxf(wmax[2][tid], wmax[3][tid]));
      float gs = wsum[0][tid] + wsum[1][tid] + wsum[2][tid] + wsum[3][tid];
      nll[(size_t)b * LLEN + jj] = gm + logf(gs) - ptgt[tid];
    }
  }
}

// ================= final assembly =================
__global__ __launch_bounds__(256) void ll_pass1(
    const float* __restrict__ outb, const float* __restrict__ nll,
    const float* __restrict__ inputs, float* __restrict__ llp, float* __restrict__ sc)
{
  int b = blockIdx.x;
  float s = 0.f;
  for (int l = 2 + (int)threadIdx.x; l < LLEN; l += 256) {
    float graw = outb[(size_t)b * NOUTF + l];
    float sg = 1.f / (1.f + expf(-graw));
    float term;
    if (inputs[(size_t)b * NI + l] > 0.f)
      term = 0.1f * logf(sg + 1e-10f) - nll[(size_t)b * LLEN + l];
    else
      term = 0.1f * logf(1.f - sg + 1e-10f);
    s += term;
  }
  for (int off = 1; off < 64; off <<= 1) s += __shfl_xor(s, off);
  __shared__ float tmp[4];
  if ((threadIdx.x & 63) == 0) tmp[threadIdx.x >> 6] = s;
  __syncthreads();
  if (threadIdx.x == 0) {
    llp[b] = tmp[0] + tmp[1] + tmp[2] + tmp[3];
    atomicAdd(sc, nll[(size_t)b * LLEN] + nll[(size_t)b * LLEN + 1]);
  }
}

__global__ void ll_pass2(const float* __restrict__ llp, const float* __restrict__ sc, float* __restrict__ outp)
{
  int i = blockIdx.x * blockDim.x + threadIdx.x;
  if (i < BATCH) outp[i] = llp[i] - sc[0] * (1.f / 1024.f);
}

extern "C" void kernel_launch(void* const* d_in, const int* in_sizes, int n_in,
                              void* d_out, int out_size, void* d_ws, size_t ws_size,
                              hipStream_t stream)
{
  const float* inputs = (const float*)d_in[0];
  const float* W_in = (const float*)d_in[1];
  const float* b_in = (const float*)d_in[2];
  const float* W_h1 = (const float*)d_in[3];
  const float* b_h1 = (const float*)d_in[4];
  const float* W_h2 = (const float*)d_in[5];
  const float* b_h2 = (const float*)d_in[6];
  const float* W_out = (const float*)d_in[7];
  const float* b_out = (const float*)d_in[8];
  const float* cw1 = (const float*)d_in[9];
  const float* g1 = (const float*)d_in[11];
  const float* be1 = (const float*)d_in[12];
  const float* cw2 = (const float*)d_in[13];
  const float* cb2 = (const float*)d_in[14];
  const float* g2 = (const float*)d_in[15];
  const float* be2 = (const float*)d_in[16];
  const float* cw3 = (const float*)d_in[17];
  const float* cb3 = (const float*)d_in[18];
  const float* g3 = (const float*)d_in[19];
  const float* be3 = (const float*)d_in[20];
  const float* cw4 = (const float*)d_in[21];
  const float* cb4 = (const float*)d_in[22];
  const float* g4 = (const float*)d_in[23];
  const float* be4 = (const float*)d_in[24];
  const float* cw5 = (const float*)d_in[25];
  const float* cb5 = (const float*)d_in[26];

  char* p = (char*)d_ws;
  short* Y = (short*)p;    p += (size_t)512 * 627 * 192 * 2;
  short* INB = (short*)p;  p += (size_t)512 * 640 * 2;
  short* HB1 = (short*)p;  p += (size_t)512 * 1024 * 2;
  short* HB2 = (short*)p;  p += (size_t)512 * 1024 * 2;
  short* HB3 = (short*)p;  p += (size_t)512 * 1024 * 2;
  short* WB1 = (short*)p;  p += (size_t)1024 * 640 * 2;
  short* WB2 = (short*)p;  p += (size_t)1024 * 1024 * 2;
  short* WB3 = (short*)p;  p += (size_t)1024 * 1024 * 2;
  short* WB4 = (short*)p;  p += (size_t)1280 * 1024 * 2;
  short* CW2B = (short*)p; p += (size_t)192 * 96 * 2;
  short* CW3B = (short*)p; p += (size_t)192 * 192 * 2;
  short* CW4B = (short*)p; p += (size_t)192 * 192 * 2;
  short* CW5B = (short*)p; p += (size_t)320 * 192 * 2;
  float* fp = (float*)p;
  float* OUTB = fp;  fp += (size_t)512 * 1254;
  float* NLLB = fp;  fp += 321028;
  float* LLP = fp;   fp += 512;
  float* A1 = fp;    fp += 96;
  float* B1g = fp;   fp += 96;
  float* A2 = fp;    fp += 192;
  float* B2g = fp;   fp += 192;
  float* A3 = fp;    fp += 192;
  float* B3g = fp;   fp += 192;
  float* A4 = fp;    fp += 192;
  float* B4g = fp;   fp += 192;
  float* CB2P = fp;  fp += 192;
  float* CB3P = fp;  fp += 192;
  float* CB4P = fp;  fp += 192;
  float* CB5P = fp;  fp += 320;
  float* TST = fp;   fp += 2;
  float* SC = fp;    fp += 2;
  float* SPP = fp;   fp += (size_t)NSLOT * 180;
  float* QPP = fp;   fp += (size_t)NSLOT * 180;
  float* SRED = fp;  fp += NRED2 * 180;
  float* QRED = fp;  fp += NRED2 * 180;

  hipMemsetAsync(TST, 0, 4 * sizeof(float), stream);

  // prep: inputs, masked MLP weights, conv weights, padded biases
  prep_inputs<<<dim3((512 * 640 + 255) / 256), 256, 0, stream>>>(inputs, INB);
  prep_mlpw<<<dim3((1024 * 640 + 255) / 256), 256, 0, stream>>>(W_in, WB1, 1024, 627, 1024, 640, 0);
  prep_mlpw<<<dim3((1024 * 1024 + 255) / 256), 256, 0, stream>>>(W_h1, WB2, 1024, 1024, 1024, 1024, 1);
  prep_mlpw<<<dim3((1024 * 1024 + 255) / 256), 256, 0, stream>>>(W_h2, WB3, 1024, 1024, 1024, 1024, 1);
  prep_mlpw<<<dim3((1280 * 1024 + 255) / 256), 256, 0, stream>>>(W_out, WB4, 1254, 1024, 1280, 1024, 2);
  prep_convw<<<dim3((192 * 96 + 255) / 256), 256, 0, stream>>>(cw2, CW2B, 180, 90, 192, 96);
  prep_convw<<<dim3((192 * 192 + 255) / 256), 256, 0, stream>>>(cw3, CW3B, 180, 180, 192, 192);
  prep_convw<<<dim3((192 * 192 + 255) / 256), 256, 0, stream>>>(cw4, CW4B, 180, 180, 192, 192);
  prep_convw<<<dim3((320 * 192 + 255) / 256), 256, 0, stream>>>(cw5, CW5B, 300, 180, 320, 192);
  prep_cb<<<1, 320, 0, stream>>>(cb2, cb3, cb4, cb5, CB2P, CB3P, CB4P, CB5P);

  // masked MLP (MFMA, 32x64 tiles, K-split-2)
  mlp_mfma<<<dim3(16, 16), 256, 0, stream>>>(INB, WB1, b_in, nullptr, HB1, 1024, 640, 1);
  mlp_mfma<<<dim3(16, 16), 256, 0, stream>>>(HB1, WB2, b_h1, nullptr, HB2, 1024, 1024, 1);
  mlp_mfma<<<dim3(16, 16), 256, 0, stream>>>(HB2, WB3, b_h2, nullptr, HB3, 1024, 1024, 0);
  mlp_mfma<<<dim3(20, 16), 256, 0, stream>>>(HB3, WB4, b_out, OUTB, nullptr, 1254, 1024, 0);

  // conv1+bn1 folded via theta stats
  theta_stats<<<dim3(BATCH), 256, 0, stream>>>(OUTB, TST);
  finalize_conv1<<<1, 96, 0, stream>>>(TST, cw1, g1, be1, A1, B1g);

  // conv2 stats -> bn2 fold (10240 slots)
  conv2_stats<<<dim3(5, BATCH), 512, 0, stream>>>(OUTB, A1, B1g, CW2B, CB2P, SPP, QPP);
  bn_reduce1<<<dim3(NRED2), 192, 0, stream>>>(SPP, QPP, SRED, QRED);
  finalize_bn2<<<1, 192, 0, stream>>>(SRED, QRED, g2, be2, A2, B2g, NRED2);

  // fused conv2->conv3 -> Y (y3) + stats3 (5120 slots) -> bn3 fold
  fused_conv23<<<dim3(5, BATCH), 512, 0, stream>>>(OUTB, A1, B1g, CW2B, CB2P, A2, B2g, CW3B, CB3P, Y, SPP, QPP);
  bn_reduce1<<<dim3(NRED34), 192, 0, stream>>>(SPP, QPP, SRED, QRED);
  finalize_bn2<<<1, 192, 0, stream>>>(SRED, QRED, g3, be3, A3, B3g, NRED34);

  // conv4 in place + stats4 (5120 slots) -> bn4 fold
  conv4_ip<<<dim3(5, BATCH), 512, 0, stream>>>(Y, A3, B3g, CW4B, CB4P, SPP, QPP);
  bn_reduce1<<<dim3(NRED34), 192, 0, stream>>>(SPP, QPP, SRED, QRED);
  finalize_bn2<<<1, 192, 0, stream>>>(SRED, QRED, g4, be4, A4, B4g, NRED34);

  // conv5 + register log_softmax + nll (64 cols/block)
  conv5_nll<<<dim3(10, BATCH), 256, 0, stream>>>(Y, A4, B4g, CW5B, CB5P, inputs, NLLB);

  // final assembly
  ll_pass1<<<dim3(BATCH), 256, 0, stream>>>(OUTB, NLLB, inputs, LLP, SC);
  ll_pass2<<<dim3(2), 256, 0, stream>>>(LLP, SC, (float*)d_out);
}